// Round 3
// baseline (1994.467 us; speedup 1.0000x reference)
//
#include <hip/hip_runtime.h>
#include <hip/hip_bf16.h>
#include <stdint.h>

// ---------------- problem constants ----------------
#define LTOK  1025      // 1024 body + 1 cls
#define NROWS 2050      // B * LTOK
#define DM    512
#define DIN   1024
#define DST   128
#define NHEAD 16
#define HDIM  64
#define CDIM  1280      // DIN + 2*DST
#define EPROJ 2320      // 2*DIN + 2*DST + NHEAD

// ---------------- workspace layout (float offsets), total 11,760,032 floats = 47.0 MB ----------------
#define O_RIDX   0          // int32 x 514 (reserve 1024)
#define O_CB     1024
#define O_CLS    1536
#define O_C1B    2048
#define O_DTB    3328
#define O_ALOG   3344
#define O_DV     3360
#define O_RMSW   3376
#define O_LNG    4400
#define O_LNB    4912
#define O_CW     5440
#define O_IPW    103744
#define O_OPW    1291584
#define O_C1W    1815872
#define O_CX     1820992
#define O_ZX     1952064
#define O_XBC    6708064
#define O_DT     9332064
#define O_DA     9364864
#define O_Y      9397664    // 2,099,200 floats; overlays H and X3 (dead after in_proj)
#define O_H      9397664    // 1,049,600
#define O_X3     10447264   // 393,216
#define O_OUTG   11496864   // 263,168 -> ends 11,760,032

// ---------------- output layout (FLOAT32 elements — harness reads f32) ----------------
#define OO_MASK 263168      // after x_out (2*257*512)
#define OO_IDR  265216
#define OO_IDK  267264

struct InPtrs { const void* p[14]; };

// ---------------- input dtype detect + convert to f32 ----------------
__device__ int detect_is_f32(const uint32_t* w, int nelem) {
  int nw = nelem / 2; if (nw > 16) nw = 16;
  int insane = 0, lozero = 0, anynz = 0;
  for (int i = 0; i < nw; ++i) {
    uint32_t word = w[i];
    if (word != 0u) anynz = 1;
    uint32_t lo = word & 0xffffu;
    if (lo == 0u) { lozero++; continue; }
    float v = __uint_as_float(lo << 16);
    float a = fabsf(v);
    if (!(a >= 1e-8f && a <= 1e4f)) insane++;   // NaN fails the range check too
  }
  if (insane >= 2) return 1;                    // f32: low halves are mantissa noise
  if (lozero == nw && anynz) return 1;          // f32 of exact powers (e.g. all-ones)
  return 0;                                     // bf16 (or all zeros; identical either way)
}

__global__ void k_convert(InPtrs ptrs, float* ws) {
  static const int sizes[14] = {131072, 98304, 512, 512, 1187840, 5120, 1280,
                                16, 16, 16, 1024, 524288, 512, 512};
  static const int offs[14]  = {O_CX, O_CW, O_CB, O_CLS, O_IPW, O_C1W, O_C1B,
                                O_DTB, O_ALOG, O_DV, O_RMSW, O_OPW, O_LNG, O_LNB};
  int t = blockIdx.x;
  int n = sizes[t];
  const uint32_t* w = (const uint32_t*)ptrs.p[t];
  __shared__ int sf;
  if (threadIdx.x == 0) sf = detect_is_f32(w, n);
  __syncthreads();
  float* dst = ws + offs[t];
  if (sf) {
    const float* s = (const float*)w;
    for (int i = threadIdx.x; i < n; i += blockDim.x) dst[i] = s[i];
  } else {
    const uint16_t* s = (const uint16_t*)w;
    for (int i = threadIdx.x; i < n; i += blockDim.x)
      dst[i] = __uint_as_float(((uint32_t)s[i]) << 16);
  }
}

// ---------------- threefry2x32 (JAX-compatible) ----------------
__device__ __forceinline__ uint32_t rotl32(uint32_t v, int d) {
  return (v << d) | (v >> (32 - d));
}
__device__ void threefry2x32(uint32_t k0, uint32_t k1, uint32_t c0, uint32_t c1,
                             uint32_t& o0, uint32_t& o1) {
  uint32_t ks0 = k0, ks1 = k1, ks2 = 0x1BD11BDAu ^ k0 ^ k1;
  uint32_t x0 = c0 + ks0, x1 = c1 + ks1;
#define TF_R4(a,b,c,d) \
  x0 += x1; x1 = rotl32(x1,a); x1 ^= x0; \
  x0 += x1; x1 = rotl32(x1,b); x1 ^= x0; \
  x0 += x1; x1 = rotl32(x1,c); x1 ^= x0; \
  x0 += x1; x1 = rotl32(x1,d); x1 ^= x0;
  TF_R4(13,15,26,6)  x0 += ks1; x1 += ks2 + 1u;
  TF_R4(17,29,16,24) x0 += ks2; x1 += ks0 + 2u;
  TF_R4(13,15,26,6)  x0 += ks0; x1 += ks1 + 3u;
  TF_R4(17,29,16,24) x0 += ks1; x1 += ks2 + 4u;
  TF_R4(13,15,26,6)  x0 += ks2; x1 += ks0 + 5u;
#undef TF_R4
  o0 = x0; o1 = x1;
}

// RNG + stable argsort ranks + mask/ids outputs + gather row list. All f32 stores.
// Partitionable threefry stream (current JAX default): bits = o0^o1, count = (0, flat idx).
__global__ __launch_bounds__(1024) void k_rng(float* out, int* rowidx) {
  int b = blockIdx.x;
  int i = threadIdx.x;
  __shared__ float vals[1024];
  uint32_t fk0, fk1;
  threefry2x32(0u, 0u, 0u, 1u, fk0, fk1);          // fold_in(key(0), 1)
  uint32_t o0, o1;
  threefry2x32(fk0, fk1, 0u, (uint32_t)(b * 1024 + i), o0, o1);
  uint32_t bits = o0 ^ o1;
  float v = __uint_as_float((bits >> 9) | 0x3f800000u) - 1.0f;
  vals[i] = v;
  __syncthreads();
  int r = 0;
  for (int j = 0; j < 1024; ++j) {
    float vj = vals[j];
    r += (vj < v || (vj == v && j < i)) ? 1 : 0;   // stable ascending rank
  }
  out[OO_IDR + b * 1024 + i] = (float)r;
  out[OO_MASK + b * 1024 + i] = (r < 256) ? 0.0f : 1.0f;
  if (r < 256) {
    out[OO_IDK + b * 256 + r] = (float)i;
    rowidx[b * 257 + r] = b * LTOK + i;            // kept body rows
  }
  if (i == 0) rowidx[b * 257 + 256] = b * LTOK + 1024;  // cls row
}

// ---------------- im2col for conv-embed ----------------
__global__ void k_im2col(const float* __restrict__ x, float* __restrict__ X3) {
  int r = blockIdx.x;                 // 0..2047  (b*1024+t)
  int b = r >> 10, t = r & 1023;
  int j = threadIdx.x;                // blockDim = 192
  if (j < 192) {
    int i = j / 3, k = j % 3;
    int tt = t + k - 1;
    float v = (tt >= 0 && tt < 1024) ? x[((long)(b * 1024 + tt)) * 64 + i] : 0.f;
    X3[(long)r * 192 + j] = v;
  }
}

__global__ void k_clsrow(const float* __restrict__ cls, float* __restrict__ h) {
  h[((long)(blockIdx.x * LTOK + 1024)) * DM + threadIdx.x] = cls[threadIdx.x];
}

// ---------------- generic fp32 SGEMM: C = A @ Bw^T (+bias) ----------------
__global__ __launch_bounds__(256) void k_sgemm(
    const float* __restrict__ A, const float* __restrict__ Bw,
    float* __restrict__ C, const float* __restrict__ bias,
    const int* __restrict__ rowmap, int M, int N, int K, int ldc, int cmode) {
  __shared__ float As[16][64];
  __shared__ float Bs[16][64];
  int tid = threadIdx.x;
  int bm = blockIdx.y << 6, bn = blockIdx.x << 6;
  int tx = tid & 15, ty = tid >> 4;
  int arow = tid >> 2, acol = (tid & 3) << 2;
  int gm = bm + arow, gn = bn + arow;
  bool mok = gm < M, nok = gn < N;
  long aoff = 0;
  if (mok) aoff = (long)(rowmap ? rowmap[gm] : gm) * K;
  long boff = (long)gn * K;
  float acc[4][4] = {};
  for (int k0 = 0; k0 < K; k0 += 16) {
    float4 av = make_float4(0.f,0.f,0.f,0.f), bv = make_float4(0.f,0.f,0.f,0.f);
    if (mok) av = *(const float4*)(A + aoff + k0 + acol);
    if (nok) bv = *(const float4*)(Bw + boff + k0 + acol);
    __syncthreads();
    As[acol+0][arow]=av.x; As[acol+1][arow]=av.y; As[acol+2][arow]=av.z; As[acol+3][arow]=av.w;
    Bs[acol+0][arow]=bv.x; Bs[acol+1][arow]=bv.y; Bs[acol+2][arow]=bv.z; Bs[acol+3][arow]=bv.w;
    __syncthreads();
#pragma unroll
    for (int kk = 0; kk < 16; ++kk) {
      float a[4], bb[4];
#pragma unroll
      for (int i = 0; i < 4; ++i) a[i] = As[kk][ty*4+i];
#pragma unroll
      for (int j = 0; j < 4; ++j) bb[j] = Bs[kk][tx*4+j];
#pragma unroll
      for (int i = 0; i < 4; ++i)
#pragma unroll
        for (int j = 0; j < 4; ++j) acc[i][j] = fmaf(a[i], bb[j], acc[i][j]);
    }
  }
#pragma unroll
  for (int i = 0; i < 4; ++i) {
    int r = bm + ty*4 + i;
    if (r >= M) continue;
    long crow = (cmode == 1) ? (long)((r >> 10) * LTOK + (r & 1023)) : (long)r;
#pragma unroll
    for (int j = 0; j < 4; ++j) {
      int c = bn + tx*4 + j;
      if (c < N) {
        float v = acc[i][j];
        if (bias) v += bias[c];
        C[crow * ldc + c] = v;
      }
    }
  }
}

// ---------------- depthwise causal conv(4) + silu ----------------
__global__ __launch_bounds__(256) void k_conv1d(const float* __restrict__ zx,
                                                const float* __restrict__ w,
                                                const float* __restrict__ bias,
                                                float* __restrict__ xbc) {
  long r = blockIdx.x;                 // 0..2049
  int b = (int)(r / LTOK), t = (int)(r % LTOK);
  for (int c = threadIdx.x; c < CDIM; c += 256) {
    float acc = bias[c];
    const float* wp = w + c * 4;
#pragma unroll
    for (int k = 0; k < 4; ++k) {
      int tt = t - 3 + k;
      if (tt >= 0)
        acc = fmaf(wp[k], zx[((long)(b * LTOK + tt)) * EPROJ + DIN + c], acc);
    }
    xbc[r * CDIM + c] = acc / (1.f + expf(-acc));   // silu
  }
}

// ---------------- dt = softplus(logit + bias), dA = exp(dt * -exp(A_log)) ----------------
__global__ void k_dtda(const float* __restrict__ zx, const float* __restrict__ dtb,
                       const float* __restrict__ alog, float* __restrict__ dt,
                       float* __restrict__ dA) {
  int idx = blockIdx.x * 256 + threadIdx.x;
  if (idx >= NROWS * NHEAD) return;
  int r = idx >> 4, h = idx & 15;
  float xv = zx[(long)r * EPROJ + (EPROJ - NHEAD) + h] + dtb[h];
  float dtv = (xv > 20.f) ? xv : log1pf(expf(xv));
  dt[idx] = dtv;
  dA[idx] = expf(dtv * (-expf(alog[h])));
}

// ---------------- zero the Y accumulator ----------------
__global__ __launch_bounds__(256) void k_zeroY(float* __restrict__ Y) {
  long r = blockIdx.x;                 // 0..2049
  float4 z = make_float4(0.f, 0.f, 0.f, 0.f);
  *(float4*)(Y + r * DIN + threadIdx.x * 4) = z;
}

// ---------------- sequential SSM scan (atomic accumulate into Y) ----------------
// grid 128 = (b, h, g); g = n-group of 32 states. thread: p = tid>>2 (0..63),
// q = tid&3 owns 8 n's. Depth-2 software-pipelined loads; y reduced over q via shfl.
struct SD { float Bv[8], Cv[8], x, dtv, dAv; };

__device__ __forceinline__ SD scan_load(const float* base, const float* dtp,
                                        const float* dAp, int t, int nbase, int xoff) {
  SD d;
  if (t < LTOK) {
    const float* row = base + (long)t * CDIM;
    float4 b0 = *(const float4*)(row + DIN + nbase);
    float4 b1 = *(const float4*)(row + DIN + nbase + 4);
    float4 c0 = *(const float4*)(row + DIN + DST + nbase);
    float4 c1 = *(const float4*)(row + DIN + DST + nbase + 4);
    d.Bv[0]=b0.x; d.Bv[1]=b0.y; d.Bv[2]=b0.z; d.Bv[3]=b0.w;
    d.Bv[4]=b1.x; d.Bv[5]=b1.y; d.Bv[6]=b1.z; d.Bv[7]=b1.w;
    d.Cv[0]=c0.x; d.Cv[1]=c0.y; d.Cv[2]=c0.z; d.Cv[3]=c0.w;
    d.Cv[4]=c1.x; d.Cv[5]=c1.y; d.Cv[6]=c1.z; d.Cv[7]=c1.w;
    d.x = row[xoff];
    d.dtv = dtp[(long)t * NHEAD];
    d.dAv = dAp[(long)t * NHEAD];
  } else {
#pragma unroll
    for (int j = 0; j < 8; ++j) { d.Bv[j] = 0.f; d.Cv[j] = 0.f; }
    d.x = 0.f; d.dtv = 0.f; d.dAv = 0.f;
  }
  return d;
}

__global__ __launch_bounds__(256) void k_scan(const float* __restrict__ xbc,
                                              const float* __restrict__ dt,
                                              const float* __restrict__ dA,
                                              float* __restrict__ Y) {
  int blk = blockIdx.x;
  int g = blk & 3, h = (blk >> 2) & 15, b = blk >> 6;
  int tid = threadIdx.x;
  int p = tid >> 2, q = tid & 3;
  int nbase = g * 32 + q * 8;
  int xoff = h * 64 + p;
  const float* base = xbc + (long)b * LTOK * CDIM;
  const float* dtp = dt + (long)b * LTOK * NHEAD + h;
  const float* dAp = dA + (long)b * LTOK * NHEAD + h;
  float* Ybase = Y + (long)b * LTOK * DIN + h * 64 + p;
  float s[8];
#pragma unroll
  for (int j = 0; j < 8; ++j) s[j] = 0.f;

  auto step = [&](const SD& d, int t) {
    float u = d.dtv * d.x;
    float y = 0.f;
#pragma unroll
    for (int j = 0; j < 8; ++j) {
      s[j] = fmaf(s[j], d.dAv, u * d.Bv[j]);
      y = fmaf(d.Cv[j], s[j], y);
    }
    y += __shfl_xor(y, 1, 64);
    y += __shfl_xor(y, 2, 64);
    if (q == 0 && t < LTOK) atomicAdd(Ybase + (long)t * DIN, y);
  };

  SD d0 = scan_load(base, dtp, dAp, 0, nbase, xoff);
  SD d1 = scan_load(base, dtp, dAp, 1, nbase, xoff);
  SD d2;
  for (int t = 0; t < 1026; t += 3) {           // 342 iterations, covers t=0..1025
    d2 = scan_load(base, dtp, dAp, t + 2, nbase, xoff);
    step(d0, t);
    d0 = scan_load(base, dtp, dAp, t + 3, nbase, xoff);
    step(d1, t + 1);
    d1 = scan_load(base, dtp, dAp, t + 4, nbase, xoff);
    step(d2, t + 2);
  }
}

// ---------------- y(+D*x) + gate silu(z) + RMSNorm, in place on Y ----------------
__global__ __launch_bounds__(256) void k_gaterms(float* __restrict__ Y,
                                                 const float* __restrict__ xbc,
                                                 const float* __restrict__ zx,
                                                 const float* __restrict__ Dv,
                                                 const float* __restrict__ rmsw) {
  long r = blockIdx.x;                   // 0..2049
  int tid = threadIdx.x;
  int e = tid * 4;
  int h = tid >> 4;
  float4 a = *(const float4*)(Y + r * DIN + e);
  const float4 xv = *(const float4*)(xbc + r * CDIM + e);
  const float4 zv = *(const float4*)(zx + r * EPROJ + e);
  float Dh = Dv[h];
  float y0 = a.x + Dh * xv.x, y1 = a.y + Dh * xv.y;
  float y2 = a.z + Dh * xv.z, y3 = a.w + Dh * xv.w;
  float g0 = y0 * (zv.x / (1.f + expf(-zv.x)));
  float g1 = y1 * (zv.y / (1.f + expf(-zv.y)));
  float g2 = y2 * (zv.z / (1.f + expf(-zv.z)));
  float g3 = y3 * (zv.w / (1.f + expf(-zv.w)));
  __shared__ float red[256];
  red[tid] = g0*g0 + g1*g1 + g2*g2 + g3*g3;
  __syncthreads();
  for (int st = 128; st; st >>= 1) {
    if (tid < st) red[tid] += red[tid + st];
    __syncthreads();
  }
  float scale = rsqrtf(red[0] * (1.0f / 1024.0f) + 1e-5f);
  float4 rw = *(const float4*)(rmsw + e);
  float4 o;
  o.x = g0 * scale * rw.x; o.y = g1 * scale * rw.y;
  o.z = g2 * scale * rw.z; o.w = g3 * scale * rw.w;
  *(float4*)(Y + r * DIN + e) = o;
}

// ---------------- final LayerNorm -> f32 out ----------------
__global__ __launch_bounds__(256) void k_ln(const float* __restrict__ outg,
                                            const float* __restrict__ lng,
                                            const float* __restrict__ lnb,
                                            float* __restrict__ out) {
  int r = blockIdx.x;                    // 0..513 (b*257 + j)
  int tid = threadIdx.x;
  const float2 v = *(const float2*)(outg + (long)r * DM + tid * 2);
  __shared__ float red[256];
  red[tid] = v.x + v.y;
  __syncthreads();
  for (int st = 128; st; st >>= 1) { if (tid < st) red[tid] += red[tid + st]; __syncthreads(); }
  float mu = red[0] * (1.0f / 512.0f);
  __syncthreads();
  float dx = v.x - mu, dy = v.y - mu;
  red[tid] = dx * dx + dy * dy;
  __syncthreads();
  for (int st = 128; st; st >>= 1) { if (tid < st) red[tid] += red[tid + st]; __syncthreads(); }
  float sc = rsqrtf(red[0] * (1.0f / 512.0f) + 1e-5f);
  int c = tid * 2;
  out[(long)r * DM + c]     = dx * sc * lng[c] + lnb[c];
  out[(long)r * DM + c + 1] = dy * sc * lng[c + 1] + lnb[c + 1];
}

// ---------------- launch ----------------
extern "C" void kernel_launch(void* const* d_in, const int* in_sizes, int n_in,
                              void* d_out, int out_size, void* d_ws, size_t ws_size,
                              hipStream_t stream) {
  float* ws = (float*)d_ws;
  float* out = (float*)d_out;
  int* rowidx = (int*)(ws + O_RIDX);
  InPtrs ip;
  for (int i = 0; i < 14; ++i) ip.p[i] = d_in[i];

  hipLaunchKernelGGL(k_convert, dim3(14), dim3(256), 0, stream, ip, ws);
  hipLaunchKernelGGL(k_rng, dim3(2), dim3(1024), 0, stream, out, rowidx);
  hipLaunchKernelGGL(k_im2col, dim3(2048), dim3(192), 0, stream, ws + O_CX, ws + O_X3);
  hipLaunchKernelGGL(k_clsrow, dim3(2), dim3(512), 0, stream, ws + O_CLS, ws + O_H);
  // conv-embed GEMM: (2048 x 192) @ (512 x 192)^T + bias -> H (row remap inserts cls gap)
  hipLaunchKernelGGL(k_sgemm, dim3(8, 32), dim3(256), 0, stream,
                     ws + O_X3, ws + O_CW, ws + O_H, ws + O_CB, (const int*)nullptr,
                     2048, 512, 192, 512, 1);
  // in_proj GEMM: (2050 x 512) @ (2320 x 512)^T -> zxbcdt
  hipLaunchKernelGGL(k_sgemm, dim3(37, 33), dim3(256), 0, stream,
                     ws + O_H, ws + O_IPW, ws + O_ZX, (const float*)nullptr, (const int*)nullptr,
                     2050, 2320, 512, 2320, 0);
  hipLaunchKernelGGL(k_conv1d, dim3(2050), dim3(256), 0, stream,
                     ws + O_ZX, ws + O_C1W, ws + O_C1B, ws + O_XBC);
  hipLaunchKernelGGL(k_dtda, dim3(129), dim3(256), 0, stream,
                     ws + O_ZX, ws + O_DTB, ws + O_ALOG, ws + O_DT, ws + O_DA);
  hipLaunchKernelGGL(k_zeroY, dim3(2050), dim3(256), 0, stream, ws + O_Y);
  hipLaunchKernelGGL(k_scan, dim3(128), dim3(256), 0, stream,
                     ws + O_XBC, ws + O_DT, ws + O_DA, ws + O_Y);
  hipLaunchKernelGGL(k_gaterms, dim3(2050), dim3(256), 0, stream,
                     ws + O_Y, ws + O_XBC, ws + O_ZX, ws + O_DV, ws + O_RMSW);
  // out_proj GEMM on gathered rows only: (514 x 1024) @ (512 x 1024)^T -> outg
  hipLaunchKernelGGL(k_sgemm, dim3(8, 9), dim3(256), 0, stream,
                     ws + O_Y, ws + O_OPW, ws + O_OUTG, (const float*)nullptr, rowidx,
                     514, 512, 1024, 512, 0);
  hipLaunchKernelGGL(k_ln, dim3(514), dim3(256), 0, stream,
                     ws + O_OUTG, ws + O_LNG, ws + O_LNB, out);
}

// Round 4
// 736.065 us; speedup vs baseline: 2.7096x; 2.7096x over previous
//
#include <hip/hip_runtime.h>
#include <hip/hip_bf16.h>
#include <stdint.h>

// ---------------- problem constants ----------------
#define LTOK  1025      // 1024 body + 1 cls
#define NROWS 2050      // B * LTOK
#define DM    512
#define DIN   1024
#define DST   128
#define NHEAD 16
#define HDIM  64
#define CDIM  1280      // DIN + 2*DST
#define EPROJ 2320      // 2*DIN + 2*DST + NHEAD

// ---------------- workspace layout (float offsets), total 11,760,032 floats = 47.0 MB ----------------
#define O_RIDX   0          // int32 x 514 (reserve 1024)
#define O_CB     1024
#define O_CLS    1536
#define O_C1B    2048
#define O_DTB    3328
#define O_ALOG   3344
#define O_DV     3360
#define O_RMSW   3376
#define O_LNG    4400
#define O_LNB    4912
#define O_CW     5440
#define O_IPW    103744
#define O_OPW    1291584
#define O_C1W    1815872
#define O_CX     1820992
#define O_ZX     1952064
#define O_XBC    6708064
#define O_DT     9332064
#define O_DA     9364864
#define O_Y      9397664    // 2,099,200 floats; overlays H and X3 (dead after in_proj)
#define O_H      9397664    // 1,049,600
#define O_X3     10447264   // 393,216
#define O_OUTG   11496864   // 263,168 -> ends 11,760,032

// ---------------- output layout (FLOAT32 elements — harness reads f32) ----------------
#define OO_MASK 263168      // after x_out (2*257*512)
#define OO_IDR  265216
#define OO_IDK  267264

struct InPtrs { const void* p[14]; };

// ---------------- input dtype detect + convert to f32 ----------------
__device__ int detect_is_f32(const uint32_t* w, int nelem) {
  int nw = nelem / 2; if (nw > 16) nw = 16;
  int insane = 0, lozero = 0, anynz = 0;
  for (int i = 0; i < nw; ++i) {
    uint32_t word = w[i];
    if (word != 0u) anynz = 1;
    uint32_t lo = word & 0xffffu;
    if (lo == 0u) { lozero++; continue; }
    float v = __uint_as_float(lo << 16);
    float a = fabsf(v);
    if (!(a >= 1e-8f && a <= 1e4f)) insane++;   // NaN fails the range check too
  }
  if (insane >= 2) return 1;                    // f32: low halves are mantissa noise
  if (lozero == nw && anynz) return 1;          // f32 of exact powers (e.g. all-ones)
  return 0;                                     // bf16 (or all zeros; identical either way)
}

// Parallel convert: grid (chunks, 14), 1024 elements per block, vectorized x4.
// All sizes are multiples of 4 and all dst offsets multiples of 16 floats.
__global__ __launch_bounds__(256) void k_convert(InPtrs ptrs, float* ws) {
  static const int sizes[14] = {131072, 98304, 512, 512, 1187840, 5120, 1280,
                                16, 16, 16, 1024, 524288, 512, 512};
  static const int offs[14]  = {O_CX, O_CW, O_CB, O_CLS, O_IPW, O_C1W, O_C1B,
                                O_DTB, O_ALOG, O_DV, O_RMSW, O_OPW, O_LNG, O_LNB};
  int t = blockIdx.y;
  int n = sizes[t];
  const uint32_t* w = (const uint32_t*)ptrs.p[t];
  __shared__ int sf;
  if (threadIdx.x == 0) sf = detect_is_f32(w, n);
  __syncthreads();
  int base = (blockIdx.x * 256 + threadIdx.x) * 4;
  if (base >= n) return;
  float* dst = ws + offs[t];
  if (sf) {
    *(float4*)(dst + base) = *(const float4*)((const float*)w + base);
  } else {
    const uint32_t* s = w + (base >> 1);        // 2 bf16 per word
    uint32_t w0 = s[0], w1 = s[1];
    float4 o;
    o.x = __uint_as_float((w0 & 0xffffu) << 16);
    o.y = __uint_as_float(w0 & 0xffff0000u);
    o.z = __uint_as_float((w1 & 0xffffu) << 16);
    o.w = __uint_as_float(w1 & 0xffff0000u);
    *(float4*)(dst + base) = o;
  }
}

// ---------------- threefry2x32 (JAX-compatible) ----------------
__device__ __forceinline__ uint32_t rotl32(uint32_t v, int d) {
  return (v << d) | (v >> (32 - d));
}
__device__ void threefry2x32(uint32_t k0, uint32_t k1, uint32_t c0, uint32_t c1,
                             uint32_t& o0, uint32_t& o1) {
  uint32_t ks0 = k0, ks1 = k1, ks2 = 0x1BD11BDAu ^ k0 ^ k1;
  uint32_t x0 = c0 + ks0, x1 = c1 + ks1;
#define TF_R4(a,b,c,d) \
  x0 += x1; x1 = rotl32(x1,a); x1 ^= x0; \
  x0 += x1; x1 = rotl32(x1,b); x1 ^= x0; \
  x0 += x1; x1 = rotl32(x1,c); x1 ^= x0; \
  x0 += x1; x1 = rotl32(x1,d); x1 ^= x0;
  TF_R4(13,15,26,6)  x0 += ks1; x1 += ks2 + 1u;
  TF_R4(17,29,16,24) x0 += ks2; x1 += ks0 + 2u;
  TF_R4(13,15,26,6)  x0 += ks0; x1 += ks1 + 3u;
  TF_R4(17,29,16,24) x0 += ks1; x1 += ks2 + 4u;
  TF_R4(13,15,26,6)  x0 += ks2; x1 += ks0 + 5u;
#undef TF_R4
  o0 = x0; o1 = x1;
}

// RNG + stable argsort ranks + mask/ids outputs + gather row list. All f32 stores.
// Partitionable threefry stream (current JAX default): bits = o0^o1, count = (0, flat idx).
__global__ __launch_bounds__(1024) void k_rng(float* out, int* rowidx) {
  int b = blockIdx.x;
  int i = threadIdx.x;
  __shared__ float vals[1024];
  uint32_t fk0, fk1;
  threefry2x32(0u, 0u, 0u, 1u, fk0, fk1);          // fold_in(key(0), 1)
  uint32_t o0, o1;
  threefry2x32(fk0, fk1, 0u, (uint32_t)(b * 1024 + i), o0, o1);
  uint32_t bits = o0 ^ o1;
  float v = __uint_as_float((bits >> 9) | 0x3f800000u) - 1.0f;
  vals[i] = v;
  __syncthreads();
  int r = 0;
  for (int j = 0; j < 1024; ++j) {
    float vj = vals[j];
    r += (vj < v || (vj == v && j < i)) ? 1 : 0;   // stable ascending rank
  }
  out[OO_IDR + b * 1024 + i] = (float)r;
  out[OO_MASK + b * 1024 + i] = (r < 256) ? 0.0f : 1.0f;
  if (r < 256) {
    out[OO_IDK + b * 256 + r] = (float)i;
    rowidx[b * 257 + r] = b * LTOK + i;            // kept body rows
  }
  if (i == 0) rowidx[b * 257 + 256] = b * LTOK + 1024;  // cls row
}

// ---------------- im2col for conv-embed ----------------
__global__ void k_im2col(const float* __restrict__ x, float* __restrict__ X3) {
  int r = blockIdx.x;                 // 0..2047  (b*1024+t)
  int b = r >> 10, t = r & 1023;
  int j = threadIdx.x;                // blockDim = 192
  if (j < 192) {
    int i = j / 3, k = j % 3;
    int tt = t + k - 1;
    float v = (tt >= 0 && tt < 1024) ? x[((long)(b * 1024 + tt)) * 64 + i] : 0.f;
    X3[(long)r * 192 + j] = v;
  }
}

__global__ void k_clsrow(const float* __restrict__ cls, float* __restrict__ h) {
  h[((long)(blockIdx.x * LTOK + 1024)) * DM + threadIdx.x] = cls[threadIdx.x];
}

// ---------------- generic fp32 SGEMM: C = A @ Bw^T (+bias) ----------------
__global__ __launch_bounds__(256) void k_sgemm(
    const float* __restrict__ A, const float* __restrict__ Bw,
    float* __restrict__ C, const float* __restrict__ bias,
    const int* __restrict__ rowmap, int M, int N, int K, int ldc, int cmode) {
  __shared__ float As[16][64];
  __shared__ float Bs[16][64];
  int tid = threadIdx.x;
  int bm = blockIdx.y << 6, bn = blockIdx.x << 6;
  int tx = tid & 15, ty = tid >> 4;
  int arow = tid >> 2, acol = (tid & 3) << 2;
  int gm = bm + arow, gn = bn + arow;
  bool mok = gm < M, nok = gn < N;
  long aoff = 0;
  if (mok) aoff = (long)(rowmap ? rowmap[gm] : gm) * K;
  long boff = (long)gn * K;
  float acc[4][4] = {};
  for (int k0 = 0; k0 < K; k0 += 16) {
    float4 av = make_float4(0.f,0.f,0.f,0.f), bv = make_float4(0.f,0.f,0.f,0.f);
    if (mok) av = *(const float4*)(A + aoff + k0 + acol);
    if (nok) bv = *(const float4*)(Bw + boff + k0 + acol);
    __syncthreads();
    As[acol+0][arow]=av.x; As[acol+1][arow]=av.y; As[acol+2][arow]=av.z; As[acol+3][arow]=av.w;
    Bs[acol+0][arow]=bv.x; Bs[acol+1][arow]=bv.y; Bs[acol+2][arow]=bv.z; Bs[acol+3][arow]=bv.w;
    __syncthreads();
#pragma unroll
    for (int kk = 0; kk < 16; ++kk) {
      float a[4], bb[4];
#pragma unroll
      for (int i = 0; i < 4; ++i) a[i] = As[kk][ty*4+i];
#pragma unroll
      for (int j = 0; j < 4; ++j) bb[j] = Bs[kk][tx*4+j];
#pragma unroll
      for (int i = 0; i < 4; ++i)
#pragma unroll
        for (int j = 0; j < 4; ++j) acc[i][j] = fmaf(a[i], bb[j], acc[i][j]);
    }
  }
#pragma unroll
  for (int i = 0; i < 4; ++i) {
    int r = bm + ty*4 + i;
    if (r >= M) continue;
    long crow = (cmode == 1) ? (long)((r >> 10) * LTOK + (r & 1023)) : (long)r;
#pragma unroll
    for (int j = 0; j < 4; ++j) {
      int c = bn + tx*4 + j;
      if (c < N) {
        float v = acc[i][j];
        if (bias) v += bias[c];
        C[crow * ldc + c] = v;
      }
    }
  }
}

// ---------------- depthwise causal conv(4) + silu ----------------
__global__ __launch_bounds__(256) void k_conv1d(const float* __restrict__ zx,
                                                const float* __restrict__ w,
                                                const float* __restrict__ bias,
                                                float* __restrict__ xbc) {
  long r = blockIdx.x;                 // 0..2049
  int b = (int)(r / LTOK), t = (int)(r % LTOK);
  for (int c = threadIdx.x; c < CDIM; c += 256) {
    float acc = bias[c];
    const float* wp = w + c * 4;
#pragma unroll
    for (int k = 0; k < 4; ++k) {
      int tt = t - 3 + k;
      if (tt >= 0)
        acc = fmaf(wp[k], zx[((long)(b * LTOK + tt)) * EPROJ + DIN + c], acc);
    }
    xbc[r * CDIM + c] = acc / (1.f + expf(-acc));   // silu
  }
}

// ---------------- dt = softplus(logit + bias), dA = exp(dt * -exp(A_log)) ----------------
__global__ void k_dtda(const float* __restrict__ zx, const float* __restrict__ dtb,
                       const float* __restrict__ alog, float* __restrict__ dt,
                       float* __restrict__ dA) {
  int idx = blockIdx.x * 256 + threadIdx.x;
  if (idx >= NROWS * NHEAD) return;
  int r = idx >> 4, h = idx & 15;
  float xv = zx[(long)r * EPROJ + (EPROJ - NHEAD) + h] + dtb[h];
  float dtv = (xv > 20.f) ? xv : log1pf(expf(xv));
  dt[idx] = dtv;
  dA[idx] = expf(dtv * (-expf(alog[h])));
}

// ---------------- zero the Y accumulator ----------------
__global__ __launch_bounds__(256) void k_zeroY(float* __restrict__ Y) {
  long r = blockIdx.x;                 // 0..2049
  float4 z = make_float4(0.f, 0.f, 0.f, 0.f);
  *(float4*)(Y + r * DIN + threadIdx.x * 4) = z;
}

// ---------------- sequential SSM scan (atomic accumulate into Y) ----------------
// grid 128 = (b, h, g); g = n-group of 32 states. thread: p = tid>>2 (0..63),
// q = tid&3 owns 8 n's. Depth-2 software-pipelined loads; y reduced over q via shfl.
struct SD { float Bv[8], Cv[8], x, dtv, dAv; };

__device__ __forceinline__ SD scan_load(const float* base, const float* dtp,
                                        const float* dAp, int t, int nbase, int xoff) {
  SD d;
  if (t < LTOK) {
    const float* row = base + (long)t * CDIM;
    float4 b0 = *(const float4*)(row + DIN + nbase);
    float4 b1 = *(const float4*)(row + DIN + nbase + 4);
    float4 c0 = *(const float4*)(row + DIN + DST + nbase);
    float4 c1 = *(const float4*)(row + DIN + DST + nbase + 4);
    d.Bv[0]=b0.x; d.Bv[1]=b0.y; d.Bv[2]=b0.z; d.Bv[3]=b0.w;
    d.Bv[4]=b1.x; d.Bv[5]=b1.y; d.Bv[6]=b1.z; d.Bv[7]=b1.w;
    d.Cv[0]=c0.x; d.Cv[1]=c0.y; d.Cv[2]=c0.z; d.Cv[3]=c0.w;
    d.Cv[4]=c1.x; d.Cv[5]=c1.y; d.Cv[6]=c1.z; d.Cv[7]=c1.w;
    d.x = row[xoff];
    d.dtv = dtp[(long)t * NHEAD];
    d.dAv = dAp[(long)t * NHEAD];
  } else {
#pragma unroll
    for (int j = 0; j < 8; ++j) { d.Bv[j] = 0.f; d.Cv[j] = 0.f; }
    d.x = 0.f; d.dtv = 0.f; d.dAv = 0.f;
  }
  return d;
}

__global__ __launch_bounds__(256) void k_scan(const float* __restrict__ xbc,
                                              const float* __restrict__ dt,
                                              const float* __restrict__ dA,
                                              float* __restrict__ Y) {
  int blk = blockIdx.x;
  int g = blk & 3, h = (blk >> 2) & 15, b = blk >> 6;
  int tid = threadIdx.x;
  int p = tid >> 2, q = tid & 3;
  int nbase = g * 32 + q * 8;
  int xoff = h * 64 + p;
  const float* base = xbc + (long)b * LTOK * CDIM;
  const float* dtp = dt + (long)b * LTOK * NHEAD + h;
  const float* dAp = dA + (long)b * LTOK * NHEAD + h;
  float* Ybase = Y + (long)b * LTOK * DIN + h * 64 + p;
  float s[8];
#pragma unroll
  for (int j = 0; j < 8; ++j) s[j] = 0.f;

  auto step = [&](const SD& d, int t) {
    float u = d.dtv * d.x;
    float y = 0.f;
#pragma unroll
    for (int j = 0; j < 8; ++j) {
      s[j] = fmaf(s[j], d.dAv, u * d.Bv[j]);
      y = fmaf(d.Cv[j], s[j], y);
    }
    y += __shfl_xor(y, 1, 64);
    y += __shfl_xor(y, 2, 64);
    if (q == 0 && t < LTOK) atomicAdd(Ybase + (long)t * DIN, y);
  };

  SD d0 = scan_load(base, dtp, dAp, 0, nbase, xoff);
  SD d1 = scan_load(base, dtp, dAp, 1, nbase, xoff);
  SD d2;
  for (int t = 0; t < 1026; t += 3) {           // 342 iterations, covers t=0..1025
    d2 = scan_load(base, dtp, dAp, t + 2, nbase, xoff);
    step(d0, t);
    d0 = scan_load(base, dtp, dAp, t + 3, nbase, xoff);
    step(d1, t + 1);
    d1 = scan_load(base, dtp, dAp, t + 4, nbase, xoff);
    step(d2, t + 2);
  }
}

// ---------------- y(+D*x) + gate silu(z) + RMSNorm, in place on Y ----------------
__global__ __launch_bounds__(256) void k_gaterms(float* __restrict__ Y,
                                                 const float* __restrict__ xbc,
                                                 const float* __restrict__ zx,
                                                 const float* __restrict__ Dv,
                                                 const float* __restrict__ rmsw) {
  long r = blockIdx.x;                   // 0..2049
  int tid = threadIdx.x;
  int e = tid * 4;
  int h = tid >> 4;
  float4 a = *(const float4*)(Y + r * DIN + e);
  const float4 xv = *(const float4*)(xbc + r * CDIM + e);
  const float4 zv = *(const float4*)(zx + r * EPROJ + e);
  float Dh = Dv[h];
  float y0 = a.x + Dh * xv.x, y1 = a.y + Dh * xv.y;
  float y2 = a.z + Dh * xv.z, y3 = a.w + Dh * xv.w;
  float g0 = y0 * (zv.x / (1.f + expf(-zv.x)));
  float g1 = y1 * (zv.y / (1.f + expf(-zv.y)));
  float g2 = y2 * (zv.z / (1.f + expf(-zv.z)));
  float g3 = y3 * (zv.w / (1.f + expf(-zv.w)));
  __shared__ float red[256];
  red[tid] = g0*g0 + g1*g1 + g2*g2 + g3*g3;
  __syncthreads();
  for (int st = 128; st; st >>= 1) {
    if (tid < st) red[tid] += red[tid + st];
    __syncthreads();
  }
  float scale = rsqrtf(red[0] * (1.0f / 1024.0f) + 1e-5f);
  float4 rw = *(const float4*)(rmsw + e);
  float4 o;
  o.x = g0 * scale * rw.x; o.y = g1 * scale * rw.y;
  o.z = g2 * scale * rw.z; o.w = g3 * scale * rw.w;
  *(float4*)(Y + r * DIN + e) = o;
}

// ---------------- final LayerNorm -> f32 out ----------------
__global__ __launch_bounds__(256) void k_ln(const float* __restrict__ outg,
                                            const float* __restrict__ lng,
                                            const float* __restrict__ lnb,
                                            float* __restrict__ out) {
  int r = blockIdx.x;                    // 0..513 (b*257 + j)
  int tid = threadIdx.x;
  const float2 v = *(const float2*)(outg + (long)r * DM + tid * 2);
  __shared__ float red[256];
  red[tid] = v.x + v.y;
  __syncthreads();
  for (int st = 128; st; st >>= 1) { if (tid < st) red[tid] += red[tid + st]; __syncthreads(); }
  float mu = red[0] * (1.0f / 512.0f);
  __syncthreads();
  float dx = v.x - mu, dy = v.y - mu;
  red[tid] = dx * dx + dy * dy;
  __syncthreads();
  for (int st = 128; st; st >>= 1) { if (tid < st) red[tid] += red[tid + st]; __syncthreads(); }
  float sc = rsqrtf(red[0] * (1.0f / 512.0f) + 1e-5f);
  int c = tid * 2;
  out[(long)r * DM + c]     = dx * sc * lng[c] + lnb[c];
  out[(long)r * DM + c + 1] = dy * sc * lng[c + 1] + lnb[c + 1];
}

// ---------------- launch ----------------
extern "C" void kernel_launch(void* const* d_in, const int* in_sizes, int n_in,
                              void* d_out, int out_size, void* d_ws, size_t ws_size,
                              hipStream_t stream) {
  float* ws = (float*)d_ws;
  float* out = (float*)d_out;
  int* rowidx = (int*)(ws + O_RIDX);
  InPtrs ip;
  for (int i = 0; i < 14; ++i) ip.p[i] = d_in[i];

  // 1160 chunks covers the largest tensor (1,187,840 / 1024)
  hipLaunchKernelGGL(k_convert, dim3(1160, 14), dim3(256), 0, stream, ip, ws);
  hipLaunchKernelGGL(k_rng, dim3(2), dim3(1024), 0, stream, out, rowidx);
  hipLaunchKernelGGL(k_im2col, dim3(2048), dim3(192), 0, stream, ws + O_CX, ws + O_X3);
  hipLaunchKernelGGL(k_clsrow, dim3(2), dim3(512), 0, stream, ws + O_CLS, ws + O_H);
  // conv-embed GEMM: (2048 x 192) @ (512 x 192)^T + bias -> H (row remap inserts cls gap)
  hipLaunchKernelGGL(k_sgemm, dim3(8, 32), dim3(256), 0, stream,
                     ws + O_X3, ws + O_CW, ws + O_H, ws + O_CB, (const int*)nullptr,
                     2048, 512, 192, 512, 1);
  // in_proj GEMM: (2050 x 512) @ (2320 x 512)^T -> zxbcdt
  hipLaunchKernelGGL(k_sgemm, dim3(37, 33), dim3(256), 0, stream,
                     ws + O_H, ws + O_IPW, ws + O_ZX, (const float*)nullptr, (const int*)nullptr,
                     2050, 2320, 512, 2320, 0);
  hipLaunchKernelGGL(k_conv1d, dim3(2050), dim3(256), 0, stream,
                     ws + O_ZX, ws + O_C1W, ws + O_C1B, ws + O_XBC);
  hipLaunchKernelGGL(k_dtda, dim3(129), dim3(256), 0, stream,
                     ws + O_ZX, ws + O_DTB, ws + O_ALOG, ws + O_DT, ws + O_DA);
  hipLaunchKernelGGL(k_zeroY, dim3(2050), dim3(256), 0, stream, ws + O_Y);
  hipLaunchKernelGGL(k_scan, dim3(128), dim3(256), 0, stream,
                     ws + O_XBC, ws + O_DT, ws + O_DA, ws + O_Y);
  hipLaunchKernelGGL(k_gaterms, dim3(2050), dim3(256), 0, stream,
                     ws + O_Y, ws + O_XBC, ws + O_ZX, ws + O_DV, ws + O_RMSW);
  // out_proj GEMM on gathered rows only: (514 x 1024) @ (512 x 1024)^T -> outg
  hipLaunchKernelGGL(k_sgemm, dim3(8, 9), dim3(256), 0, stream,
                     ws + O_Y, ws + O_OPW, ws + O_OUTG, (const float*)nullptr, rowidx,
                     514, 512, 1024, 512, 0);
  hipLaunchKernelGGL(k_ln, dim3(514), dim3(256), 0, stream,
                     ws + O_OUTG, ws + O_LNG, ws + O_LNB, out);
}

// Round 5
// 655.724 us; speedup vs baseline: 3.0416x; 1.1225x over previous
//
#include <hip/hip_runtime.h>
#include <hip/hip_bf16.h>
#include <stdint.h>

// ---------------- problem constants ----------------
#define LTOK  1025      // 1024 body + 1 cls
#define NROWS 2050      // B * LTOK
#define DM    512
#define DIN   1024
#define DST   128
#define NHEAD 16
#define HDIM  64
#define CDIM  1280      // DIN + 2*DST
#define EPROJ 2320      // 2*DIN + 2*DST + NHEAD
#define QC    64        // SSD chunk length
#define NCH   17        // ceil(1025/64)

// ---------------- workspace layout (float offsets), total 16,251,296 floats = 65.0 MB ----------------
#define O_RIDX   0          // int32 x 514 (reserve 1024)
#define O_CB     1024
#define O_CLS    1536
#define O_C1B    2048
#define O_DTB    3328
#define O_ALOG   3344
#define O_DV     3360
#define O_RMSW   3376
#define O_LNG    4400
#define O_LNB    4912
#define O_CW     5440
#define O_IPW    103744
#define O_OPW    1291584
#define O_C1W    1815872
#define O_CX     1820992
#define O_ZX     1952064
#define O_XBC    6708064
#define O_DT     9332064
#define O_LGA    9364864    // log(dA) = dt * (-exp(A_log))
#define O_Y      9397664    // 2,099,200 floats; overlays H and X3 (dead after in_proj)
#define O_H      9397664    // 1,049,600
#define O_X3     10447264   // 393,216
#define O_OUTG   11496864   // 263,168
#define O_SL     11760032   // chunk-local states: 32*17*8192 = 4,456,448
#define O_CLA    16216480   // within-chunk cumsum logdA: 32*17*64 = 34,816 -> ends 16,251,296

// ---------------- output layout (FLOAT32 elements) ----------------
#define OO_MASK 263168
#define OO_IDR  265216
#define OO_IDK  267264

struct InPtrs { const void* p[14]; };

// ---------------- input dtype detect + convert to f32 ----------------
__device__ int detect_is_f32(const uint32_t* w, int nelem) {
  int nw = nelem / 2; if (nw > 16) nw = 16;
  int insane = 0, lozero = 0, anynz = 0;
  for (int i = 0; i < nw; ++i) {
    uint32_t word = w[i];
    if (word != 0u) anynz = 1;
    uint32_t lo = word & 0xffffu;
    if (lo == 0u) { lozero++; continue; }
    float v = __uint_as_float(lo << 16);
    float a = fabsf(v);
    if (!(a >= 1e-8f && a <= 1e4f)) insane++;
  }
  if (insane >= 2) return 1;
  if (lozero == nw && anynz) return 1;
  return 0;
}

__global__ __launch_bounds__(256) void k_convert(InPtrs ptrs, float* ws) {
  static const int sizes[14] = {131072, 98304, 512, 512, 1187840, 5120, 1280,
                                16, 16, 16, 1024, 524288, 512, 512};
  static const int offs[14]  = {O_CX, O_CW, O_CB, O_CLS, O_IPW, O_C1W, O_C1B,
                                O_DTB, O_ALOG, O_DV, O_RMSW, O_OPW, O_LNG, O_LNB};
  int t = blockIdx.y;
  int n = sizes[t];
  const uint32_t* w = (const uint32_t*)ptrs.p[t];
  __shared__ int sf;
  if (threadIdx.x == 0) sf = detect_is_f32(w, n);
  __syncthreads();
  int base = (blockIdx.x * 256 + threadIdx.x) * 4;
  if (base >= n) return;
  float* dst = ws + offs[t];
  if (sf) {
    *(float4*)(dst + base) = *(const float4*)((const float*)w + base);
  } else {
    const uint32_t* s = w + (base >> 1);
    uint32_t w0 = s[0], w1 = s[1];
    float4 o;
    o.x = __uint_as_float((w0 & 0xffffu) << 16);
    o.y = __uint_as_float(w0 & 0xffff0000u);
    o.z = __uint_as_float((w1 & 0xffffu) << 16);
    o.w = __uint_as_float(w1 & 0xffff0000u);
    *(float4*)(dst + base) = o;
  }
}

// ---------------- threefry2x32 (JAX-compatible) ----------------
__device__ __forceinline__ uint32_t rotl32(uint32_t v, int d) {
  return (v << d) | (v >> (32 - d));
}
__device__ void threefry2x32(uint32_t k0, uint32_t k1, uint32_t c0, uint32_t c1,
                             uint32_t& o0, uint32_t& o1) {
  uint32_t ks0 = k0, ks1 = k1, ks2 = 0x1BD11BDAu ^ k0 ^ k1;
  uint32_t x0 = c0 + ks0, x1 = c1 + ks1;
#define TF_R4(a,b,c,d) \
  x0 += x1; x1 = rotl32(x1,a); x1 ^= x0; \
  x0 += x1; x1 = rotl32(x1,b); x1 ^= x0; \
  x0 += x1; x1 = rotl32(x1,c); x1 ^= x0; \
  x0 += x1; x1 = rotl32(x1,d); x1 ^= x0;
  TF_R4(13,15,26,6)  x0 += ks1; x1 += ks2 + 1u;
  TF_R4(17,29,16,24) x0 += ks2; x1 += ks0 + 2u;
  TF_R4(13,15,26,6)  x0 += ks0; x1 += ks1 + 3u;
  TF_R4(17,29,16,24) x0 += ks1; x1 += ks2 + 4u;
  TF_R4(13,15,26,6)  x0 += ks2; x1 += ks0 + 5u;
#undef TF_R4
  o0 = x0; o1 = x1;
}

__global__ __launch_bounds__(1024) void k_rng(float* out, int* rowidx) {
  int b = blockIdx.x;
  int i = threadIdx.x;
  __shared__ float vals[1024];
  uint32_t fk0, fk1;
  threefry2x32(0u, 0u, 0u, 1u, fk0, fk1);
  uint32_t o0, o1;
  threefry2x32(fk0, fk1, 0u, (uint32_t)(b * 1024 + i), o0, o1);
  uint32_t bits = o0 ^ o1;
  float v = __uint_as_float((bits >> 9) | 0x3f800000u) - 1.0f;
  vals[i] = v;
  __syncthreads();
  int r = 0;
  for (int j = 0; j < 1024; ++j) {
    float vj = vals[j];
    r += (vj < v || (vj == v && j < i)) ? 1 : 0;
  }
  out[OO_IDR + b * 1024 + i] = (float)r;
  out[OO_MASK + b * 1024 + i] = (r < 256) ? 0.0f : 1.0f;
  if (r < 256) {
    out[OO_IDK + b * 256 + r] = (float)i;
    rowidx[b * 257 + r] = b * LTOK + i;
  }
  if (i == 0) rowidx[b * 257 + 256] = b * LTOK + 1024;
}

// ---------------- im2col for conv-embed ----------------
__global__ void k_im2col(const float* __restrict__ x, float* __restrict__ X3) {
  int r = blockIdx.x;
  int b = r >> 10, t = r & 1023;
  int j = threadIdx.x;
  if (j < 192) {
    int i = j / 3, k = j % 3;
    int tt = t + k - 1;
    float v = (tt >= 0 && tt < 1024) ? x[((long)(b * 1024 + tt)) * 64 + i] : 0.f;
    X3[(long)r * 192 + j] = v;
  }
}

__global__ void k_clsrow(const float* __restrict__ cls, float* __restrict__ h) {
  h[((long)(blockIdx.x * LTOK + 1024)) * DM + threadIdx.x] = cls[threadIdx.x];
}

// ---------------- generic fp32 SGEMM: C = A @ Bw^T (+bias) ----------------
__global__ __launch_bounds__(256) void k_sgemm(
    const float* __restrict__ A, const float* __restrict__ Bw,
    float* __restrict__ C, const float* __restrict__ bias,
    const int* __restrict__ rowmap, int M, int N, int K, int ldc, int cmode) {
  __shared__ float As[16][64];
  __shared__ float Bs[16][64];
  int tid = threadIdx.x;
  int bm = blockIdx.y << 6, bn = blockIdx.x << 6;
  int tx = tid & 15, ty = tid >> 4;
  int arow = tid >> 2, acol = (tid & 3) << 2;
  int gm = bm + arow, gn = bn + arow;
  bool mok = gm < M, nok = gn < N;
  long aoff = 0;
  if (mok) aoff = (long)(rowmap ? rowmap[gm] : gm) * K;
  long boff = (long)gn * K;
  float acc[4][4] = {};
  for (int k0 = 0; k0 < K; k0 += 16) {
    float4 av = make_float4(0.f,0.f,0.f,0.f), bv = make_float4(0.f,0.f,0.f,0.f);
    if (mok) av = *(const float4*)(A + aoff + k0 + acol);
    if (nok) bv = *(const float4*)(Bw + boff + k0 + acol);
    __syncthreads();
    As[acol+0][arow]=av.x; As[acol+1][arow]=av.y; As[acol+2][arow]=av.z; As[acol+3][arow]=av.w;
    Bs[acol+0][arow]=bv.x; Bs[acol+1][arow]=bv.y; Bs[acol+2][arow]=bv.z; Bs[acol+3][arow]=bv.w;
    __syncthreads();
#pragma unroll
    for (int kk = 0; kk < 16; ++kk) {
      float a[4], bb[4];
#pragma unroll
      for (int i = 0; i < 4; ++i) a[i] = As[kk][ty*4+i];
#pragma unroll
      for (int j = 0; j < 4; ++j) bb[j] = Bs[kk][tx*4+j];
#pragma unroll
      for (int i = 0; i < 4; ++i)
#pragma unroll
        for (int j = 0; j < 4; ++j) acc[i][j] = fmaf(a[i], bb[j], acc[i][j]);
    }
  }
#pragma unroll
  for (int i = 0; i < 4; ++i) {
    int r = bm + ty*4 + i;
    if (r >= M) continue;
    long crow = (cmode == 1) ? (long)((r >> 10) * LTOK + (r & 1023)) : (long)r;
#pragma unroll
    for (int j = 0; j < 4; ++j) {
      int c = bn + tx*4 + j;
      if (c < N) {
        float v = acc[i][j];
        if (bias) v += bias[c];
        C[crow * ldc + c] = v;
      }
    }
  }
}

// ---------------- depthwise causal conv(4) + silu ----------------
__global__ __launch_bounds__(256) void k_conv1d(const float* __restrict__ zx,
                                                const float* __restrict__ w,
                                                const float* __restrict__ bias,
                                                float* __restrict__ xbc) {
  long r = blockIdx.x;
  int b = (int)(r / LTOK), t = (int)(r % LTOK);
  for (int c = threadIdx.x; c < CDIM; c += 256) {
    float acc = bias[c];
    const float* wp = w + c * 4;
#pragma unroll
    for (int k = 0; k < 4; ++k) {
      int tt = t - 3 + k;
      if (tt >= 0)
        acc = fmaf(wp[k], zx[((long)(b * LTOK + tt)) * EPROJ + DIN + c], acc);
    }
    xbc[r * CDIM + c] = acc / (1.f + expf(-acc));
  }
}

// ---------------- dt = softplus(logit + bias), lga = dt * -exp(A_log) ----------------
__global__ void k_dtda(const float* __restrict__ zx, const float* __restrict__ dtb,
                       const float* __restrict__ alog, float* __restrict__ dt,
                       float* __restrict__ lga) {
  int idx = blockIdx.x * 256 + threadIdx.x;
  if (idx >= NROWS * NHEAD) return;
  int r = idx >> 4, h = idx & 15;
  float xv = zx[(long)r * EPROJ + (EPROJ - NHEAD) + h] + dtb[h];
  float dtv = (xv > 20.f) ? xv : log1pf(expf(xv));
  dt[idx] = dtv;
  lga[idx] = dtv * (-expf(alog[h]));
}

// ---------------- SSD phase 1: per (b,h,chunk) intra-chunk work ----------------
// blk = c + 17*(h + 16*b). Computes Y_intra (direct store), S_loc, clA.
__global__ __launch_bounds__(256) void k_ssd1(const float* __restrict__ xbc,
                                              const float* __restrict__ dt,
                                              const float* __restrict__ lga,
                                              float* __restrict__ Y,
                                              float* __restrict__ SL,
                                              float* __restrict__ CLA) {
  int blk = blockIdx.x;
  int c = blk % NCH;
  int hh = blk / NCH;            // h + 16*b
  int h = hh & 15, b = hh >> 4;
  int tid = threadIdx.x;
  int tx = tid & 15, ty = tid >> 4;

  __shared__ float Bs[64 * 129];
  __shared__ float Cs[64 * 129];
  __shared__ float xs[64 * 65];
  __shared__ float Ms[64 * 65];
  __shared__ float dtw[64], clA[64], wwv[64];

  int t0 = c * QC;
  const float* base = xbc + (long)b * LTOK * CDIM;

  // load B, C chunks (64 x 128 each)
#pragma unroll
  for (int k = 0; k < 32; ++k) {
    int e = tid + k * 256;
    int row = e >> 7, col = e & 127;
    int t = t0 + row;
    float bv = 0.f, cv = 0.f;
    if (t < LTOK) {
      const float* rp = base + (long)t * CDIM;
      bv = rp[DIN + col];
      cv = rp[DIN + DST + col];
    }
    Bs[row * 129 + col] = bv;
    Cs[row * 129 + col] = cv;
  }
  // load x chunk (64 x 64)
#pragma unroll
  for (int k = 0; k < 16; ++k) {
    int e = tid + k * 256;
    int row = e >> 6, col = e & 63;
    int t = t0 + row;
    xs[row * 65 + col] = (t < LTOK) ? base[(long)t * CDIM + h * 64 + col] : 0.f;
  }
  if (tid < 64) {
    int t = t0 + tid;
    dtw[tid] = (t < LTOK) ? dt[((long)(b * LTOK + t)) * NHEAD + h] : 0.f;
    clA[tid] = (t < LTOK) ? lga[((long)(b * LTOK + t)) * NHEAD + h] : 0.f;
  }
  __syncthreads();
  if (tid == 0) {                 // inclusive cumsum of logdA (64 adds, trivial)
    float s = 0.f;
    for (int i = 0; i < 64; ++i) { s += clA[i]; clA[i] = s; }
  }
  __syncthreads();
  float clEnd = clA[63];
  if (tid < 64) {
    wwv[tid] = __expf(clEnd - clA[tid]) * dtw[tid];
    CLA[(long)blk * 64 + tid] = clA[tid];
  }
  __syncthreads();

  // GEMM1: G[t][t'] = C_t . B_t'  (64x64, K=128)
  float acc[4][4] = {};
  for (int n = 0; n < 128; ++n) {
    float cv[4], bv[4];
#pragma unroll
    for (int i = 0; i < 4; ++i) cv[i] = Cs[(ty * 4 + i) * 129 + n];
#pragma unroll
    for (int j = 0; j < 4; ++j) bv[j] = Bs[(tx * 4 + j) * 129 + n];
#pragma unroll
    for (int i = 0; i < 4; ++i)
#pragma unroll
      for (int j = 0; j < 4; ++j) acc[i][j] = fmaf(cv[i], bv[j], acc[i][j]);
  }
  // M[t][t'] = G * exp(clA[t]-clA[t']) * dt[t'] for t'<=t
#pragma unroll
  for (int i = 0; i < 4; ++i) {
    int t = ty * 4 + i;
#pragma unroll
    for (int j = 0; j < 4; ++j) {
      int tp = tx * 4 + j;
      float m = 0.f;
      if (tp <= t) m = acc[i][j] * __expf(clA[t] - clA[tp]) * dtw[tp];
      Ms[t * 65 + tp] = m;
    }
  }
  __syncthreads();

  // GEMM2: Yintra[t][p] = sum_t' M[t][t'] * x[t'][p]   (64x64, K=64)
  float y[4][4] = {};
  for (int tp = 0; tp < 64; ++tp) {
    float mv[4], xv[4];
#pragma unroll
    for (int i = 0; i < 4; ++i) mv[i] = Ms[(ty * 4 + i) * 65 + tp];
#pragma unroll
    for (int j = 0; j < 4; ++j) xv[j] = xs[tp * 65 + tx * 4 + j];
#pragma unroll
    for (int i = 0; i < 4; ++i)
#pragma unroll
      for (int j = 0; j < 4; ++j) y[i][j] = fmaf(mv[i], xv[j], y[i][j]);
  }
#pragma unroll
  for (int i = 0; i < 4; ++i) {
    int t = t0 + ty * 4 + i;
    if (t < LTOK) {
      float* yp = Y + ((long)(b * LTOK + t)) * DIN + h * 64 + tx * 4;
#pragma unroll
      for (int j = 0; j < 4; ++j) yp[j] = y[i][j];
    }
  }

  // GEMM3: Sloc[n][p] = sum_t wwv[t] * B[t][n] * x[t][p]  (128x64, K=64)
  float sacc[8][4] = {};
  for (int t = 0; t < 64; ++t) {
    float w = wwv[t];
    float bv[8], xv[4];
#pragma unroll
    for (int i = 0; i < 8; ++i) bv[i] = Bs[t * 129 + ty * 8 + i] * w;
#pragma unroll
    for (int j = 0; j < 4; ++j) xv[j] = xs[t * 65 + tx * 4 + j];
#pragma unroll
    for (int i = 0; i < 8; ++i)
#pragma unroll
      for (int j = 0; j < 4; ++j) sacc[i][j] = fmaf(bv[i], xv[j], sacc[i][j]);
  }
  float* slp = SL + (long)blk * 8192;
#pragma unroll
  for (int i = 0; i < 8; ++i)
#pragma unroll
    for (int j = 0; j < 4; ++j)
      slp[(ty * 8 + i) * 64 + tx * 4 + j] = sacc[i][j];
}

// ---------------- SSD phase 2: sequential chunk combine + Y_inter ----------------
// grid 64: bx = ph + 2*(h + 16*b); ph = p-half (0/1). S in LDS, 17 chunk iters.
__global__ __launch_bounds__(256) void k_ssd2(const float* __restrict__ xbc,
                                              const float* __restrict__ SL,
                                              const float* __restrict__ CLA,
                                              float* __restrict__ Y) {
  int bx = blockIdx.x;
  int ph = bx & 1;
  int hh = bx >> 1;              // h + 16*b
  int h = hh & 15, b = hh >> 4;
  int tid = threadIdx.x;
  int tx = tid & 15, ty = tid >> 4;

  __shared__ float Cs[64 * 129];
  __shared__ float Ss[128 * 33];
  __shared__ float evec[64];

  // zero state
#pragma unroll
  for (int k = 0; k < 16; ++k) {
    int e = tid + k * 256;
    Ss[(e >> 5) * 33 + (e & 31)] = 0.f;
  }
  const float* base = xbc + (long)b * LTOK * CDIM;

  for (int c = 0; c < NCH; ++c) {
    // load C chunk + evec (prev iter's GEMM reads finished at the pre-update sync)
#pragma unroll
    for (int k = 0; k < 32; ++k) {
      int e = tid + k * 256;
      int row = e >> 7, col = e & 127;
      int t = c * QC + row;
      Cs[row * 129 + col] = (t < LTOK) ? base[(long)t * CDIM + DIN + DST + col] : 0.f;
    }
    if (tid < 64) evec[tid] = __expf(CLA[((long)(hh * NCH + c)) * 64 + tid]);
    __syncthreads();

    // Yinter[t][pl] = evec[t] * sum_n C[t][n] * S[n][pl]  (64 x 32, K=128)
    float y[4][2] = {};
    for (int n = 0; n < 128; ++n) {
      float cv[4], sv[2];
#pragma unroll
      for (int i = 0; i < 4; ++i) cv[i] = Cs[(ty * 4 + i) * 129 + n];
#pragma unroll
      for (int j = 0; j < 2; ++j) sv[j] = Ss[n * 33 + tx * 2 + j];
#pragma unroll
      for (int i = 0; i < 4; ++i)
#pragma unroll
        for (int j = 0; j < 2; ++j) y[i][j] = fmaf(cv[i], sv[j], y[i][j]);
    }
#pragma unroll
    for (int i = 0; i < 4; ++i) {
      int tl = ty * 4 + i;
      int t = c * QC + tl;
      if (t < LTOK) {
        float ev = evec[tl];
        float* yp = Y + ((long)(b * LTOK + t)) * DIN + h * 64 + ph * 32 + tx * 2;
        yp[0] += ev * y[i][0];
        yp[1] += ev * y[i][1];
      }
    }
    float P = evec[63];            // exp(clA_end)
    __syncthreads();               // all GEMM reads of Ss done before overwrite

    // S = P*S + Sloc
    const float* slp = SL + ((long)(hh * NCH + c)) * 8192;
#pragma unroll
    for (int k = 0; k < 16; ++k) {
      int e = tid + k * 256;       // 0..4095 over this p-half
      int n = e >> 5, pl = e & 31;
      Ss[n * 33 + pl] = P * Ss[n * 33 + pl] + slp[n * 64 + ph * 32 + pl];
    }
    __syncthreads();
  }
}

// ---------------- y(+D*x) + gate silu(z) + RMSNorm, in place on Y ----------------
__global__ __launch_bounds__(256) void k_gaterms(float* __restrict__ Y,
                                                 const float* __restrict__ xbc,
                                                 const float* __restrict__ zx,
                                                 const float* __restrict__ Dv,
                                                 const float* __restrict__ rmsw) {
  long r = blockIdx.x;
  int tid = threadIdx.x;
  int e = tid * 4;
  int h = tid >> 4;
  float4 a = *(const float4*)(Y + r * DIN + e);
  const float4 xv = *(const float4*)(xbc + r * CDIM + e);
  const float4 zv = *(const float4*)(zx + r * EPROJ + e);
  float Dh = Dv[h];
  float y0 = a.x + Dh * xv.x, y1 = a.y + Dh * xv.y;
  float y2 = a.z + Dh * xv.z, y3 = a.w + Dh * xv.w;
  float g0 = y0 * (zv.x / (1.f + expf(-zv.x)));
  float g1 = y1 * (zv.y / (1.f + expf(-zv.y)));
  float g2 = y2 * (zv.z / (1.f + expf(-zv.z)));
  float g3 = y3 * (zv.w / (1.f + expf(-zv.w)));
  __shared__ float red[256];
  red[tid] = g0*g0 + g1*g1 + g2*g2 + g3*g3;
  __syncthreads();
  for (int st = 128; st; st >>= 1) {
    if (tid < st) red[tid] += red[tid + st];
    __syncthreads();
  }
  float scale = rsqrtf(red[0] * (1.0f / 1024.0f) + 1e-5f);
  float4 rw = *(const float4*)(rmsw + e);
  float4 o;
  o.x = g0 * scale * rw.x; o.y = g1 * scale * rw.y;
  o.z = g2 * scale * rw.z; o.w = g3 * scale * rw.w;
  *(float4*)(Y + r * DIN + e) = o;
}

// ---------------- final LayerNorm -> f32 out ----------------
__global__ __launch_bounds__(256) void k_ln(const float* __restrict__ outg,
                                            const float* __restrict__ lng,
                                            const float* __restrict__ lnb,
                                            float* __restrict__ out) {
  int r = blockIdx.x;
  int tid = threadIdx.x;
  const float2 v = *(const float2*)(outg + (long)r * DM + tid * 2);
  __shared__ float red[256];
  red[tid] = v.x + v.y;
  __syncthreads();
  for (int st = 128; st; st >>= 1) { if (tid < st) red[tid] += red[tid + st]; __syncthreads(); }
  float mu = red[0] * (1.0f / 512.0f);
  __syncthreads();
  float dx = v.x - mu, dy = v.y - mu;
  red[tid] = dx * dx + dy * dy;
  __syncthreads();
  for (int st = 128; st; st >>= 1) { if (tid < st) red[tid] += red[tid + st]; __syncthreads(); }
  float sc = rsqrtf(red[0] * (1.0f / 512.0f) + 1e-5f);
  int c = tid * 2;
  out[(long)r * DM + c]     = dx * sc * lng[c] + lnb[c];
  out[(long)r * DM + c + 1] = dy * sc * lng[c + 1] + lnb[c + 1];
}

// ---------------- launch ----------------
extern "C" void kernel_launch(void* const* d_in, const int* in_sizes, int n_in,
                              void* d_out, int out_size, void* d_ws, size_t ws_size,
                              hipStream_t stream) {
  float* ws = (float*)d_ws;
  float* out = (float*)d_out;
  int* rowidx = (int*)(ws + O_RIDX);
  InPtrs ip;
  for (int i = 0; i < 14; ++i) ip.p[i] = d_in[i];

  hipLaunchKernelGGL(k_convert, dim3(1160, 14), dim3(256), 0, stream, ip, ws);
  hipLaunchKernelGGL(k_rng, dim3(2), dim3(1024), 0, stream, out, rowidx);
  hipLaunchKernelGGL(k_im2col, dim3(2048), dim3(192), 0, stream, ws + O_CX, ws + O_X3);
  hipLaunchKernelGGL(k_clsrow, dim3(2), dim3(512), 0, stream, ws + O_CLS, ws + O_H);
  hipLaunchKernelGGL(k_sgemm, dim3(8, 32), dim3(256), 0, stream,
                     ws + O_X3, ws + O_CW, ws + O_H, ws + O_CB, (const int*)nullptr,
                     2048, 512, 192, 512, 1);
  hipLaunchKernelGGL(k_sgemm, dim3(37, 33), dim3(256), 0, stream,
                     ws + O_H, ws + O_IPW, ws + O_ZX, (const float*)nullptr, (const int*)nullptr,
                     2050, 2320, 512, 2320, 0);
  hipLaunchKernelGGL(k_conv1d, dim3(2050), dim3(256), 0, stream,
                     ws + O_ZX, ws + O_C1W, ws + O_C1B, ws + O_XBC);
  hipLaunchKernelGGL(k_dtda, dim3(129), dim3(256), 0, stream,
                     ws + O_ZX, ws + O_DTB, ws + O_ALOG, ws + O_DT, ws + O_LGA);
  // SSD chunked scan
  hipLaunchKernelGGL(k_ssd1, dim3(32 * NCH), dim3(256), 0, stream,
                     ws + O_XBC, ws + O_DT, ws + O_LGA, ws + O_Y, ws + O_SL, ws + O_CLA);
  hipLaunchKernelGGL(k_ssd2, dim3(64), dim3(256), 0, stream,
                     ws + O_XBC, ws + O_SL, ws + O_CLA, ws + O_Y);
  hipLaunchKernelGGL(k_gaterms, dim3(2050), dim3(256), 0, stream,
                     ws + O_Y, ws + O_XBC, ws + O_ZX, ws + O_DV, ws + O_RMSW);
  hipLaunchKernelGGL(k_sgemm, dim3(8, 9), dim3(256), 0, stream,
                     ws + O_Y, ws + O_OPW, ws + O_OUTG, (const float*)nullptr, rowidx,
                     514, 512, 1024, 512, 0);
  hipLaunchKernelGGL(k_ln, dim3(514), dim3(256), 0, stream,
                     ws + O_OUTG, ws + O_LNG, ws + O_LNB, out);
}

// Round 6
// 439.378 us; speedup vs baseline: 4.5393x; 1.4924x over previous
//
#include <hip/hip_runtime.h>
#include <hip/hip_bf16.h>
#include <stdint.h>

// ---------------- problem constants ----------------
#define LTOK  1025      // 1024 body + 1 cls
#define NROWS 2050      // B * LTOK
#define DM    512
#define DIN   1024
#define DST   128
#define NHEAD 16
#define HDIM  64
#define CDIM  1280      // DIN + 2*DST
#define EPROJ 2320      // 2*DIN + 2*DST + NHEAD
#define QC    64        // SSD chunk length
#define NCH   17        // ceil(1025/64)

// ---------------- workspace layout (float offsets), total 16,251,296 floats = 65.0 MB ----------------
#define O_RIDX   0          // int32 x 514 (reserve 1024)
#define O_CB     1024
#define O_CLS    1536
#define O_C1B    2048
#define O_DTB    3328
#define O_ALOG   3344
#define O_DV     3360
#define O_RMSW   3376
#define O_LNG    4400
#define O_LNB    4912
#define O_CW     5440
#define O_IPW    103744
#define O_OPW    1291584
#define O_C1W    1815872
#define O_CX     1820992
#define O_ZX     1952064
#define O_XBC    6708064
#define O_DT     9332064
#define O_LGA    9364864    // log(dA) = dt * (-exp(A_log))
#define O_Y      9397664    // 2,099,200 floats; overlays H and X3 (dead after in_proj)
#define O_H      9397664    // 1,049,600
#define O_X3     10447264   // 393,216
#define O_OUTG   11496864   // 263,168
#define O_SL     11760032   // chunk states: 32*17*8192 (S_loc, then in-place S_start)
#define O_CLA    16216480   // within-chunk cumsum logdA: 32*17*64 -> ends 16,251,296

// ---------------- output layout (FLOAT32 elements) ----------------
#define OO_MASK 263168
#define OO_IDR  265216
#define OO_IDK  267264

struct InPtrs { const void* p[14]; };

// ---------------- input dtype detect + convert to f32 ----------------
__device__ int detect_is_f32(const uint32_t* w, int nelem) {
  int nw = nelem / 2; if (nw > 16) nw = 16;
  int insane = 0, lozero = 0, anynz = 0;
  for (int i = 0; i < nw; ++i) {
    uint32_t word = w[i];
    if (word != 0u) anynz = 1;
    uint32_t lo = word & 0xffffu;
    if (lo == 0u) { lozero++; continue; }
    float v = __uint_as_float(lo << 16);
    float a = fabsf(v);
    if (!(a >= 1e-8f && a <= 1e4f)) insane++;
  }
  if (insane >= 2) return 1;
  if (lozero == nw && anynz) return 1;
  return 0;
}

__global__ __launch_bounds__(256) void k_convert(InPtrs ptrs, float* ws) {
  static const int sizes[14] = {131072, 98304, 512, 512, 1187840, 5120, 1280,
                                16, 16, 16, 1024, 524288, 512, 512};
  static const int offs[14]  = {O_CX, O_CW, O_CB, O_CLS, O_IPW, O_C1W, O_C1B,
                                O_DTB, O_ALOG, O_DV, O_RMSW, O_OPW, O_LNG, O_LNB};
  int t = blockIdx.y;
  int n = sizes[t];
  const uint32_t* w = (const uint32_t*)ptrs.p[t];
  __shared__ int sf;
  if (threadIdx.x == 0) sf = detect_is_f32(w, n);
  __syncthreads();
  int base = (blockIdx.x * 256 + threadIdx.x) * 4;
  if (base >= n) return;
  float* dst = ws + offs[t];
  if (sf) {
    *(float4*)(dst + base) = *(const float4*)((const float*)w + base);
  } else {
    const uint32_t* s = w + (base >> 1);
    uint32_t w0 = s[0], w1 = s[1];
    float4 o;
    o.x = __uint_as_float((w0 & 0xffffu) << 16);
    o.y = __uint_as_float(w0 & 0xffff0000u);
    o.z = __uint_as_float((w1 & 0xffffu) << 16);
    o.w = __uint_as_float(w1 & 0xffff0000u);
    *(float4*)(dst + base) = o;
  }
}

// ---------------- threefry2x32 (JAX-compatible) ----------------
__device__ __forceinline__ uint32_t rotl32(uint32_t v, int d) {
  return (v << d) | (v >> (32 - d));
}
__device__ void threefry2x32(uint32_t k0, uint32_t k1, uint32_t c0, uint32_t c1,
                             uint32_t& o0, uint32_t& o1) {
  uint32_t ks0 = k0, ks1 = k1, ks2 = 0x1BD11BDAu ^ k0 ^ k1;
  uint32_t x0 = c0 + ks0, x1 = c1 + ks1;
#define TF_R4(a,b,c,d) \
  x0 += x1; x1 = rotl32(x1,a); x1 ^= x0; \
  x0 += x1; x1 = rotl32(x1,b); x1 ^= x0; \
  x0 += x1; x1 = rotl32(x1,c); x1 ^= x0; \
  x0 += x1; x1 = rotl32(x1,d); x1 ^= x0;
  TF_R4(13,15,26,6)  x0 += ks1; x1 += ks2 + 1u;
  TF_R4(17,29,16,24) x0 += ks2; x1 += ks0 + 2u;
  TF_R4(13,15,26,6)  x0 += ks0; x1 += ks1 + 3u;
  TF_R4(17,29,16,24) x0 += ks1; x1 += ks2 + 4u;
  TF_R4(13,15,26,6)  x0 += ks2; x1 += ks0 + 5u;
#undef TF_R4
  o0 = x0; o1 = x1;
}

__global__ __launch_bounds__(1024) void k_rng(float* out, int* rowidx) {
  int b = blockIdx.x;
  int i = threadIdx.x;
  __shared__ float vals[1024];
  uint32_t fk0, fk1;
  threefry2x32(0u, 0u, 0u, 1u, fk0, fk1);
  uint32_t o0, o1;
  threefry2x32(fk0, fk1, 0u, (uint32_t)(b * 1024 + i), o0, o1);
  uint32_t bits = o0 ^ o1;
  float v = __uint_as_float((bits >> 9) | 0x3f800000u) - 1.0f;
  vals[i] = v;
  __syncthreads();
  int r = 0;
  for (int j = 0; j < 1024; ++j) {
    float vj = vals[j];
    r += (vj < v || (vj == v && j < i)) ? 1 : 0;
  }
  out[OO_IDR + b * 1024 + i] = (float)r;
  out[OO_MASK + b * 1024 + i] = (r < 256) ? 0.0f : 1.0f;
  if (r < 256) {
    out[OO_IDK + b * 256 + r] = (float)i;
    rowidx[b * 257 + r] = b * LTOK + i;
  }
  if (i == 0) rowidx[b * 257 + 256] = b * LTOK + 1024;
}

// ---------------- im2col for conv-embed ----------------
__global__ void k_im2col(const float* __restrict__ x, float* __restrict__ X3) {
  int r = blockIdx.x;
  int b = r >> 10, t = r & 1023;
  int j = threadIdx.x;
  if (j < 192) {
    int i = j / 3, k = j % 3;
    int tt = t + k - 1;
    float v = (tt >= 0 && tt < 1024) ? x[((long)(b * 1024 + tt)) * 64 + i] : 0.f;
    X3[(long)r * 192 + j] = v;
  }
}

__global__ void k_clsrow(const float* __restrict__ cls, float* __restrict__ h) {
  h[((long)(blockIdx.x * LTOK + 1024)) * DM + threadIdx.x] = cls[threadIdx.x];
}

// ---------------- generic fp32 SGEMM: C = A @ Bw^T (+bias) ----------------
__global__ __launch_bounds__(256) void k_sgemm(
    const float* __restrict__ A, const float* __restrict__ Bw,
    float* __restrict__ C, const float* __restrict__ bias,
    const int* __restrict__ rowmap, int M, int N, int K, int ldc, int cmode) {
  __shared__ float As[16][64];
  __shared__ float Bs[16][64];
  int tid = threadIdx.x;
  int bm = blockIdx.y << 6, bn = blockIdx.x << 6;
  int tx = tid & 15, ty = tid >> 4;
  int arow = tid >> 2, acol = (tid & 3) << 2;
  int gm = bm + arow, gn = bn + arow;
  bool mok = gm < M, nok = gn < N;
  long aoff = 0;
  if (mok) aoff = (long)(rowmap ? rowmap[gm] : gm) * K;
  long boff = (long)gn * K;
  float acc[4][4] = {};
  for (int k0 = 0; k0 < K; k0 += 16) {
    float4 av = make_float4(0.f,0.f,0.f,0.f), bv = make_float4(0.f,0.f,0.f,0.f);
    if (mok) av = *(const float4*)(A + aoff + k0 + acol);
    if (nok) bv = *(const float4*)(Bw + boff + k0 + acol);
    __syncthreads();
    As[acol+0][arow]=av.x; As[acol+1][arow]=av.y; As[acol+2][arow]=av.z; As[acol+3][arow]=av.w;
    Bs[acol+0][arow]=bv.x; Bs[acol+1][arow]=bv.y; Bs[acol+2][arow]=bv.z; Bs[acol+3][arow]=bv.w;
    __syncthreads();
#pragma unroll
    for (int kk = 0; kk < 16; ++kk) {
      float a[4], bb[4];
#pragma unroll
      for (int i = 0; i < 4; ++i) a[i] = As[kk][ty*4+i];
#pragma unroll
      for (int j = 0; j < 4; ++j) bb[j] = Bs[kk][tx*4+j];
#pragma unroll
      for (int i = 0; i < 4; ++i)
#pragma unroll
        for (int j = 0; j < 4; ++j) acc[i][j] = fmaf(a[i], bb[j], acc[i][j]);
    }
  }
#pragma unroll
  for (int i = 0; i < 4; ++i) {
    int r = bm + ty*4 + i;
    if (r >= M) continue;
    long crow = (cmode == 1) ? (long)((r >> 10) * LTOK + (r & 1023)) : (long)r;
#pragma unroll
    for (int j = 0; j < 4; ++j) {
      int c = bn + tx*4 + j;
      if (c < N) {
        float v = acc[i][j];
        if (bias) v += bias[c];
        C[crow * ldc + c] = v;
      }
    }
  }
}

// ---------------- depthwise causal conv(4) + silu ----------------
__global__ __launch_bounds__(256) void k_conv1d(const float* __restrict__ zx,
                                                const float* __restrict__ w,
                                                const float* __restrict__ bias,
                                                float* __restrict__ xbc) {
  long r = blockIdx.x;
  int b = (int)(r / LTOK), t = (int)(r % LTOK);
  for (int c = threadIdx.x; c < CDIM; c += 256) {
    float acc = bias[c];
    const float* wp = w + c * 4;
#pragma unroll
    for (int k = 0; k < 4; ++k) {
      int tt = t - 3 + k;
      if (tt >= 0)
        acc = fmaf(wp[k], zx[((long)(b * LTOK + tt)) * EPROJ + DIN + c], acc);
    }
    xbc[r * CDIM + c] = acc / (1.f + expf(-acc));
  }
}

// ---------------- dt = softplus(logit + bias), lga = dt * -exp(A_log) ----------------
__global__ void k_dtda(const float* __restrict__ zx, const float* __restrict__ dtb,
                       const float* __restrict__ alog, float* __restrict__ dt,
                       float* __restrict__ lga) {
  int idx = blockIdx.x * 256 + threadIdx.x;
  if (idx >= NROWS * NHEAD) return;
  int r = idx >> 4, h = idx & 15;
  float xv = zx[(long)r * EPROJ + (EPROJ - NHEAD) + h] + dtb[h];
  float dtv = (xv > 20.f) ? xv : log1pf(expf(xv));
  dt[idx] = dtv;
  lga[idx] = dtv * (-expf(alog[h]));
}

// ---------------- SSD phase 1: per (b,h,chunk) intra-chunk work ----------------
// blk = c + 17*(h + 16*b). Computes Y_intra (direct store), S_loc, clA.
__global__ __launch_bounds__(256) void k_ssd1(const float* __restrict__ xbc,
                                              const float* __restrict__ dt,
                                              const float* __restrict__ lga,
                                              float* __restrict__ Y,
                                              float* __restrict__ SL,
                                              float* __restrict__ CLA) {
  int blk = blockIdx.x;
  int c = blk % NCH;
  int hh = blk / NCH;            // h + 16*b
  int h = hh & 15, b = hh >> 4;
  int tid = threadIdx.x;
  int tx = tid & 15, ty = tid >> 4;

  __shared__ float Bs[64 * 129];
  __shared__ float Cs[64 * 129];
  __shared__ float xs[64 * 65];
  __shared__ float Ms[64 * 65];
  __shared__ float dtw[64], clA[64], wwv[64];

  int t0 = c * QC;
  const float* base = xbc + (long)b * LTOK * CDIM;

#pragma unroll
  for (int k = 0; k < 32; ++k) {
    int e = tid + k * 256;
    int row = e >> 7, col = e & 127;
    int t = t0 + row;
    float bv = 0.f, cv = 0.f;
    if (t < LTOK) {
      const float* rp = base + (long)t * CDIM;
      bv = rp[DIN + col];
      cv = rp[DIN + DST + col];
    }
    Bs[row * 129 + col] = bv;
    Cs[row * 129 + col] = cv;
  }
#pragma unroll
  for (int k = 0; k < 16; ++k) {
    int e = tid + k * 256;
    int row = e >> 6, col = e & 63;
    int t = t0 + row;
    xs[row * 65 + col] = (t < LTOK) ? base[(long)t * CDIM + h * 64 + col] : 0.f;
  }
  if (tid < 64) {
    int t = t0 + tid;
    dtw[tid] = (t < LTOK) ? dt[((long)(b * LTOK + t)) * NHEAD + h] : 0.f;
    clA[tid] = (t < LTOK) ? lga[((long)(b * LTOK + t)) * NHEAD + h] : 0.f;
  }
  __syncthreads();
  if (tid == 0) {
    float s = 0.f;
    for (int i = 0; i < 64; ++i) { s += clA[i]; clA[i] = s; }
  }
  __syncthreads();
  float clEnd = clA[63];
  if (tid < 64) {
    wwv[tid] = __expf(clEnd - clA[tid]) * dtw[tid];
    CLA[(long)blk * 64 + tid] = clA[tid];
  }
  __syncthreads();

  // GEMM1: G[t][t'] = C_t . B_t'  (64x64, K=128)
  float acc[4][4] = {};
  for (int n = 0; n < 128; ++n) {
    float cv[4], bv[4];
#pragma unroll
    for (int i = 0; i < 4; ++i) cv[i] = Cs[(ty * 4 + i) * 129 + n];
#pragma unroll
    for (int j = 0; j < 4; ++j) bv[j] = Bs[(tx * 4 + j) * 129 + n];
#pragma unroll
    for (int i = 0; i < 4; ++i)
#pragma unroll
      for (int j = 0; j < 4; ++j) acc[i][j] = fmaf(cv[i], bv[j], acc[i][j]);
  }
#pragma unroll
  for (int i = 0; i < 4; ++i) {
    int t = ty * 4 + i;
#pragma unroll
    for (int j = 0; j < 4; ++j) {
      int tp = tx * 4 + j;
      float m = 0.f;
      if (tp <= t) m = acc[i][j] * __expf(clA[t] - clA[tp]) * dtw[tp];
      Ms[t * 65 + tp] = m;
    }
  }
  __syncthreads();

  // GEMM2: Yintra[t][p] = sum_t' M[t][t'] * x[t'][p]
  float y[4][4] = {};
  for (int tp = 0; tp < 64; ++tp) {
    float mv[4], xv[4];
#pragma unroll
    for (int i = 0; i < 4; ++i) mv[i] = Ms[(ty * 4 + i) * 65 + tp];
#pragma unroll
    for (int j = 0; j < 4; ++j) xv[j] = xs[tp * 65 + tx * 4 + j];
#pragma unroll
    for (int i = 0; i < 4; ++i)
#pragma unroll
      for (int j = 0; j < 4; ++j) y[i][j] = fmaf(mv[i], xv[j], y[i][j]);
  }
#pragma unroll
  for (int i = 0; i < 4; ++i) {
    int t = t0 + ty * 4 + i;
    if (t < LTOK) {
      float* yp = Y + ((long)(b * LTOK + t)) * DIN + h * 64 + tx * 4;
#pragma unroll
      for (int j = 0; j < 4; ++j) yp[j] = y[i][j];
    }
  }

  // GEMM3: Sloc[n][p] = sum_t wwv[t] * B[t][n] * x[t][p]
  float sacc[8][4] = {};
  for (int t = 0; t < 64; ++t) {
    float w = wwv[t];
    float bv[8], xv[4];
#pragma unroll
    for (int i = 0; i < 8; ++i) bv[i] = Bs[t * 129 + ty * 8 + i] * w;
#pragma unroll
    for (int j = 0; j < 4; ++j) xv[j] = xs[t * 65 + tx * 4 + j];
#pragma unroll
    for (int i = 0; i < 8; ++i)
#pragma unroll
      for (int j = 0; j < 4; ++j) sacc[i][j] = fmaf(bv[i], xv[j], sacc[i][j]);
  }
  float* slp = SL + (long)blk * 8192;
#pragma unroll
  for (int i = 0; i < 8; ++i)
#pragma unroll
    for (int j = 0; j < 4; ++j)
      slp[(ty * 8 + i) * 64 + tx * 4 + j] = sacc[i][j];
}

// ---------------- SSD phase 2a: in-place sequential combine over chunks ----------------
// After this, SL[blk=c+17*hh] holds S_start for chunk c (state BEFORE chunk c).
// Element-parallel: grid = 8 pieces * 32 (b,h); thread owns 4 state elements.
__global__ __launch_bounds__(256) void k_comb(float* __restrict__ SL,
                                              const float* __restrict__ CLA) {
  int bx = blockIdx.x;
  int piece = bx & 7;
  int hh = bx >> 3;              // h + 16*b
  int off = piece * 1024 + threadIdx.x * 4;
  float4 s = make_float4(0.f, 0.f, 0.f, 0.f);
  for (int c = 0; c < NCH; ++c) {
    long cb = (long)(hh * NCH + c);
    float* p = SL + cb * 8192 + off;
    float P = __expf(CLA[cb * 64 + 63]);
    float4 tmp = *(float4*)p;
    *(float4*)p = s;
    s.x = fmaf(P, s.x, tmp.x);
    s.y = fmaf(P, s.y, tmp.y);
    s.z = fmaf(P, s.z, tmp.z);
    s.w = fmaf(P, s.w, tmp.w);
  }
}

// ---------------- SSD phase 2b: Y += evec[t] * C_t . S_start  (fully parallel) ----------------
// blk = c + 17*hh, like ssd1. GEMM 64x64 over K=128 in two 64-wide halves.
__global__ __launch_bounds__(256) void k_ssd3(const float* __restrict__ xbc,
                                              const float* __restrict__ SL,
                                              const float* __restrict__ CLA,
                                              float* __restrict__ Y) {
  int blk = blockIdx.x;
  int c = blk % NCH;
  int hh = blk / NCH;
  int h = hh & 15, b = hh >> 4;
  int tid = threadIdx.x;
  int tx = tid & 15, ty = tid >> 4;

  __shared__ float Cs[64 * 65];
  __shared__ float Ss[64 * 64];
  __shared__ float evec[64];

  int t0 = c * QC;
  const float* base = xbc + (long)b * LTOK * CDIM;
  const float* slp = SL + (long)blk * 8192;
  if (tid < 64) evec[tid] = __expf(CLA[(long)blk * 64 + tid]);

  float y[4][4] = {};
#pragma unroll
  for (int half = 0; half < 2; ++half) {
    int n0 = half * 64;
    __syncthreads();              // protect previous phase's LDS reads
#pragma unroll
    for (int k = 0; k < 16; ++k) {
      int e = tid + k * 256;
      int row = e >> 6, col = e & 63;
      int t = t0 + row;
      Cs[row * 65 + col] = (t < LTOK) ? base[(long)t * CDIM + DIN + DST + n0 + col] : 0.f;
    }
#pragma unroll
    for (int k = 0; k < 4; ++k) {
      int e = (tid + k * 256) * 4;
      *(float4*)(Ss + e) = *(const float4*)(slp + n0 * 64 + e);
    }
    __syncthreads();
    for (int n = 0; n < 64; ++n) {
      float cv[4], sv[4];
#pragma unroll
      for (int i = 0; i < 4; ++i) cv[i] = Cs[(ty * 4 + i) * 65 + n];
#pragma unroll
      for (int j = 0; j < 4; ++j) sv[j] = Ss[n * 64 + tx * 4 + j];
#pragma unroll
      for (int i = 0; i < 4; ++i)
#pragma unroll
        for (int j = 0; j < 4; ++j) y[i][j] = fmaf(cv[i], sv[j], y[i][j]);
    }
  }
#pragma unroll
  for (int i = 0; i < 4; ++i) {
    int tl = ty * 4 + i;
    int t = t0 + tl;
    if (t < LTOK) {
      float ev = evec[tl];
      float* yp = Y + ((long)(b * LTOK + t)) * DIN + h * 64 + tx * 4;
#pragma unroll
      for (int j = 0; j < 4; ++j) yp[j] += ev * y[i][j];
    }
  }
}

// ---------------- y(+D*x) + gate silu(z) + RMSNorm, in place on Y ----------------
__global__ __launch_bounds__(256) void k_gaterms(float* __restrict__ Y,
                                                 const float* __restrict__ xbc,
                                                 const float* __restrict__ zx,
                                                 const float* __restrict__ Dv,
                                                 const float* __restrict__ rmsw) {
  long r = blockIdx.x;
  int tid = threadIdx.x;
  int e = tid * 4;
  int h = tid >> 4;
  float4 a = *(const float4*)(Y + r * DIN + e);
  const float4 xv = *(const float4*)(xbc + r * CDIM + e);
  const float4 zv = *(const float4*)(zx + r * EPROJ + e);
  float Dh = Dv[h];
  float y0 = a.x + Dh * xv.x, y1 = a.y + Dh * xv.y;
  float y2 = a.z + Dh * xv.z, y3 = a.w + Dh * xv.w;
  float g0 = y0 * (zv.x / (1.f + expf(-zv.x)));
  float g1 = y1 * (zv.y / (1.f + expf(-zv.y)));
  float g2 = y2 * (zv.z / (1.f + expf(-zv.z)));
  float g3 = y3 * (zv.w / (1.f + expf(-zv.w)));
  __shared__ float red[256];
  red[tid] = g0*g0 + g1*g1 + g2*g2 + g3*g3;
  __syncthreads();
  for (int st = 128; st; st >>= 1) {
    if (tid < st) red[tid] += red[tid + st];
    __syncthreads();
  }
  float scale = rsqrtf(red[0] * (1.0f / 1024.0f) + 1e-5f);
  float4 rw = *(const float4*)(rmsw + e);
  float4 o;
  o.x = g0 * scale * rw.x; o.y = g1 * scale * rw.y;
  o.z = g2 * scale * rw.z; o.w = g3 * scale * rw.w;
  *(float4*)(Y + r * DIN + e) = o;
}

// ---------------- final LayerNorm -> f32 out ----------------
__global__ __launch_bounds__(256) void k_ln(const float* __restrict__ outg,
                                            const float* __restrict__ lng,
                                            const float* __restrict__ lnb,
                                            float* __restrict__ out) {
  int r = blockIdx.x;
  int tid = threadIdx.x;
  const float2 v = *(const float2*)(outg + (long)r * DM + tid * 2);
  __shared__ float red[256];
  red[tid] = v.x + v.y;
  __syncthreads();
  for (int st = 128; st; st >>= 1) { if (tid < st) red[tid] += red[tid + st]; __syncthreads(); }
  float mu = red[0] * (1.0f / 512.0f);
  __syncthreads();
  float dx = v.x - mu, dy = v.y - mu;
  red[tid] = dx * dx + dy * dy;
  __syncthreads();
  for (int st = 128; st; st >>= 1) { if (tid < st) red[tid] += red[tid + st]; __syncthreads(); }
  float sc = rsqrtf(red[0] * (1.0f / 512.0f) + 1e-5f);
  int c = tid * 2;
  out[(long)r * DM + c]     = dx * sc * lng[c] + lnb[c];
  out[(long)r * DM + c + 1] = dy * sc * lng[c + 1] + lnb[c + 1];
}

// ---------------- launch ----------------
extern "C" void kernel_launch(void* const* d_in, const int* in_sizes, int n_in,
                              void* d_out, int out_size, void* d_ws, size_t ws_size,
                              hipStream_t stream) {
  float* ws = (float*)d_ws;
  float* out = (float*)d_out;
  int* rowidx = (int*)(ws + O_RIDX);
  InPtrs ip;
  for (int i = 0; i < 14; ++i) ip.p[i] = d_in[i];

  hipLaunchKernelGGL(k_convert, dim3(1160, 14), dim3(256), 0, stream, ip, ws);
  hipLaunchKernelGGL(k_rng, dim3(2), dim3(1024), 0, stream, out, rowidx);
  hipLaunchKernelGGL(k_im2col, dim3(2048), dim3(192), 0, stream, ws + O_CX, ws + O_X3);
  hipLaunchKernelGGL(k_clsrow, dim3(2), dim3(512), 0, stream, ws + O_CLS, ws + O_H);
  hipLaunchKernelGGL(k_sgemm, dim3(8, 32), dim3(256), 0, stream,
                     ws + O_X3, ws + O_CW, ws + O_H, ws + O_CB, (const int*)nullptr,
                     2048, 512, 192, 512, 1);
  hipLaunchKernelGGL(k_sgemm, dim3(37, 33), dim3(256), 0, stream,
                     ws + O_H, ws + O_IPW, ws + O_ZX, (const float*)nullptr, (const int*)nullptr,
                     2050, 2320, 512, 2320, 0);
  hipLaunchKernelGGL(k_conv1d, dim3(2050), dim3(256), 0, stream,
                     ws + O_ZX, ws + O_C1W, ws + O_C1B, ws + O_XBC);
  hipLaunchKernelGGL(k_dtda, dim3(129), dim3(256), 0, stream,
                     ws + O_ZX, ws + O_DTB, ws + O_ALOG, ws + O_DT, ws + O_LGA);
  // SSD chunked scan: intra-chunk -> element-parallel combine -> inter-chunk GEMM
  hipLaunchKernelGGL(k_ssd1, dim3(32 * NCH), dim3(256), 0, stream,
                     ws + O_XBC, ws + O_DT, ws + O_LGA, ws + O_Y, ws + O_SL, ws + O_CLA);
  hipLaunchKernelGGL(k_comb, dim3(256), dim3(256), 0, stream, ws + O_SL, ws + O_CLA);
  hipLaunchKernelGGL(k_ssd3, dim3(32 * NCH), dim3(256), 0, stream,
                     ws + O_XBC, ws + O_SL, ws + O_CLA, ws + O_Y);
  hipLaunchKernelGGL(k_gaterms, dim3(2050), dim3(256), 0, stream,
                     ws + O_Y, ws + O_XBC, ws + O_ZX, ws + O_DV, ws + O_RMSW);
  hipLaunchKernelGGL(k_sgemm, dim3(8, 9), dim3(256), 0, stream,
                     ws + O_Y, ws + O_OPW, ws + O_OUTG, (const float*)nullptr, rowidx,
                     514, 512, 1024, 512, 0);
  hipLaunchKernelGGL(k_ln, dim3(514), dim3(256), 0, stream,
                     ws + O_OUTG, ws + O_LNG, ws + O_LNB, out);
}

// Round 7
// 373.406 us; speedup vs baseline: 5.3413x; 1.1767x over previous
//
#include <hip/hip_runtime.h>
#include <hip/hip_bf16.h>
#include <stdint.h>

// ---------------- problem constants ----------------
#define LTOK  1025      // 1024 body + 1 cls
#define NROWS 2050      // B * LTOK
#define DM    512
#define DIN   1024
#define DST   128
#define NHEAD 16
#define HDIM  64
#define CDIM  1280      // DIN + 2*DST
#define EPROJ 2320      // 2*DIN + 2*DST + NHEAD
#define QC    64        // SSD chunk length
#define NCH   17        // ceil(1025/64)

// ---------------- workspace layout (float offsets), total 16,251,296 floats = 65.0 MB ----------------
#define O_RIDX   0          // int32 x 514 (reserve 1024)
#define O_CB     1024
#define O_CLS    1536
#define O_C1B    2048
#define O_DTB    3328
#define O_ALOG   3344
#define O_DV     3360
#define O_RMSW   3376
#define O_LNG    4400
#define O_LNB    4912
#define O_CW     5440
#define O_IPW    103744
#define O_OPW    1291584
#define O_C1W    1815872
#define O_CX     1820992
#define O_ZX     1952064
#define O_XBC    6708064
#define O_DT     9332064
#define O_LGA    9364864    // log(dA) = dt * (-exp(A_log))
#define O_Y      9397664    // 2,099,200 floats; overlays H and X3 (dead after in_proj)
#define O_H      9397664    // 1,049,600
#define O_X3     10447264   // 393,216
#define O_OUTG   11496864   // 263,168
#define O_SL     11760032   // chunk states: 32*17*8192 (S_loc, then in-place S_start)
#define O_CLA    16216480   // within-chunk cumsum logdA: 32*17*64 -> ends 16,251,296

// ---------------- output layout (FLOAT32 elements) ----------------
#define OO_MASK 263168
#define OO_IDR  265216
#define OO_IDK  267264

typedef __attribute__((ext_vector_type(8))) short short8;
typedef __attribute__((ext_vector_type(4))) float floatx4;

__device__ __forceinline__ short f2bs(float f) {
  union { float f; uint32_t u; } v; v.f = f;
  uint32_t r = (v.u + 0x7FFFu + ((v.u >> 16) & 1u)) >> 16;
  return (short)r;
}

struct InPtrs { const void* p[14]; };

// ---------------- input dtype detect + convert to f32 ----------------
__device__ int detect_is_f32(const uint32_t* w, int nelem) {
  int nw = nelem / 2; if (nw > 16) nw = 16;
  int insane = 0, lozero = 0, anynz = 0;
  for (int i = 0; i < nw; ++i) {
    uint32_t word = w[i];
    if (word != 0u) anynz = 1;
    uint32_t lo = word & 0xffffu;
    if (lo == 0u) { lozero++; continue; }
    float v = __uint_as_float(lo << 16);
    float a = fabsf(v);
    if (!(a >= 1e-8f && a <= 1e4f)) insane++;
  }
  if (insane >= 2) return 1;
  if (lozero == nw && anynz) return 1;
  return 0;
}

__global__ __launch_bounds__(256) void k_convert(InPtrs ptrs, float* ws) {
  static const int sizes[14] = {131072, 98304, 512, 512, 1187840, 5120, 1280,
                                16, 16, 16, 1024, 524288, 512, 512};
  static const int offs[14]  = {O_CX, O_CW, O_CB, O_CLS, O_IPW, O_C1W, O_C1B,
                                O_DTB, O_ALOG, O_DV, O_RMSW, O_OPW, O_LNG, O_LNB};
  int t = blockIdx.y;
  int n = sizes[t];
  const uint32_t* w = (const uint32_t*)ptrs.p[t];
  __shared__ int sf;
  if (threadIdx.x == 0) sf = detect_is_f32(w, n);
  __syncthreads();
  int base = (blockIdx.x * 256 + threadIdx.x) * 4;
  if (base >= n) return;
  float* dst = ws + offs[t];
  if (sf) {
    *(float4*)(dst + base) = *(const float4*)((const float*)w + base);
  } else {
    const uint32_t* s = w + (base >> 1);
    uint32_t w0 = s[0], w1 = s[1];
    float4 o;
    o.x = __uint_as_float((w0 & 0xffffu) << 16);
    o.y = __uint_as_float(w0 & 0xffff0000u);
    o.z = __uint_as_float((w1 & 0xffffu) << 16);
    o.w = __uint_as_float(w1 & 0xffff0000u);
    *(float4*)(dst + base) = o;
  }
}

// ---------------- threefry2x32 (JAX-compatible) ----------------
__device__ __forceinline__ uint32_t rotl32(uint32_t v, int d) {
  return (v << d) | (v >> (32 - d));
}
__device__ void threefry2x32(uint32_t k0, uint32_t k1, uint32_t c0, uint32_t c1,
                             uint32_t& o0, uint32_t& o1) {
  uint32_t ks0 = k0, ks1 = k1, ks2 = 0x1BD11BDAu ^ k0 ^ k1;
  uint32_t x0 = c0 + ks0, x1 = c1 + ks1;
#define TF_R4(a,b,c,d) \
  x0 += x1; x1 = rotl32(x1,a); x1 ^= x0; \
  x0 += x1; x1 = rotl32(x1,b); x1 ^= x0; \
  x0 += x1; x1 = rotl32(x1,c); x1 ^= x0; \
  x0 += x1; x1 = rotl32(x1,d); x1 ^= x0;
  TF_R4(13,15,26,6)  x0 += ks1; x1 += ks2 + 1u;
  TF_R4(17,29,16,24) x0 += ks2; x1 += ks0 + 2u;
  TF_R4(13,15,26,6)  x0 += ks0; x1 += ks1 + 3u;
  TF_R4(17,29,16,24) x0 += ks1; x1 += ks2 + 4u;
  TF_R4(13,15,26,6)  x0 += ks2; x1 += ks0 + 5u;
#undef TF_R4
  o0 = x0; o1 = x1;
}

__global__ __launch_bounds__(1024) void k_rng(float* out, int* rowidx) {
  int b = blockIdx.x;
  int i = threadIdx.x;
  __shared__ float vals[1024];
  uint32_t fk0, fk1;
  threefry2x32(0u, 0u, 0u, 1u, fk0, fk1);
  uint32_t o0, o1;
  threefry2x32(fk0, fk1, 0u, (uint32_t)(b * 1024 + i), o0, o1);
  uint32_t bits = o0 ^ o1;
  float v = __uint_as_float((bits >> 9) | 0x3f800000u) - 1.0f;
  vals[i] = v;
  __syncthreads();
  int r = 0;
  for (int j = 0; j < 1024; ++j) {
    float vj = vals[j];
    r += (vj < v || (vj == v && j < i)) ? 1 : 0;
  }
  out[OO_IDR + b * 1024 + i] = (float)r;
  out[OO_MASK + b * 1024 + i] = (r < 256) ? 0.0f : 1.0f;
  if (r < 256) {
    out[OO_IDK + b * 256 + r] = (float)i;
    rowidx[b * 257 + r] = b * LTOK + i;
  }
  if (i == 0) rowidx[b * 257 + 256] = b * LTOK + 1024;
}

// ---------------- im2col for conv-embed ----------------
__global__ void k_im2col(const float* __restrict__ x, float* __restrict__ X3) {
  int r = blockIdx.x;
  int b = r >> 10, t = r & 1023;
  int j = threadIdx.x;
  if (j < 192) {
    int i = j / 3, k = j % 3;
    int tt = t + k - 1;
    float v = (tt >= 0 && tt < 1024) ? x[((long)(b * 1024 + tt)) * 64 + i] : 0.f;
    X3[(long)r * 192 + j] = v;
  }
}

__global__ void k_clsrow(const float* __restrict__ cls, float* __restrict__ h) {
  h[((long)(blockIdx.x * LTOK + 1024)) * DM + threadIdx.x] = cls[threadIdx.x];
}

// ---------------- generic fp32 SGEMM: C = A @ Bw^T (+bias) ----------------
__global__ __launch_bounds__(256) void k_sgemm(
    const float* __restrict__ A, const float* __restrict__ Bw,
    float* __restrict__ C, const float* __restrict__ bias,
    const int* __restrict__ rowmap, int M, int N, int K, int ldc, int cmode) {
  __shared__ float As[16][64];
  __shared__ float Bs[16][64];
  int tid = threadIdx.x;
  int bm = blockIdx.y << 6, bn = blockIdx.x << 6;
  int tx = tid & 15, ty = tid >> 4;
  int arow = tid >> 2, acol = (tid & 3) << 2;
  int gm = bm + arow, gn = bn + arow;
  bool mok = gm < M, nok = gn < N;
  long aoff = 0;
  if (mok) aoff = (long)(rowmap ? rowmap[gm] : gm) * K;
  long boff = (long)gn * K;
  float acc[4][4] = {};
  for (int k0 = 0; k0 < K; k0 += 16) {
    float4 av = make_float4(0.f,0.f,0.f,0.f), bv = make_float4(0.f,0.f,0.f,0.f);
    if (mok) av = *(const float4*)(A + aoff + k0 + acol);
    if (nok) bv = *(const float4*)(Bw + boff + k0 + acol);
    __syncthreads();
    As[acol+0][arow]=av.x; As[acol+1][arow]=av.y; As[acol+2][arow]=av.z; As[acol+3][arow]=av.w;
    Bs[acol+0][arow]=bv.x; Bs[acol+1][arow]=bv.y; Bs[acol+2][arow]=bv.z; Bs[acol+3][arow]=bv.w;
    __syncthreads();
#pragma unroll
    for (int kk = 0; kk < 16; ++kk) {
      float a[4], bb[4];
#pragma unroll
      for (int i = 0; i < 4; ++i) a[i] = As[kk][ty*4+i];
#pragma unroll
      for (int j = 0; j < 4; ++j) bb[j] = Bs[kk][tx*4+j];
#pragma unroll
      for (int i = 0; i < 4; ++i)
#pragma unroll
        for (int j = 0; j < 4; ++j) acc[i][j] = fmaf(a[i], bb[j], acc[i][j]);
    }
  }
#pragma unroll
  for (int i = 0; i < 4; ++i) {
    int r = bm + ty*4 + i;
    if (r >= M) continue;
    long crow = (cmode == 1) ? (long)((r >> 10) * LTOK + (r & 1023)) : (long)r;
#pragma unroll
    for (int j = 0; j < 4; ++j) {
      int c = bn + tx*4 + j;
      if (c < N) {
        float v = acc[i][j];
        if (bias) v += bias[c];
        C[crow * ldc + c] = v;
      }
    }
  }
}

// ---------------- depthwise causal conv(4) + silu ----------------
__global__ __launch_bounds__(256) void k_conv1d(const float* __restrict__ zx,
                                                const float* __restrict__ w,
                                                const float* __restrict__ bias,
                                                float* __restrict__ xbc) {
  long r = blockIdx.x;
  int b = (int)(r / LTOK), t = (int)(r % LTOK);
  for (int c = threadIdx.x; c < CDIM; c += 256) {
    float acc = bias[c];
    const float* wp = w + c * 4;
#pragma unroll
    for (int k = 0; k < 4; ++k) {
      int tt = t - 3 + k;
      if (tt >= 0)
        acc = fmaf(wp[k], zx[((long)(b * LTOK + tt)) * EPROJ + DIN + c], acc);
    }
    xbc[r * CDIM + c] = acc / (1.f + expf(-acc));
  }
}

// ---------------- dt = softplus(logit + bias), lga = dt * -exp(A_log) ----------------
__global__ void k_dtda(const float* __restrict__ zx, const float* __restrict__ dtb,
                       const float* __restrict__ alog, float* __restrict__ dt,
                       float* __restrict__ lga) {
  int idx = blockIdx.x * 256 + threadIdx.x;
  if (idx >= NROWS * NHEAD) return;
  int r = idx >> 4, h = idx & 15;
  float xv = zx[(long)r * EPROJ + (EPROJ - NHEAD) + h] + dtb[h];
  float dtv = (xv > 20.f) ? xv : log1pf(expf(xv));
  dt[idx] = dtv;
  lga[idx] = dtv * (-expf(alog[h]));
}

// ---------------- SSD phase 1 (MFMA bf16): per (b,h,chunk) intra-chunk work ----------------
// blk = c + 17*(h + 16*b). GEMM1: G=C.B^T (64x64x128); mask/decay -> M;
// GEMM2: Yintra = M.x (64x64x64); GEMM3: Sloc = (wwv*B)^T.x (128x64x64).
// MFMA 16x16x32 bf16. A-frag: A[m=lane&15][k=quad*8+j]; C/D: col=lane&15, row=quad*4+reg.
__global__ __launch_bounds__(256) void k_ssd1(const float* __restrict__ xbc,
                                              const float* __restrict__ dt,
                                              const float* __restrict__ lga,
                                              float* __restrict__ Y,
                                              float* __restrict__ SL,
                                              float* __restrict__ CLA) {
  int blk = blockIdx.x;
  int c = blk % NCH;
  int hh = blk / NCH;            // h + 16*b
  int h = hh & 15, b = hh >> 4;
  int tid = threadIdx.x;
  int lane = tid & 63, w = tid >> 6;       // wave 0..3
  int lm = lane & 15, q = lane >> 4;       // m/col part, quad

  __shared__ __align__(16) short sB[64 * 136];    // B[t][n]
  __shared__ __align__(16) short sC[64 * 136];    // C[t][n]
  __shared__ __align__(16) short sBT[128 * 72];   // wwv[t]*B[t][n], as [n][t]
  __shared__ __align__(16) short sXT[64 * 72];    // x[t][p] as [p][t]
  __shared__ __align__(16) short sM[64 * 72];     // M[t][tp]
  __shared__ float dtw[64], clA[64], wwv[64];

  int t0 = c * QC;
  const float* base = xbc + (long)b * LTOK * CDIM;

  if (tid < 64) {
    int t = t0 + tid;
    dtw[tid] = (t < LTOK) ? dt[((long)(b * LTOK + t)) * NHEAD + h] : 0.f;
    clA[tid] = (t < LTOK) ? lga[((long)(b * LTOK + t)) * NHEAD + h] : 0.f;
  }
  __syncthreads();
  if (tid == 0) {
    float s = 0.f;
    for (int i = 0; i < 64; ++i) { s += clA[i]; clA[i] = s; }
  }
  __syncthreads();
  float clEnd = clA[63];
  if (tid < 64) {
    wwv[tid] = __expf(clEnd - clA[tid]) * dtw[tid];
    CLA[(long)blk * 64 + tid] = clA[tid];
  }
  __syncthreads();

  // stage B, C (bf16), BT (wwv-weighted), XT (transposed)
#pragma unroll
  for (int k = 0; k < 8; ++k) {
    int e4 = (tid + k * 256) * 4;
    int row = e4 >> 7, col = e4 & 127;
    int t = t0 + row;
    float4 bv = make_float4(0.f,0.f,0.f,0.f), cv = make_float4(0.f,0.f,0.f,0.f);
    if (t < LTOK) {
      const float* rp = base + (long)t * CDIM;
      bv = *(const float4*)(rp + DIN + col);
      cv = *(const float4*)(rp + DIN + DST + col);
    }
    float wv = wwv[row];
    short b0=f2bs(bv.x), b1=f2bs(bv.y), b2=f2bs(bv.z), b3=f2bs(bv.w);
    sB[row*136+col]=b0; sB[row*136+col+1]=b1; sB[row*136+col+2]=b2; sB[row*136+col+3]=b3;
    sC[row*136+col]=f2bs(cv.x); sC[row*136+col+1]=f2bs(cv.y);
    sC[row*136+col+2]=f2bs(cv.z); sC[row*136+col+3]=f2bs(cv.w);
    sBT[(col  )*72+row]=f2bs(bv.x*wv); sBT[(col+1)*72+row]=f2bs(bv.y*wv);
    sBT[(col+2)*72+row]=f2bs(bv.z*wv); sBT[(col+3)*72+row]=f2bs(bv.w*wv);
  }
#pragma unroll
  for (int k = 0; k < 4; ++k) {
    int e4 = (tid + k * 256) * 4;
    int row = e4 >> 6, col = e4 & 63;
    int t = t0 + row;
    float4 xv = make_float4(0.f,0.f,0.f,0.f);
    if (t < LTOK) xv = *(const float4*)(base + (long)t * CDIM + h * 64 + col);
    sXT[(col  )*72+row]=f2bs(xv.x); sXT[(col+1)*72+row]=f2bs(xv.y);
    sXT[(col+2)*72+row]=f2bs(xv.z); sXT[(col+3)*72+row]=f2bs(xv.w);
  }
  __syncthreads();

  // GEMM1: G tile rows [w*16, w*16+16), cols ct*16..
  floatx4 g[4] = {};
#pragma unroll
  for (int kb = 0; kb < 4; ++kb) {
    short8 a = *(const short8*)&sC[(w*16 + lm)*136 + kb*32 + q*8];
#pragma unroll
    for (int ct = 0; ct < 4; ++ct) {
      short8 bb = *(const short8*)&sB[(ct*16 + lm)*136 + kb*32 + q*8];
      g[ct] = __builtin_amdgcn_mfma_f32_16x16x32_bf16(a, bb, g[ct], 0, 0, 0);
    }
  }
  // decay + causal mask -> sM (bf16)
#pragma unroll
  for (int ct = 0; ct < 4; ++ct) {
    int tp = ct*16 + lm;
#pragma unroll
    for (int reg = 0; reg < 4; ++reg) {
      int tl = w*16 + q*4 + reg;
      float m = 0.f;
      if (tp <= tl) m = g[ct][reg] * __expf(clA[tl] - clA[tp]) * dtw[tp];
      sM[tl*72 + tp] = f2bs(m);
    }
  }
  __syncthreads();

  // GEMM2: Yintra rows [w*16..), col tiles ct (p)
  floatx4 y[4] = {};
#pragma unroll
  for (int kb = 0; kb < 2; ++kb) {
    short8 a = *(const short8*)&sM[(w*16 + lm)*72 + kb*32 + q*8];
#pragma unroll
    for (int ct = 0; ct < 4; ++ct) {
      short8 bb = *(const short8*)&sXT[(ct*16 + lm)*72 + kb*32 + q*8];
      y[ct] = __builtin_amdgcn_mfma_f32_16x16x32_bf16(a, bb, y[ct], 0, 0, 0);
    }
  }
#pragma unroll
  for (int ct = 0; ct < 4; ++ct) {
    int p = ct*16 + lm;
#pragma unroll
    for (int reg = 0; reg < 4; ++reg) {
      int t = t0 + w*16 + q*4 + reg;
      if (t < LTOK)
        Y[((long)(b * LTOK + t)) * DIN + h * 64 + p] = y[ct][reg];
    }
  }

  // GEMM3: Sloc n-tiles (w*2+nt), p-tiles ct
  floatx4 s[2][4] = {};
#pragma unroll
  for (int kb = 0; kb < 2; ++kb) {
    short8 bfr[4];
#pragma unroll
    for (int ct = 0; ct < 4; ++ct)
      bfr[ct] = *(const short8*)&sXT[(ct*16 + lm)*72 + kb*32 + q*8];
#pragma unroll
    for (int nt = 0; nt < 2; ++nt) {
      short8 a = *(const short8*)&sBT[((w*2+nt)*16 + lm)*72 + kb*32 + q*8];
#pragma unroll
      for (int ct = 0; ct < 4; ++ct)
        s[nt][ct] = __builtin_amdgcn_mfma_f32_16x16x32_bf16(a, bfr[ct], s[nt][ct], 0, 0, 0);
    }
  }
  float* slp = SL + (long)blk * 8192;
#pragma unroll
  for (int nt = 0; nt < 2; ++nt)
#pragma unroll
    for (int ct = 0; ct < 4; ++ct)
#pragma unroll
      for (int reg = 0; reg < 4; ++reg) {
        int n = (w*2+nt)*16 + q*4 + reg;
        int p = ct*16 + lm;
        slp[n*64 + p] = s[nt][ct][reg];
      }
}

// ---------------- SSD phase 2a: in-place sequential combine over chunks ----------------
__global__ __launch_bounds__(256) void k_comb(float* __restrict__ SL,
                                              const float* __restrict__ CLA) {
  int bx = blockIdx.x;
  int piece = bx & 7;
  int hh = bx >> 3;
  int off = piece * 1024 + threadIdx.x * 4;
  float4 s = make_float4(0.f, 0.f, 0.f, 0.f);
  for (int c = 0; c < NCH; ++c) {
    long cb = (long)(hh * NCH + c);
    float* p = SL + cb * 8192 + off;
    float P = __expf(CLA[cb * 64 + 63]);
    float4 tmp = *(float4*)p;
    *(float4*)p = s;
    s.x = fmaf(P, s.x, tmp.x);
    s.y = fmaf(P, s.y, tmp.y);
    s.z = fmaf(P, s.z, tmp.z);
    s.w = fmaf(P, s.w, tmp.w);
  }
}

// ---------------- SSD phase 2b: Y += evec[t] * C_t . S_start  (fully parallel) ----------------
__global__ __launch_bounds__(256) void k_ssd3(const float* __restrict__ xbc,
                                              const float* __restrict__ SL,
                                              const float* __restrict__ CLA,
                                              float* __restrict__ Y) {
  int blk = blockIdx.x;
  int c = blk % NCH;
  int hh = blk / NCH;
  int h = hh & 15, b = hh >> 4;
  int tid = threadIdx.x;
  int tx = tid & 15, ty = tid >> 4;

  __shared__ float Cs[64 * 65];
  __shared__ float Ss[64 * 64];
  __shared__ float evec[64];

  int t0 = c * QC;
  const float* base = xbc + (long)b * LTOK * CDIM;
  const float* slp = SL + (long)blk * 8192;
  if (tid < 64) evec[tid] = __expf(CLA[(long)blk * 64 + tid]);

  float y[4][4] = {};
#pragma unroll
  for (int half = 0; half < 2; ++half) {
    int n0 = half * 64;
    __syncthreads();
#pragma unroll
    for (int k = 0; k < 16; ++k) {
      int e = tid + k * 256;
      int row = e >> 6, col = e & 63;
      int t = t0 + row;
      Cs[row * 65 + col] = (t < LTOK) ? base[(long)t * CDIM + DIN + DST + n0 + col] : 0.f;
    }
#pragma unroll
    for (int k = 0; k < 4; ++k) {
      int e = (tid + k * 256) * 4;
      *(float4*)(Ss + e) = *(const float4*)(slp + n0 * 64 + e);
    }
    __syncthreads();
    for (int n = 0; n < 64; ++n) {
      float cv[4], sv[4];
#pragma unroll
      for (int i = 0; i < 4; ++i) cv[i] = Cs[(ty * 4 + i) * 65 + n];
#pragma unroll
      for (int j = 0; j < 4; ++j) sv[j] = Ss[n * 64 + tx * 4 + j];
#pragma unroll
      for (int i = 0; i < 4; ++i)
#pragma unroll
        for (int j = 0; j < 4; ++j) y[i][j] = fmaf(cv[i], sv[j], y[i][j]);
    }
  }
#pragma unroll
  for (int i = 0; i < 4; ++i) {
    int tl = ty * 4 + i;
    int t = t0 + tl;
    if (t < LTOK) {
      float ev = evec[tl];
      float* yp = Y + ((long)(b * LTOK + t)) * DIN + h * 64 + tx * 4;
#pragma unroll
      for (int j = 0; j < 4; ++j) yp[j] += ev * y[i][j];
    }
  }
}

// ---------------- y(+D*x) + gate silu(z) + RMSNorm, in place on Y ----------------
__global__ __launch_bounds__(256) void k_gaterms(float* __restrict__ Y,
                                                 const float* __restrict__ xbc,
                                                 const float* __restrict__ zx,
                                                 const float* __restrict__ Dv,
                                                 const float* __restrict__ rmsw) {
  long r = blockIdx.x;
  int tid = threadIdx.x;
  int e = tid * 4;
  int h = tid >> 4;
  float4 a = *(const float4*)(Y + r * DIN + e);
  const float4 xv = *(const float4*)(xbc + r * CDIM + e);
  const float4 zv = *(const float4*)(zx + r * EPROJ + e);
  float Dh = Dv[h];
  float y0 = a.x + Dh * xv.x, y1 = a.y + Dh * xv.y;
  float y2 = a.z + Dh * xv.z, y3 = a.w + Dh * xv.w;
  float g0 = y0 * (zv.x / (1.f + expf(-zv.x)));
  float g1 = y1 * (zv.y / (1.f + expf(-zv.y)));
  float g2 = y2 * (zv.z / (1.f + expf(-zv.z)));
  float g3 = y3 * (zv.w / (1.f + expf(-zv.w)));
  __shared__ float red[256];
  red[tid] = g0*g0 + g1*g1 + g2*g2 + g3*g3;
  __syncthreads();
  for (int st = 128; st; st >>= 1) {
    if (tid < st) red[tid] += red[tid + st];
    __syncthreads();
  }
  float scale = rsqrtf(red[0] * (1.0f / 1024.0f) + 1e-5f);
  float4 rw = *(const float4*)(rmsw + e);
  float4 o;
  o.x = g0 * scale * rw.x; o.y = g1 * scale * rw.y;
  o.z = g2 * scale * rw.z; o.w = g3 * scale * rw.w;
  *(float4*)(Y + r * DIN + e) = o;
}

// ---------------- final LayerNorm -> f32 out ----------------
__global__ __launch_bounds__(256) void k_ln(const float* __restrict__ outg,
                                            const float* __restrict__ lng,
                                            const float* __restrict__ lnb,
                                            float* __restrict__ out) {
  int r = blockIdx.x;
  int tid = threadIdx.x;
  const float2 v = *(const float2*)(outg + (long)r * DM + tid * 2);
  __shared__ float red[256];
  red[tid] = v.x + v.y;
  __syncthreads();
  for (int st = 128; st; st >>= 1) { if (tid < st) red[tid] += red[tid + st]; __syncthreads(); }
  float mu = red[0] * (1.0f / 512.0f);
  __syncthreads();
  float dx = v.x - mu, dy = v.y - mu;
  red[tid] = dx * dx + dy * dy;
  __syncthreads();
  for (int st = 128; st; st >>= 1) { if (tid < st) red[tid] += red[tid + st]; __syncthreads(); }
  float sc = rsqrtf(red[0] * (1.0f / 512.0f) + 1e-5f);
  int c = tid * 2;
  out[(long)r * DM + c]     = dx * sc * lng[c] + lnb[c];
  out[(long)r * DM + c + 1] = dy * sc * lng[c + 1] + lnb[c + 1];
}

// ---------------- launch ----------------
extern "C" void kernel_launch(void* const* d_in, const int* in_sizes, int n_in,
                              void* d_out, int out_size, void* d_ws, size_t ws_size,
                              hipStream_t stream) {
  float* ws = (float*)d_ws;
  float* out = (float*)d_out;
  int* rowidx = (int*)(ws + O_RIDX);
  InPtrs ip;
  for (int i = 0; i < 14; ++i) ip.p[i] = d_in[i];

  hipLaunchKernelGGL(k_convert, dim3(1160, 14), dim3(256), 0, stream, ip, ws);
  hipLaunchKernelGGL(k_rng, dim3(2), dim3(1024), 0, stream, out, rowidx);
  hipLaunchKernelGGL(k_im2col, dim3(2048), dim3(192), 0, stream, ws + O_CX, ws + O_X3);
  hipLaunchKernelGGL(k_clsrow, dim3(2), dim3(512), 0, stream, ws + O_CLS, ws + O_H);
  hipLaunchKernelGGL(k_sgemm, dim3(8, 32), dim3(256), 0, stream,
                     ws + O_X3, ws + O_CW, ws + O_H, ws + O_CB, (const int*)nullptr,
                     2048, 512, 192, 512, 1);
  hipLaunchKernelGGL(k_sgemm, dim3(37, 33), dim3(256), 0, stream,
                     ws + O_H, ws + O_IPW, ws + O_ZX, (const float*)nullptr, (const int*)nullptr,
                     2050, 2320, 512, 2320, 0);
  hipLaunchKernelGGL(k_conv1d, dim3(2050), dim3(256), 0, stream,
                     ws + O_ZX, ws + O_C1W, ws + O_C1B, ws + O_XBC);
  hipLaunchKernelGGL(k_dtda, dim3(129), dim3(256), 0, stream,
                     ws + O_ZX, ws + O_DTB, ws + O_ALOG, ws + O_DT, ws + O_LGA);
  hipLaunchKernelGGL(k_ssd1, dim3(32 * NCH), dim3(256), 0, stream,
                     ws + O_XBC, ws + O_DT, ws + O_LGA, ws + O_Y, ws + O_SL, ws + O_CLA);
  hipLaunchKernelGGL(k_comb, dim3(256), dim3(256), 0, stream, ws + O_SL, ws + O_CLA);
  hipLaunchKernelGGL(k_ssd3, dim3(32 * NCH), dim3(256), 0, stream,
                     ws + O_XBC, ws + O_SL, ws + O_CLA, ws + O_Y);
  hipLaunchKernelGGL(k_gaterms, dim3(2050), dim3(256), 0, stream,
                     ws + O_Y, ws + O_XBC, ws + O_ZX, ws + O_DV, ws + O_RMSW);
  hipLaunchKernelGGL(k_sgemm, dim3(8, 9), dim3(256), 0, stream,
                     ws + O_Y, ws + O_OPW, ws + O_OUTG, (const float*)nullptr, rowidx,
                     514, 512, 1024, 512, 0);
  hipLaunchKernelGGL(k_ln, dim3(514), dim3(256), 0, stream,
                     ws + O_OUTG, ws + O_LNG, ws + O_LNB, out);
}

// Round 8
// 337.424 us; speedup vs baseline: 5.9109x; 1.1066x over previous
//
#include <hip/hip_runtime.h>
#include <hip/hip_bf16.h>
#include <stdint.h>

// ---------------- problem constants ----------------
#define LTOK  1025      // 1024 body + 1 cls
#define NROWS 2050      // B * LTOK
#define DM    512
#define DIN   1024
#define DST   128
#define NHEAD 16
#define HDIM  64
#define CDIM  1280      // DIN + 2*DST
#define EPROJ 2320      // 2*DIN + 2*DST + NHEAD
#define QC    64        // SSD chunk length
#define NCH   17        // ceil(1025/64)

// ---------------- workspace layout (float offsets), total 16,251,296 floats = 65.0 MB ----------------
#define O_RIDX   0          // int32 x 514 (reserve 1024)
#define O_CB     1024
#define O_CLS    1536
#define O_C1B    2048
#define O_DTB    3328
#define O_ALOG   3344
#define O_DV     3360
#define O_RMSW   3376
#define O_LNG    4400
#define O_LNB    4912
#define O_CW     5440
#define O_IPW    103744
#define O_OPW    1291584
#define O_C1W    1815872
#define O_CX     1820992
#define O_ZX     1952064
#define O_XBC    6708064
#define O_DT     9332064
#define O_LGA    9364864    // log(dA) = dt * (-exp(A_log))
#define O_Y      9397664    // 2,099,200 floats; overlays H and X3 (dead after in_proj)
#define O_H      9397664    // 1,049,600
#define O_X3     10447264   // 393,216
#define O_OUTG   11496864   // 263,168
#define O_SL     11760032   // chunk states: 32*17*8192 (S_loc, then in-place S_start)
#define O_CLA    16216480   // within-chunk cumsum logdA: 32*17*64 -> ends 16,251,296

// ---------------- output layout (FLOAT32 elements) ----------------
#define OO_MASK 263168
#define OO_IDR  265216
#define OO_IDK  267264

typedef __attribute__((ext_vector_type(8))) short short8;
typedef __attribute__((ext_vector_type(4))) short shortx4;
typedef __attribute__((ext_vector_type(4))) float floatx4;

__device__ __forceinline__ short f2bs(float f) {
  union { float f; uint32_t u; } v; v.f = f;
  uint32_t r = (v.u + 0x7FFFu + ((v.u >> 16) & 1u)) >> 16;
  return (short)r;
}

struct InPtrs { const void* p[14]; };

// ---------------- input dtype detect + convert to f32 ----------------
__device__ int detect_is_f32(const uint32_t* w, int nelem) {
  int nw = nelem / 2; if (nw > 16) nw = 16;
  int insane = 0, lozero = 0, anynz = 0;
  for (int i = 0; i < nw; ++i) {
    uint32_t word = w[i];
    if (word != 0u) anynz = 1;
    uint32_t lo = word & 0xffffu;
    if (lo == 0u) { lozero++; continue; }
    float v = __uint_as_float(lo << 16);
    float a = fabsf(v);
    if (!(a >= 1e-8f && a <= 1e4f)) insane++;
  }
  if (insane >= 2) return 1;
  if (lozero == nw && anynz) return 1;
  return 0;
}

__global__ __launch_bounds__(256) void k_convert(InPtrs ptrs, float* ws) {
  static const int sizes[14] = {131072, 98304, 512, 512, 1187840, 5120, 1280,
                                16, 16, 16, 1024, 524288, 512, 512};
  static const int offs[14]  = {O_CX, O_CW, O_CB, O_CLS, O_IPW, O_C1W, O_C1B,
                                O_DTB, O_ALOG, O_DV, O_RMSW, O_OPW, O_LNG, O_LNB};
  int t = blockIdx.y;
  int n = sizes[t];
  const uint32_t* w = (const uint32_t*)ptrs.p[t];
  __shared__ int sf;
  if (threadIdx.x == 0) sf = detect_is_f32(w, n);
  __syncthreads();
  int base = (blockIdx.x * 256 + threadIdx.x) * 4;
  if (base >= n) return;
  float* dst = ws + offs[t];
  if (sf) {
    *(float4*)(dst + base) = *(const float4*)((const float*)w + base);
  } else {
    const uint32_t* s = w + (base >> 1);
    uint32_t w0 = s[0], w1 = s[1];
    float4 o;
    o.x = __uint_as_float((w0 & 0xffffu) << 16);
    o.y = __uint_as_float(w0 & 0xffff0000u);
    o.z = __uint_as_float((w1 & 0xffffu) << 16);
    o.w = __uint_as_float(w1 & 0xffff0000u);
    *(float4*)(dst + base) = o;
  }
}

// ---------------- threefry2x32 (JAX-compatible) ----------------
__device__ __forceinline__ uint32_t rotl32(uint32_t v, int d) {
  return (v << d) | (v >> (32 - d));
}
__device__ void threefry2x32(uint32_t k0, uint32_t k1, uint32_t c0, uint32_t c1,
                             uint32_t& o0, uint32_t& o1) {
  uint32_t ks0 = k0, ks1 = k1, ks2 = 0x1BD11BDAu ^ k0 ^ k1;
  uint32_t x0 = c0 + ks0, x1 = c1 + ks1;
#define TF_R4(a,b,c,d) \
  x0 += x1; x1 = rotl32(x1,a); x1 ^= x0; \
  x0 += x1; x1 = rotl32(x1,b); x1 ^= x0; \
  x0 += x1; x1 = rotl32(x1,c); x1 ^= x0; \
  x0 += x1; x1 = rotl32(x1,d); x1 ^= x0;
  TF_R4(13,15,26,6)  x0 += ks1; x1 += ks2 + 1u;
  TF_R4(17,29,16,24) x0 += ks2; x1 += ks0 + 2u;
  TF_R4(13,15,26,6)  x0 += ks0; x1 += ks1 + 3u;
  TF_R4(17,29,16,24) x0 += ks1; x1 += ks2 + 4u;
  TF_R4(13,15,26,6)  x0 += ks2; x1 += ks0 + 5u;
#undef TF_R4
  o0 = x0; o1 = x1;
}

__global__ __launch_bounds__(1024) void k_rng(float* out, int* rowidx) {
  int b = blockIdx.x;
  int i = threadIdx.x;
  __shared__ float vals[1024];
  uint32_t fk0, fk1;
  threefry2x32(0u, 0u, 0u, 1u, fk0, fk1);
  uint32_t o0, o1;
  threefry2x32(fk0, fk1, 0u, (uint32_t)(b * 1024 + i), o0, o1);
  uint32_t bits = o0 ^ o1;
  float v = __uint_as_float((bits >> 9) | 0x3f800000u) - 1.0f;
  vals[i] = v;
  __syncthreads();
  int r = 0;
  for (int j = 0; j < 1024; ++j) {
    float vj = vals[j];
    r += (vj < v || (vj == v && j < i)) ? 1 : 0;
  }
  out[OO_IDR + b * 1024 + i] = (float)r;
  out[OO_MASK + b * 1024 + i] = (r < 256) ? 0.0f : 1.0f;
  if (r < 256) {
    out[OO_IDK + b * 256 + r] = (float)i;
    rowidx[b * 257 + r] = b * LTOK + i;
  }
  if (i == 0) rowidx[b * 257 + 256] = b * LTOK + 1024;
}

// ---------------- im2col for conv-embed ----------------
__global__ void k_im2col(const float* __restrict__ x, float* __restrict__ X3) {
  int r = blockIdx.x;
  int b = r >> 10, t = r & 1023;
  int j = threadIdx.x;
  if (j < 192) {
    int i = j / 3, k = j % 3;
    int tt = t + k - 1;
    float v = (tt >= 0 && tt < 1024) ? x[((long)(b * 1024 + tt)) * 64 + i] : 0.f;
    X3[(long)r * 192 + j] = v;
  }
}

__global__ void k_clsrow(const float* __restrict__ cls, float* __restrict__ h) {
  h[((long)(blockIdx.x * LTOK + 1024)) * DM + threadIdx.x] = cls[threadIdx.x];
}

// ---------------- MFMA bf16 GEMM: C = A @ Bw^T (+bias), f32 in/out ----------------
// 128x128 tile, 4 waves (2x2), each wave 4x4 16x16 tiles, K-step 32.
// A: M x K f32 (optional rowmap); Bw: N x K f32; K % 32 == 0.
// cmode==1: remap C row r -> (r>>10)*LTOK + (r&1023)  (conv-embed cls gap)
__global__ __launch_bounds__(256) void k_bgemm(
    const float* __restrict__ A, const float* __restrict__ Bw,
    float* __restrict__ C, const float* __restrict__ bias,
    const int* __restrict__ rowmap, int M, int N, int K, int ldc, int cmode) {
  __shared__ __align__(16) short sA[128 * 40];
  __shared__ __align__(16) short sB[128 * 40];
  int tid = threadIdx.x;
  int lane = tid & 63, w = tid >> 6;
  int lm = lane & 15, q = lane >> 4;
  int wm = (w >> 1) * 64, wn = (w & 1) * 64;
  int bm = blockIdx.y * 128, bn = blockIdx.x * 128;

  floatx4 acc[4][4] = {};

  for (int k0 = 0; k0 < K; k0 += 32) {
    shortx4 ar[4], br[4];
#pragma unroll
    for (int it = 0; it < 4; ++it) {
      int e4 = (tid + it * 256) * 4;
      int row = e4 >> 5, col = e4 & 31;
      float4 va = make_float4(0.f, 0.f, 0.f, 0.f);
      float4 vb = make_float4(0.f, 0.f, 0.f, 0.f);
      int gm = bm + row;
      if (gm < M) {
        long ao = (long)(rowmap ? rowmap[gm] : gm) * K;
        va = *(const float4*)(A + ao + k0 + col);
      }
      int gn = bn + row;
      if (gn < N) vb = *(const float4*)(Bw + (long)gn * K + k0 + col);
      ar[it] = shortx4{f2bs(va.x), f2bs(va.y), f2bs(va.z), f2bs(va.w)};
      br[it] = shortx4{f2bs(vb.x), f2bs(vb.y), f2bs(vb.z), f2bs(vb.w)};
    }
    __syncthreads();
#pragma unroll
    for (int it = 0; it < 4; ++it) {
      int e4 = (tid + it * 256) * 4;
      int row = e4 >> 5, col = e4 & 31;
      *(shortx4*)&sA[row * 40 + col] = ar[it];
      *(shortx4*)&sB[row * 40 + col] = br[it];
    }
    __syncthreads();
    short8 afrag[4], bfrag[4];
#pragma unroll
    for (int i = 0; i < 4; ++i)
      afrag[i] = *(const short8*)&sA[(wm + i * 16 + lm) * 40 + q * 8];
#pragma unroll
    for (int j = 0; j < 4; ++j)
      bfrag[j] = *(const short8*)&sB[(wn + j * 16 + lm) * 40 + q * 8];
#pragma unroll
    for (int i = 0; i < 4; ++i)
#pragma unroll
      for (int j = 0; j < 4; ++j)
        acc[i][j] = __builtin_amdgcn_mfma_f32_16x16x32_bf16(afrag[i], bfrag[j], acc[i][j], 0, 0, 0);
  }

#pragma unroll
  for (int i = 0; i < 4; ++i) {
    int rowl = wm + i * 16 + q * 4;
#pragma unroll
    for (int reg = 0; reg < 4; ++reg) {
      int r = bm + rowl + reg;
      if (r >= M) continue;
      long crow = cmode ? (long)((r >> 10) * LTOK + (r & 1023)) : (long)r;
#pragma unroll
      for (int j = 0; j < 4; ++j) {
        int ccol = bn + wn + j * 16 + lm;
        if (ccol < N) {
          float v = acc[i][j][reg];
          if (bias) v += bias[ccol];
          C[crow * ldc + ccol] = v;
        }
      }
    }
  }
}

// ---------------- depthwise causal conv(4) + silu ----------------
__global__ __launch_bounds__(256) void k_conv1d(const float* __restrict__ zx,
                                                const float* __restrict__ w,
                                                const float* __restrict__ bias,
                                                float* __restrict__ xbc) {
  long r = blockIdx.x;
  int b = (int)(r / LTOK), t = (int)(r % LTOK);
  for (int c = threadIdx.x; c < CDIM; c += 256) {
    float acc = bias[c];
    const float* wp = w + c * 4;
#pragma unroll
    for (int k = 0; k < 4; ++k) {
      int tt = t - 3 + k;
      if (tt >= 0)
        acc = fmaf(wp[k], zx[((long)(b * LTOK + tt)) * EPROJ + DIN + c], acc);
    }
    xbc[r * CDIM + c] = acc / (1.f + expf(-acc));
  }
}

// ---------------- dt = softplus(logit + bias), lga = dt * -exp(A_log) ----------------
__global__ void k_dtda(const float* __restrict__ zx, const float* __restrict__ dtb,
                       const float* __restrict__ alog, float* __restrict__ dt,
                       float* __restrict__ lga) {
  int idx = blockIdx.x * 256 + threadIdx.x;
  if (idx >= NROWS * NHEAD) return;
  int r = idx >> 4, h = idx & 15;
  float xv = zx[(long)r * EPROJ + (EPROJ - NHEAD) + h] + dtb[h];
  float dtv = (xv > 20.f) ? xv : log1pf(expf(xv));
  dt[idx] = dtv;
  lga[idx] = dtv * (-expf(alog[h]));
}

// ---------------- SSD phase 1 (MFMA bf16): per (b,h,chunk) intra-chunk work ----------------
__global__ __launch_bounds__(256) void k_ssd1(const float* __restrict__ xbc,
                                              const float* __restrict__ dt,
                                              const float* __restrict__ lga,
                                              float* __restrict__ Y,
                                              float* __restrict__ SL,
                                              float* __restrict__ CLA) {
  int blk = blockIdx.x;
  int c = blk % NCH;
  int hh = blk / NCH;            // h + 16*b
  int h = hh & 15, b = hh >> 4;
  int tid = threadIdx.x;
  int lane = tid & 63, w = tid >> 6;
  int lm = lane & 15, q = lane >> 4;

  __shared__ __align__(16) short sB[64 * 136];
  __shared__ __align__(16) short sC[64 * 136];
  __shared__ __align__(16) short sBT[128 * 72];
  __shared__ __align__(16) short sXT[64 * 72];
  __shared__ __align__(16) short sM[64 * 72];
  __shared__ float dtw[64], clA[64], wwv[64];

  int t0 = c * QC;
  const float* base = xbc + (long)b * LTOK * CDIM;

  if (tid < 64) {
    int t = t0 + tid;
    dtw[tid] = (t < LTOK) ? dt[((long)(b * LTOK + t)) * NHEAD + h] : 0.f;
    clA[tid] = (t < LTOK) ? lga[((long)(b * LTOK + t)) * NHEAD + h] : 0.f;
  }
  __syncthreads();
  if (tid == 0) {
    float s = 0.f;
    for (int i = 0; i < 64; ++i) { s += clA[i]; clA[i] = s; }
  }
  __syncthreads();
  float clEnd = clA[63];
  if (tid < 64) {
    wwv[tid] = __expf(clEnd - clA[tid]) * dtw[tid];
    CLA[(long)blk * 64 + tid] = clA[tid];
  }
  __syncthreads();

#pragma unroll
  for (int k = 0; k < 8; ++k) {
    int e4 = (tid + k * 256) * 4;
    int row = e4 >> 7, col = e4 & 127;
    int t = t0 + row;
    float4 bv = make_float4(0.f,0.f,0.f,0.f), cv = make_float4(0.f,0.f,0.f,0.f);
    if (t < LTOK) {
      const float* rp = base + (long)t * CDIM;
      bv = *(const float4*)(rp + DIN + col);
      cv = *(const float4*)(rp + DIN + DST + col);
    }
    float wv = wwv[row];
    sB[row*136+col]=f2bs(bv.x); sB[row*136+col+1]=f2bs(bv.y);
    sB[row*136+col+2]=f2bs(bv.z); sB[row*136+col+3]=f2bs(bv.w);
    sC[row*136+col]=f2bs(cv.x); sC[row*136+col+1]=f2bs(cv.y);
    sC[row*136+col+2]=f2bs(cv.z); sC[row*136+col+3]=f2bs(cv.w);
    sBT[(col  )*72+row]=f2bs(bv.x*wv); sBT[(col+1)*72+row]=f2bs(bv.y*wv);
    sBT[(col+2)*72+row]=f2bs(bv.z*wv); sBT[(col+3)*72+row]=f2bs(bv.w*wv);
  }
#pragma unroll
  for (int k = 0; k < 4; ++k) {
    int e4 = (tid + k * 256) * 4;
    int row = e4 >> 6, col = e4 & 63;
    int t = t0 + row;
    float4 xv = make_float4(0.f,0.f,0.f,0.f);
    if (t < LTOK) xv = *(const float4*)(base + (long)t * CDIM + h * 64 + col);
    sXT[(col  )*72+row]=f2bs(xv.x); sXT[(col+1)*72+row]=f2bs(xv.y);
    sXT[(col+2)*72+row]=f2bs(xv.z); sXT[(col+3)*72+row]=f2bs(xv.w);
  }
  __syncthreads();

  floatx4 g[4] = {};
#pragma unroll
  for (int kb = 0; kb < 4; ++kb) {
    short8 a = *(const short8*)&sC[(w*16 + lm)*136 + kb*32 + q*8];
#pragma unroll
    for (int ct = 0; ct < 4; ++ct) {
      short8 bb = *(const short8*)&sB[(ct*16 + lm)*136 + kb*32 + q*8];
      g[ct] = __builtin_amdgcn_mfma_f32_16x16x32_bf16(a, bb, g[ct], 0, 0, 0);
    }
  }
#pragma unroll
  for (int ct = 0; ct < 4; ++ct) {
    int tp = ct*16 + lm;
#pragma unroll
    for (int reg = 0; reg < 4; ++reg) {
      int tl = w*16 + q*4 + reg;
      float m = 0.f;
      if (tp <= tl) m = g[ct][reg] * __expf(clA[tl] - clA[tp]) * dtw[tp];
      sM[tl*72 + tp] = f2bs(m);
    }
  }
  __syncthreads();

  floatx4 y[4] = {};
#pragma unroll
  for (int kb = 0; kb < 2; ++kb) {
    short8 a = *(const short8*)&sM[(w*16 + lm)*72 + kb*32 + q*8];
#pragma unroll
    for (int ct = 0; ct < 4; ++ct) {
      short8 bb = *(const short8*)&sXT[(ct*16 + lm)*72 + kb*32 + q*8];
      y[ct] = __builtin_amdgcn_mfma_f32_16x16x32_bf16(a, bb, y[ct], 0, 0, 0);
    }
  }
#pragma unroll
  for (int ct = 0; ct < 4; ++ct) {
    int p = ct*16 + lm;
#pragma unroll
    for (int reg = 0; reg < 4; ++reg) {
      int t = t0 + w*16 + q*4 + reg;
      if (t < LTOK)
        Y[((long)(b * LTOK + t)) * DIN + h * 64 + p] = y[ct][reg];
    }
  }

  floatx4 s[2][4] = {};
#pragma unroll
  for (int kb = 0; kb < 2; ++kb) {
    short8 bfr[4];
#pragma unroll
    for (int ct = 0; ct < 4; ++ct)
      bfr[ct] = *(const short8*)&sXT[(ct*16 + lm)*72 + kb*32 + q*8];
#pragma unroll
    for (int nt = 0; nt < 2; ++nt) {
      short8 a = *(const short8*)&sBT[((w*2+nt)*16 + lm)*72 + kb*32 + q*8];
#pragma unroll
      for (int ct = 0; ct < 4; ++ct)
        s[nt][ct] = __builtin_amdgcn_mfma_f32_16x16x32_bf16(a, bfr[ct], s[nt][ct], 0, 0, 0);
    }
  }
  float* slp = SL + (long)blk * 8192;
#pragma unroll
  for (int nt = 0; nt < 2; ++nt)
#pragma unroll
    for (int ct = 0; ct < 4; ++ct)
#pragma unroll
      for (int reg = 0; reg < 4; ++reg) {
        int n = (w*2+nt)*16 + q*4 + reg;
        int p = ct*16 + lm;
        slp[n*64 + p] = s[nt][ct][reg];
      }
}

// ---------------- SSD phase 2a: in-place sequential combine over chunks ----------------
__global__ __launch_bounds__(256) void k_comb(float* __restrict__ SL,
                                              const float* __restrict__ CLA) {
  int bx = blockIdx.x;
  int piece = bx & 7;
  int hh = bx >> 3;
  int off = piece * 1024 + threadIdx.x * 4;
  float4 s = make_float4(0.f, 0.f, 0.f, 0.f);
  for (int c = 0; c < NCH; ++c) {
    long cb = (long)(hh * NCH + c);
    float* p = SL + cb * 8192 + off;
    float P = __expf(CLA[cb * 64 + 63]);
    float4 tmp = *(float4*)p;
    *(float4*)p = s;
    s.x = fmaf(P, s.x, tmp.x);
    s.y = fmaf(P, s.y, tmp.y);
    s.z = fmaf(P, s.z, tmp.z);
    s.w = fmaf(P, s.w, tmp.w);
  }
}

// ---------------- SSD phase 2b: Y += evec[t] * C_t . S_start  (fully parallel) ----------------
__global__ __launch_bounds__(256) void k_ssd3(const float* __restrict__ xbc,
                                              const float* __restrict__ SL,
                                              const float* __restrict__ CLA,
                                              float* __restrict__ Y) {
  int blk = blockIdx.x;
  int c = blk % NCH;
  int hh = blk / NCH;
  int h = hh & 15, b = hh >> 4;
  int tid = threadIdx.x;
  int tx = tid & 15, ty = tid >> 4;

  __shared__ float Cs[64 * 65];
  __shared__ float Ss[64 * 64];
  __shared__ float evec[64];

  int t0 = c * QC;
  const float* base = xbc + (long)b * LTOK * CDIM;
  const float* slp = SL + (long)blk * 8192;
  if (tid < 64) evec[tid] = __expf(CLA[(long)blk * 64 + tid]);

  float y[4][4] = {};
#pragma unroll
  for (int half = 0; half < 2; ++half) {
    int n0 = half * 64;
    __syncthreads();
#pragma unroll
    for (int k = 0; k < 16; ++k) {
      int e = tid + k * 256;
      int row = e >> 6, col = e & 63;
      int t = t0 + row;
      Cs[row * 65 + col] = (t < LTOK) ? base[(long)t * CDIM + DIN + DST + n0 + col] : 0.f;
    }
#pragma unroll
    for (int k = 0; k < 4; ++k) {
      int e = (tid + k * 256) * 4;
      *(float4*)(Ss + e) = *(const float4*)(slp + n0 * 64 + e);
    }
    __syncthreads();
    for (int n = 0; n < 64; ++n) {
      float cv[4], sv[4];
#pragma unroll
      for (int i = 0; i < 4; ++i) cv[i] = Cs[(ty * 4 + i) * 65 + n];
#pragma unroll
      for (int j = 0; j < 4; ++j) sv[j] = Ss[n * 64 + tx * 4 + j];
#pragma unroll
      for (int i = 0; i < 4; ++i)
#pragma unroll
        for (int j = 0; j < 4; ++j) y[i][j] = fmaf(cv[i], sv[j], y[i][j]);
    }
  }
#pragma unroll
  for (int i = 0; i < 4; ++i) {
    int tl = ty * 4 + i;
    int t = t0 + tl;
    if (t < LTOK) {
      float ev = evec[tl];
      float* yp = Y + ((long)(b * LTOK + t)) * DIN + h * 64 + tx * 4;
#pragma unroll
      for (int j = 0; j < 4; ++j) yp[j] += ev * y[i][j];
    }
  }
}

// ---------------- y(+D*x) + gate silu(z) + RMSNorm, in place on Y ----------------
__global__ __launch_bounds__(256) void k_gaterms(float* __restrict__ Y,
                                                 const float* __restrict__ xbc,
                                                 const float* __restrict__ zx,
                                                 const float* __restrict__ Dv,
                                                 const float* __restrict__ rmsw) {
  long r = blockIdx.x;
  int tid = threadIdx.x;
  int e = tid * 4;
  int h = tid >> 4;
  float4 a = *(const float4*)(Y + r * DIN + e);
  const float4 xv = *(const float4*)(xbc + r * CDIM + e);
  const float4 zv = *(const float4*)(zx + r * EPROJ + e);
  float Dh = Dv[h];
  float y0 = a.x + Dh * xv.x, y1 = a.y + Dh * xv.y;
  float y2 = a.z + Dh * xv.z, y3 = a.w + Dh * xv.w;
  float g0 = y0 * (zv.x / (1.f + expf(-zv.x)));
  float g1 = y1 * (zv.y / (1.f + expf(-zv.y)));
  float g2 = y2 * (zv.z / (1.f + expf(-zv.z)));
  float g3 = y3 * (zv.w / (1.f + expf(-zv.w)));
  __shared__ float red[256];
  red[tid] = g0*g0 + g1*g1 + g2*g2 + g3*g3;
  __syncthreads();
  for (int st = 128; st; st >>= 1) {
    if (tid < st) red[tid] += red[tid + st];
    __syncthreads();
  }
  float scale = rsqrtf(red[0] * (1.0f / 1024.0f) + 1e-5f);
  float4 rw = *(const float4*)(rmsw + e);
  float4 o;
  o.x = g0 * scale * rw.x; o.y = g1 * scale * rw.y;
  o.z = g2 * scale * rw.z; o.w = g3 * scale * rw.w;
  *(float4*)(Y + r * DIN + e) = o;
}

// ---------------- final LayerNorm -> f32 out ----------------
__global__ __launch_bounds__(256) void k_ln(const float* __restrict__ outg,
                                            const float* __restrict__ lng,
                                            const float* __restrict__ lnb,
                                            float* __restrict__ out) {
  int r = blockIdx.x;
  int tid = threadIdx.x;
  const float2 v = *(const float2*)(outg + (long)r * DM + tid * 2);
  __shared__ float red[256];
  red[tid] = v.x + v.y;
  __syncthreads();
  for (int st = 128; st; st >>= 1) { if (tid < st) red[tid] += red[tid + st]; __syncthreads(); }
  float mu = red[0] * (1.0f / 512.0f);
  __syncthreads();
  float dx = v.x - mu, dy = v.y - mu;
  red[tid] = dx * dx + dy * dy;
  __syncthreads();
  for (int st = 128; st; st >>= 1) { if (tid < st) red[tid] += red[tid + st]; __syncthreads(); }
  float sc = rsqrtf(red[0] * (1.0f / 512.0f) + 1e-5f);
  int c = tid * 2;
  out[(long)r * DM + c]     = dx * sc * lng[c] + lnb[c];
  out[(long)r * DM + c + 1] = dy * sc * lng[c + 1] + lnb[c + 1];
}

// ---------------- launch ----------------
extern "C" void kernel_launch(void* const* d_in, const int* in_sizes, int n_in,
                              void* d_out, int out_size, void* d_ws, size_t ws_size,
                              hipStream_t stream) {
  float* ws = (float*)d_ws;
  float* out = (float*)d_out;
  int* rowidx = (int*)(ws + O_RIDX);
  InPtrs ip;
  for (int i = 0; i < 14; ++i) ip.p[i] = d_in[i];

  hipLaunchKernelGGL(k_convert, dim3(1160, 14), dim3(256), 0, stream, ip, ws);
  hipLaunchKernelGGL(k_rng, dim3(2), dim3(1024), 0, stream, out, rowidx);
  hipLaunchKernelGGL(k_im2col, dim3(2048), dim3(192), 0, stream, ws + O_CX, ws + O_X3);
  hipLaunchKernelGGL(k_clsrow, dim3(2), dim3(512), 0, stream, ws + O_CLS, ws + O_H);
  // conv-embed GEMM (MFMA): (2048 x 192) @ (512 x 192)^T + bias -> H (cls-gap remap)
  hipLaunchKernelGGL(k_bgemm, dim3(4, 16), dim3(256), 0, stream,
                     ws + O_X3, ws + O_CW, ws + O_H, ws + O_CB, (const int*)nullptr,
                     2048, 512, 192, 512, 1);
  // in_proj GEMM (MFMA): (2050 x 512) @ (2320 x 512)^T -> zxbcdt
  hipLaunchKernelGGL(k_bgemm, dim3(19, 17), dim3(256), 0, stream,
                     ws + O_H, ws + O_IPW, ws + O_ZX, (const float*)nullptr, (const int*)nullptr,
                     2050, 2320, 512, 2320, 0);
  hipLaunchKernelGGL(k_conv1d, dim3(2050), dim3(256), 0, stream,
                     ws + O_ZX, ws + O_C1W, ws + O_C1B, ws + O_XBC);
  hipLaunchKernelGGL(k_dtda, dim3(129), dim3(256), 0, stream,
                     ws + O_ZX, ws + O_DTB, ws + O_ALOG, ws + O_DT, ws + O_LGA);
  hipLaunchKernelGGL(k_ssd1, dim3(32 * NCH), dim3(256), 0, stream,
                     ws + O_XBC, ws + O_DT, ws + O_LGA, ws + O_Y, ws + O_SL, ws + O_CLA);
  hipLaunchKernelGGL(k_comb, dim3(256), dim3(256), 0, stream, ws + O_SL, ws + O_CLA);
  hipLaunchKernelGGL(k_ssd3, dim3(32 * NCH), dim3(256), 0, stream,
                     ws + O_XBC, ws + O_SL, ws + O_CLA, ws + O_Y);
  hipLaunchKernelGGL(k_gaterms, dim3(2050), dim3(256), 0, stream,
                     ws + O_Y, ws + O_XBC, ws + O_ZX, ws + O_DV, ws + O_RMSW);
  // out_proj GEMM (MFMA) on gathered rows: (514 x 1024) @ (512 x 1024)^T -> outg
  hipLaunchKernelGGL(k_bgemm, dim3(4, 5), dim3(256), 0, stream,
                     ws + O_Y, ws + O_OPW, ws + O_OUTG, (const float*)nullptr, rowidx,
                     514, 512, 1024, 512, 0);
  hipLaunchKernelGGL(k_ln, dim3(514), dim3(256), 0, stream,
                     ws + O_OUTG, ws + O_LNG, ws + O_LNB, out);
}

// Round 9
// 274.840 us; speedup vs baseline: 7.2568x; 1.2277x over previous
//
#include <hip/hip_runtime.h>
#include <hip/hip_bf16.h>
#include <stdint.h>

// ---------------- problem constants ----------------
#define LTOK  1025      // 1024 body + 1 cls
#define NROWS 2050      // B * LTOK
#define DM    512
#define DIN   1024
#define DST   128
#define NHEAD 16
#define HDIM  64
#define CDIM  1280      // DIN + 2*DST
#define EPROJ 2320      // 2*DIN + 2*DST + NHEAD
#define QC    64        // SSD chunk length
#define NCH   17        // ceil(1025/64)

// ---------------- workspace layout (float offsets), total 16,251,296 floats = 65.0 MB ----------------
#define O_RIDX   0          // int32 x 514 (reserve 1024)
#define O_CB     1024
#define O_CLS    1536
#define O_C1B    2048
#define O_DTB    3328
#define O_ALOG   3344
#define O_DV     3360
#define O_RMSW   3376
#define O_LNG    4400
#define O_LNB    4912
#define O_CW     5440
#define O_IPW    103744
#define O_OPW    1291584
#define O_C1W    1815872
#define O_CX     1820992
#define O_ZX     1952064
#define O_XBC    6708064
#define O_DT     9332064
#define O_LGA    9364864    // log(dA) = dt * (-exp(A_log))
#define O_Y      9397664    // 2,099,200 floats; overlays H and X3 (dead after in_proj)
#define O_H      9397664    // 1,049,600
#define O_X3     10447264   // 393,216
#define O_OUTG   11496864   // 263,168
#define O_SL     11760032   // chunk states: 32*17*8192 (S_loc, then in-place S_start)
#define O_CLA    16216480   // within-chunk cumsum logdA: 32*17*64 -> ends 16,251,296

// ---------------- output layout (FLOAT32 elements) ----------------
#define OO_MASK 263168
#define OO_IDR  265216
#define OO_IDK  267264

typedef __attribute__((ext_vector_type(8))) short short8;
typedef __attribute__((ext_vector_type(4))) short shortx4;
typedef __attribute__((ext_vector_type(4))) float floatx4;

__device__ __forceinline__ short f2bs(float f) {
  union { float f; uint32_t u; } v; v.f = f;
  uint32_t r = (v.u + 0x7FFFu + ((v.u >> 16) & 1u)) >> 16;
  return (short)r;
}

struct InPtrs { const void* p[14]; };

// ---------------- input dtype detect + convert to f32 ----------------
__device__ int detect_is_f32(const uint32_t* w, int nelem) {
  int nw = nelem / 2; if (nw > 16) nw = 16;
  int insane = 0, lozero = 0, anynz = 0;
  for (int i = 0; i < nw; ++i) {
    uint32_t word = w[i];
    if (word != 0u) anynz = 1;
    uint32_t lo = word & 0xffffu;
    if (lo == 0u) { lozero++; continue; }
    float v = __uint_as_float(lo << 16);
    float a = fabsf(v);
    if (!(a >= 1e-8f && a <= 1e4f)) insane++;
  }
  if (insane >= 2) return 1;
  if (lozero == nw && anynz) return 1;
  return 0;
}

__global__ __launch_bounds__(256) void k_convert(InPtrs ptrs, float* ws) {
  static const int sizes[14] = {131072, 98304, 512, 512, 1187840, 5120, 1280,
                                16, 16, 16, 1024, 524288, 512, 512};
  static const int offs[14]  = {O_CX, O_CW, O_CB, O_CLS, O_IPW, O_C1W, O_C1B,
                                O_DTB, O_ALOG, O_DV, O_RMSW, O_OPW, O_LNG, O_LNB};
  int t = blockIdx.y;
  int n = sizes[t];
  const uint32_t* w = (const uint32_t*)ptrs.p[t];
  __shared__ int sf;
  if (threadIdx.x == 0) sf = detect_is_f32(w, n);
  __syncthreads();
  int base = (blockIdx.x * 256 + threadIdx.x) * 4;
  if (base >= n) return;
  float* dst = ws + offs[t];
  if (sf) {
    *(float4*)(dst + base) = *(const float4*)((const float*)w + base);
  } else {
    const uint32_t* s = w + (base >> 1);
    uint32_t w0 = s[0], w1 = s[1];
    float4 o;
    o.x = __uint_as_float((w0 & 0xffffu) << 16);
    o.y = __uint_as_float(w0 & 0xffff0000u);
    o.z = __uint_as_float((w1 & 0xffffu) << 16);
    o.w = __uint_as_float(w1 & 0xffff0000u);
    *(float4*)(dst + base) = o;
  }
}

// ---------------- zero a float region (grid.x * 1024 elements) ----------------
__global__ __launch_bounds__(256) void k_zero(float* __restrict__ p, int n) {
  int e = (blockIdx.x * 256 + threadIdx.x) * 4;
  if (e < n) *(float4*)(p + e) = make_float4(0.f, 0.f, 0.f, 0.f);
}

// ---------------- threefry2x32 (JAX-compatible) ----------------
__device__ __forceinline__ uint32_t rotl32(uint32_t v, int d) {
  return (v << d) | (v >> (32 - d));
}
__device__ void threefry2x32(uint32_t k0, uint32_t k1, uint32_t c0, uint32_t c1,
                             uint32_t& o0, uint32_t& o1) {
  uint32_t ks0 = k0, ks1 = k1, ks2 = 0x1BD11BDAu ^ k0 ^ k1;
  uint32_t x0 = c0 + ks0, x1 = c1 + ks1;
#define TF_R4(a,b,c,d) \
  x0 += x1; x1 = rotl32(x1,a); x1 ^= x0; \
  x0 += x1; x1 = rotl32(x1,b); x1 ^= x0; \
  x0 += x1; x1 = rotl32(x1,c); x1 ^= x0; \
  x0 += x1; x1 = rotl32(x1,d); x1 ^= x0;
  TF_R4(13,15,26,6)  x0 += ks1; x1 += ks2 + 1u;
  TF_R4(17,29,16,24) x0 += ks2; x1 += ks0 + 2u;
  TF_R4(13,15,26,6)  x0 += ks0; x1 += ks1 + 3u;
  TF_R4(17,29,16,24) x0 += ks1; x1 += ks2 + 4u;
  TF_R4(13,15,26,6)  x0 += ks2; x1 += ks0 + 5u;
#undef TF_R4
  o0 = x0; o1 = x1;
}

__global__ __launch_bounds__(1024) void k_rng(float* out, int* rowidx) {
  int b = blockIdx.x;
  int i = threadIdx.x;
  __shared__ float vals[1024];
  uint32_t fk0, fk1;
  threefry2x32(0u, 0u, 0u, 1u, fk0, fk1);
  uint32_t o0, o1;
  threefry2x32(fk0, fk1, 0u, (uint32_t)(b * 1024 + i), o0, o1);
  uint32_t bits = o0 ^ o1;
  float v = __uint_as_float((bits >> 9) | 0x3f800000u) - 1.0f;
  vals[i] = v;
  __syncthreads();
  int r = 0;
  for (int j = 0; j < 1024; ++j) {
    float vj = vals[j];
    r += (vj < v || (vj == v && j < i)) ? 1 : 0;
  }
  out[OO_IDR + b * 1024 + i] = (float)r;
  out[OO_MASK + b * 1024 + i] = (r < 256) ? 0.0f : 1.0f;
  if (r < 256) {
    out[OO_IDK + b * 256 + r] = (float)i;
    rowidx[b * 257 + r] = b * LTOK + i;
  }
  if (i == 0) rowidx[b * 257 + 256] = b * LTOK + 1024;
}

// ---------------- im2col for conv-embed ----------------
__global__ void k_im2col(const float* __restrict__ x, float* __restrict__ X3) {
  int r = blockIdx.x;
  int b = r >> 10, t = r & 1023;
  int j = threadIdx.x;
  if (j < 192) {
    int i = j / 3, k = j % 3;
    int tt = t + k - 1;
    float v = (tt >= 0 && tt < 1024) ? x[((long)(b * 1024 + tt)) * 64 + i] : 0.f;
    X3[(long)r * 192 + j] = v;
  }
}

__global__ void k_clsrow(const float* __restrict__ cls, float* __restrict__ h) {
  h[((long)(blockIdx.x * LTOK + 1024)) * DM + threadIdx.x] = cls[threadIdx.x];
}

// ---------------- MFMA bf16 GEMM: C = A @ Bw^T (+bias), f32 in/out ----------------
// 128x128 tile, 4 waves (2x2), each wave 4x4 16x16 tiles, K-step 32.
// Double-buffered LDS staging (1 barrier/iter). Optional split-K over gridDim.z:
// each z handles K/gridDim.z; when gz>1, epilogue uses atomicAdd (bias must be null
// and C pre-zeroed). cmode==1: remap C row r -> (r>>10)*LTOK + (r&1023).
__global__ __launch_bounds__(256) void k_bgemm(
    const float* __restrict__ A, const float* __restrict__ Bw,
    float* __restrict__ C, const float* __restrict__ bias,
    const int* __restrict__ rowmap, int M, int N, int K, int ldc, int cmode) {
  __shared__ __align__(16) short sA[2][128 * 40];
  __shared__ __align__(16) short sB[2][128 * 40];
  int tid = threadIdx.x;
  int lane = tid & 63, w = tid >> 6;
  int lm = lane & 15, q = lane >> 4;
  int wm = (w >> 1) * 64, wn = (w & 1) * 64;
  int bm = blockIdx.y * 128, bn = blockIdx.x * 128;
  int gz = gridDim.z;
  int Ks = K / gz;
  int kbase = blockIdx.z * Ks;
  int nk = Ks >> 5;

  // per-thread staging coords (4 rows of 32-wide K-slab, float4 each)
  int srow[4], scol[4];
  long aoff[4]; bool aok[4]; long boff[4]; bool bok[4];
#pragma unroll
  for (int it = 0; it < 4; ++it) {
    int e4 = (tid + it * 256) * 4;
    srow[it] = e4 >> 5; scol[it] = e4 & 31;
    int gm = bm + srow[it];
    aok[it] = gm < M;
    aoff[it] = aok[it] ? (long)(rowmap ? rowmap[gm] : gm) * K : 0;
    int gn = bn + srow[it];
    bok[it] = gn < N;
    boff[it] = bok[it] ? (long)gn * K : 0;
  }

  auto gload = [&](int kt, float4* va, float4* vb) {
    int kc = kbase + kt * 32;
#pragma unroll
    for (int it = 0; it < 4; ++it) {
      va[it] = aok[it] ? *(const float4*)(A + aoff[it] + kc + scol[it])
                       : make_float4(0.f, 0.f, 0.f, 0.f);
      vb[it] = bok[it] ? *(const float4*)(Bw + boff[it] + kc + scol[it])
                       : make_float4(0.f, 0.f, 0.f, 0.f);
    }
  };
  auto sstore = [&](int buf, const float4* va, const float4* vb) {
#pragma unroll
    for (int it = 0; it < 4; ++it) {
      *(shortx4*)&sA[buf][srow[it] * 40 + scol[it]] =
          shortx4{f2bs(va[it].x), f2bs(va[it].y), f2bs(va[it].z), f2bs(va[it].w)};
      *(shortx4*)&sB[buf][srow[it] * 40 + scol[it]] =
          shortx4{f2bs(vb[it].x), f2bs(vb[it].y), f2bs(vb[it].z), f2bs(vb[it].w)};
    }
  };

  floatx4 acc[4][4] = {};
  float4 va[4], vb[4], na[4], nb[4];

  gload(0, va, vb);
  sstore(0, va, vb);
  for (int kt = 0; kt < nk; ++kt) {
    int cur = kt & 1;
    if (kt + 1 < nk) gload(kt + 1, na, nb);    // issue next loads early
    __syncthreads();                            // buf[cur] visible; buf[1-cur] reads (iter kt-1) done
    short8 afrag[4], bfrag[4];
#pragma unroll
    for (int i = 0; i < 4; ++i)
      afrag[i] = *(const short8*)&sA[cur][(wm + i * 16 + lm) * 40 + q * 8];
#pragma unroll
    for (int j = 0; j < 4; ++j)
      bfrag[j] = *(const short8*)&sB[cur][(wn + j * 16 + lm) * 40 + q * 8];
#pragma unroll
    for (int i = 0; i < 4; ++i)
#pragma unroll
      for (int j = 0; j < 4; ++j)
        acc[i][j] = __builtin_amdgcn_mfma_f32_16x16x32_bf16(afrag[i], bfrag[j], acc[i][j], 0, 0, 0);
    if (kt + 1 < nk) sstore(1 - cur, na, nb);   // overlaps MFMA execution
  }

#pragma unroll
  for (int i = 0; i < 4; ++i) {
    int rowl = wm + i * 16 + q * 4;
#pragma unroll
    for (int reg = 0; reg < 4; ++reg) {
      int r = bm + rowl + reg;
      if (r >= M) continue;
      long crow = cmode ? (long)((r >> 10) * LTOK + (r & 1023)) : (long)r;
#pragma unroll
      for (int j = 0; j < 4; ++j) {
        int ccol = bn + wn + j * 16 + lm;
        if (ccol < N) {
          float v = acc[i][j][reg];
          if (gz > 1) {
            atomicAdd(&C[crow * ldc + ccol], v);
          } else {
            if (bias) v += bias[ccol];
            C[crow * ldc + ccol] = v;
          }
        }
      }
    }
  }
}

// ---------------- depthwise causal conv(4) + silu ----------------
__global__ __launch_bounds__(256) void k_conv1d(const float* __restrict__ zx,
                                                const float* __restrict__ w,
                                                const float* __restrict__ bias,
                                                float* __restrict__ xbc) {
  long r = blockIdx.x;
  int b = (int)(r / LTOK), t = (int)(r % LTOK);
  for (int c = threadIdx.x; c < CDIM; c += 256) {
    float acc = bias[c];
    const float* wp = w + c * 4;
#pragma unroll
    for (int k = 0; k < 4; ++k) {
      int tt = t - 3 + k;
      if (tt >= 0)
        acc = fmaf(wp[k], zx[((long)(b * LTOK + tt)) * EPROJ + DIN + c], acc);
    }
    xbc[r * CDIM + c] = acc / (1.f + expf(-acc));
  }
}

// ---------------- dt = softplus(logit + bias), lga = dt * -exp(A_log) ----------------
__global__ void k_dtda(const float* __restrict__ zx, const float* __restrict__ dtb,
                       const float* __restrict__ alog, float* __restrict__ dt,
                       float* __restrict__ lga) {
  int idx = blockIdx.x * 256 + threadIdx.x;
  if (idx >= NROWS * NHEAD) return;
  int r = idx >> 4, h = idx & 15;
  float xv = zx[(long)r * EPROJ + (EPROJ - NHEAD) + h] + dtb[h];
  float dtv = (xv > 20.f) ? xv : log1pf(expf(xv));
  dt[idx] = dtv;
  lga[idx] = dtv * (-expf(alog[h]));
}

// ---------------- SSD phase 1 (MFMA bf16): per (b,h,chunk) intra-chunk work ----------------
__global__ __launch_bounds__(256) void k_ssd1(const float* __restrict__ xbc,
                                              const float* __restrict__ dt,
                                              const float* __restrict__ lga,
                                              float* __restrict__ Y,
                                              float* __restrict__ SL,
                                              float* __restrict__ CLA) {
  int blk = blockIdx.x;
  int c = blk % NCH;
  int hh = blk / NCH;            // h + 16*b
  int h = hh & 15, b = hh >> 4;
  int tid = threadIdx.x;
  int lane = tid & 63, w = tid >> 6;
  int lm = lane & 15, q = lane >> 4;

  __shared__ __align__(16) short sB[64 * 136];
  __shared__ __align__(16) short sC[64 * 136];
  __shared__ __align__(16) short sBT[128 * 72];
  __shared__ __align__(16) short sXT[64 * 72];
  __shared__ __align__(16) short sM[64 * 72];
  __shared__ float dtw[64], clA[64], wwv[64];

  int t0 = c * QC;
  const float* base = xbc + (long)b * LTOK * CDIM;

  if (tid < 64) {
    int t = t0 + tid;
    dtw[tid] = (t < LTOK) ? dt[((long)(b * LTOK + t)) * NHEAD + h] : 0.f;
    clA[tid] = (t < LTOK) ? lga[((long)(b * LTOK + t)) * NHEAD + h] : 0.f;
  }
  __syncthreads();
  if (tid == 0) {
    float s = 0.f;
    for (int i = 0; i < 64; ++i) { s += clA[i]; clA[i] = s; }
  }
  __syncthreads();
  float clEnd = clA[63];
  if (tid < 64) {
    wwv[tid] = __expf(clEnd - clA[tid]) * dtw[tid];
    CLA[(long)blk * 64 + tid] = clA[tid];
  }
  __syncthreads();

#pragma unroll
  for (int k = 0; k < 8; ++k) {
    int e4 = (tid + k * 256) * 4;
    int row = e4 >> 7, col = e4 & 127;
    int t = t0 + row;
    float4 bv = make_float4(0.f,0.f,0.f,0.f), cv = make_float4(0.f,0.f,0.f,0.f);
    if (t < LTOK) {
      const float* rp = base + (long)t * CDIM;
      bv = *(const float4*)(rp + DIN + col);
      cv = *(const float4*)(rp + DIN + DST + col);
    }
    float wv = wwv[row];
    sB[row*136+col]=f2bs(bv.x); sB[row*136+col+1]=f2bs(bv.y);
    sB[row*136+col+2]=f2bs(bv.z); sB[row*136+col+3]=f2bs(bv.w);
    sC[row*136+col]=f2bs(cv.x); sC[row*136+col+1]=f2bs(cv.y);
    sC[row*136+col+2]=f2bs(cv.z); sC[row*136+col+3]=f2bs(cv.w);
    sBT[(col  )*72+row]=f2bs(bv.x*wv); sBT[(col+1)*72+row]=f2bs(bv.y*wv);
    sBT[(col+2)*72+row]=f2bs(bv.z*wv); sBT[(col+3)*72+row]=f2bs(bv.w*wv);
  }
#pragma unroll
  for (int k = 0; k < 4; ++k) {
    int e4 = (tid + k * 256) * 4;
    int row = e4 >> 6, col = e4 & 63;
    int t = t0 + row;
    float4 xv = make_float4(0.f,0.f,0.f,0.f);
    if (t < LTOK) xv = *(const float4*)(base + (long)t * CDIM + h * 64 + col);
    sXT[(col  )*72+row]=f2bs(xv.x); sXT[(col+1)*72+row]=f2bs(xv.y);
    sXT[(col+2)*72+row]=f2bs(xv.z); sXT[(col+3)*72+row]=f2bs(xv.w);
  }
  __syncthreads();

  floatx4 g[4] = {};
#pragma unroll
  for (int kb = 0; kb < 4; ++kb) {
    short8 a = *(const short8*)&sC[(w*16 + lm)*136 + kb*32 + q*8];
#pragma unroll
    for (int ct = 0; ct < 4; ++ct) {
      short8 bb = *(const short8*)&sB[(ct*16 + lm)*136 + kb*32 + q*8];
      g[ct] = __builtin_amdgcn_mfma_f32_16x16x32_bf16(a, bb, g[ct], 0, 0, 0);
    }
  }
#pragma unroll
  for (int ct = 0; ct < 4; ++ct) {
    int tp = ct*16 + lm;
#pragma unroll
    for (int reg = 0; reg < 4; ++reg) {
      int tl = w*16 + q*4 + reg;
      float m = 0.f;
      if (tp <= tl) m = g[ct][reg] * __expf(clA[tl] - clA[tp]) * dtw[tp];
      sM[tl*72 + tp] = f2bs(m);
    }
  }
  __syncthreads();

  floatx4 y[4] = {};
#pragma unroll
  for (int kb = 0; kb < 2; ++kb) {
    short8 a = *(const short8*)&sM[(w*16 + lm)*72 + kb*32 + q*8];
#pragma unroll
    for (int ct = 0; ct < 4; ++ct) {
      short8 bb = *(const short8*)&sXT[(ct*16 + lm)*72 + kb*32 + q*8];
      y[ct] = __builtin_amdgcn_mfma_f32_16x16x32_bf16(a, bb, y[ct], 0, 0, 0);
    }
  }
#pragma unroll
  for (int ct = 0; ct < 4; ++ct) {
    int p = ct*16 + lm;
#pragma unroll
    for (int reg = 0; reg < 4; ++reg) {
      int t = t0 + w*16 + q*4 + reg;
      if (t < LTOK)
        Y[((long)(b * LTOK + t)) * DIN + h * 64 + p] = y[ct][reg];
    }
  }

  floatx4 s[2][4] = {};
#pragma unroll
  for (int kb = 0; kb < 2; ++kb) {
    short8 bfr[4];
#pragma unroll
    for (int ct = 0; ct < 4; ++ct)
      bfr[ct] = *(const short8*)&sXT[(ct*16 + lm)*72 + kb*32 + q*8];
#pragma unroll
    for (int nt = 0; nt < 2; ++nt) {
      short8 a = *(const short8*)&sBT[((w*2+nt)*16 + lm)*72 + kb*32 + q*8];
#pragma unroll
      for (int ct = 0; ct < 4; ++ct)
        s[nt][ct] = __builtin_amdgcn_mfma_f32_16x16x32_bf16(a, bfr[ct], s[nt][ct], 0, 0, 0);
    }
  }
  float* slp = SL + (long)blk * 8192;
#pragma unroll
  for (int nt = 0; nt < 2; ++nt)
#pragma unroll
    for (int ct = 0; ct < 4; ++ct)
#pragma unroll
      for (int reg = 0; reg < 4; ++reg) {
        int n = (w*2+nt)*16 + q*4 + reg;
        int p = ct*16 + lm;
        slp[n*64 + p] = s[nt][ct][reg];
      }
}

// ---------------- SSD phase 2a: in-place sequential combine over chunks ----------------
__global__ __launch_bounds__(256) void k_comb(float* __restrict__ SL,
                                              const float* __restrict__ CLA) {
  int bx = blockIdx.x;
  int piece = bx & 7;
  int hh = bx >> 3;
  int off = piece * 1024 + threadIdx.x * 4;
  float4 s = make_float4(0.f, 0.f, 0.f, 0.f);
  for (int c = 0; c < NCH; ++c) {
    long cb = (long)(hh * NCH + c);
    float* p = SL + cb * 8192 + off;
    float P = __expf(CLA[cb * 64 + 63]);
    float4 tmp = *(float4*)p;
    *(float4*)p = s;
    s.x = fmaf(P, s.x, tmp.x);
    s.y = fmaf(P, s.y, tmp.y);
    s.z = fmaf(P, s.z, tmp.z);
    s.w = fmaf(P, s.w, tmp.w);
  }
}

// ---------------- SSD phase 2b: Y += evec[t] * C_t . S_start  (fully parallel) ----------------
__global__ __launch_bounds__(256) void k_ssd3(const float* __restrict__ xbc,
                                              const float* __restrict__ SL,
                                              const float* __restrict__ CLA,
                                              float* __restrict__ Y) {
  int blk = blockIdx.x;
  int c = blk % NCH;
  int hh = blk / NCH;
  int h = hh & 15, b = hh >> 4;
  int tid = threadIdx.x;
  int tx = tid & 15, ty = tid >> 4;

  __shared__ float Cs[64 * 65];
  __shared__ float Ss[64 * 64];
  __shared__ float evec[64];

  int t0 = c * QC;
  const float* base = xbc + (long)b * LTOK * CDIM;
  const float* slp = SL + (long)blk * 8192;
  if (tid < 64) evec[tid] = __expf(CLA[(long)blk * 64 + tid]);

  float y[4][4] = {};
#pragma unroll
  for (int half = 0; half < 2; ++half) {
    int n0 = half * 64;
    __syncthreads();
#pragma unroll
    for (int k = 0; k < 16; ++k) {
      int e = tid + k * 256;
      int row = e >> 6, col = e & 63;
      int t = t0 + row;
      Cs[row * 65 + col] = (t < LTOK) ? base[(long)t * CDIM + DIN + DST + n0 + col] : 0.f;
    }
#pragma unroll
    for (int k = 0; k < 4; ++k) {
      int e = (tid + k * 256) * 4;
      *(float4*)(Ss + e) = *(const float4*)(slp + n0 * 64 + e);
    }
    __syncthreads();
    for (int n = 0; n < 64; ++n) {
      float cv[4], sv[4];
#pragma unroll
      for (int i = 0; i < 4; ++i) cv[i] = Cs[(ty * 4 + i) * 65 + n];
#pragma unroll
      for (int j = 0; j < 4; ++j) sv[j] = Ss[n * 64 + tx * 4 + j];
#pragma unroll
      for (int i = 0; i < 4; ++i)
#pragma unroll
        for (int j = 0; j < 4; ++j) y[i][j] = fmaf(cv[i], sv[j], y[i][j]);
    }
  }
#pragma unroll
  for (int i = 0; i < 4; ++i) {
    int tl = ty * 4 + i;
    int t = t0 + tl;
    if (t < LTOK) {
      float ev = evec[tl];
      float* yp = Y + ((long)(b * LTOK + t)) * DIN + h * 64 + tx * 4;
#pragma unroll
      for (int j = 0; j < 4; ++j) yp[j] += ev * y[i][j];
    }
  }
}

// ---------------- y(+D*x) + gate silu(z) + RMSNorm, in place on Y ----------------
__global__ __launch_bounds__(256) void k_gaterms(float* __restrict__ Y,
                                                 const float* __restrict__ xbc,
                                                 const float* __restrict__ zx,
                                                 const float* __restrict__ Dv,
                                                 const float* __restrict__ rmsw) {
  long r = blockIdx.x;
  int tid = threadIdx.x;
  int e = tid * 4;
  int h = tid >> 4;
  float4 a = *(const float4*)(Y + r * DIN + e);
  const float4 xv = *(const float4*)(xbc + r * CDIM + e);
  const float4 zv = *(const float4*)(zx + r * EPROJ + e);
  float Dh = Dv[h];
  float y0 = a.x + Dh * xv.x, y1 = a.y + Dh * xv.y;
  float y2 = a.z + Dh * xv.z, y3 = a.w + Dh * xv.w;
  float g0 = y0 * (zv.x / (1.f + expf(-zv.x)));
  float g1 = y1 * (zv.y / (1.f + expf(-zv.y)));
  float g2 = y2 * (zv.z / (1.f + expf(-zv.z)));
  float g3 = y3 * (zv.w / (1.f + expf(-zv.w)));
  __shared__ float red[256];
  red[tid] = g0*g0 + g1*g1 + g2*g2 + g3*g3;
  __syncthreads();
  for (int st = 128; st; st >>= 1) {
    if (tid < st) red[tid] += red[tid + st];
    __syncthreads();
  }
  float scale = rsqrtf(red[0] * (1.0f / 1024.0f) + 1e-5f);
  float4 rw = *(const float4*)(rmsw + e);
  float4 o;
  o.x = g0 * scale * rw.x; o.y = g1 * scale * rw.y;
  o.z = g2 * scale * rw.z; o.w = g3 * scale * rw.w;
  *(float4*)(Y + r * DIN + e) = o;
}

// ---------------- final LayerNorm -> f32 out ----------------
__global__ __launch_bounds__(256) void k_ln(const float* __restrict__ outg,
                                            const float* __restrict__ lng,
                                            const float* __restrict__ lnb,
                                            float* __restrict__ out) {
  int r = blockIdx.x;
  int tid = threadIdx.x;
  const float2 v = *(const float2*)(outg + (long)r * DM + tid * 2);
  __shared__ float red[256];
  red[tid] = v.x + v.y;
  __syncthreads();
  for (int st = 128; st; st >>= 1) { if (tid < st) red[tid] += red[tid + st]; __syncthreads(); }
  float mu = red[0] * (1.0f / 512.0f);
  __syncthreads();
  float dx = v.x - mu, dy = v.y - mu;
  red[tid] = dx * dx + dy * dy;
  __syncthreads();
  for (int st = 128; st; st >>= 1) { if (tid < st) red[tid] += red[tid + st]; __syncthreads(); }
  float sc = rsqrtf(red[0] * (1.0f / 512.0f) + 1e-5f);
  int c = tid * 2;
  out[(long)r * DM + c]     = dx * sc * lng[c] + lnb[c];
  out[(long)r * DM + c + 1] = dy * sc * lng[c + 1] + lnb[c + 1];
}

// ---------------- launch ----------------
extern "C" void kernel_launch(void* const* d_in, const int* in_sizes, int n_in,
                              void* d_out, int out_size, void* d_ws, size_t ws_size,
                              hipStream_t stream) {
  float* ws = (float*)d_ws;
  float* out = (float*)d_out;
  int* rowidx = (int*)(ws + O_RIDX);
  InPtrs ip;
  for (int i = 0; i < 14; ++i) ip.p[i] = d_in[i];

  hipLaunchKernelGGL(k_convert, dim3(1160, 14), dim3(256), 0, stream, ip, ws);
  hipLaunchKernelGGL(k_rng, dim3(2), dim3(1024), 0, stream, out, rowidx);
  hipLaunchKernelGGL(k_im2col, dim3(2048), dim3(192), 0, stream, ws + O_CX, ws + O_X3);
  hipLaunchKernelGGL(k_clsrow, dim3(2), dim3(512), 0, stream, ws + O_CLS, ws + O_H);
  // conv-embed GEMM (MFMA): (2048 x 192) @ (512 x 192)^T + bias -> H (cls-gap remap)
  hipLaunchKernelGGL(k_bgemm, dim3(4, 16, 1), dim3(256), 0, stream,
                     ws + O_X3, ws + O_CW, ws + O_H, ws + O_CB, (const int*)nullptr,
                     2048, 512, 192, 512, 1);
  // in_proj GEMM (MFMA): (2050 x 512) @ (2320 x 512)^T -> zxbcdt
  hipLaunchKernelGGL(k_bgemm, dim3(19, 17, 1), dim3(256), 0, stream,
                     ws + O_H, ws + O_IPW, ws + O_ZX, (const float*)nullptr, (const int*)nullptr,
                     2050, 2320, 512, 2320, 0);
  hipLaunchKernelGGL(k_conv1d, dim3(2050), dim3(256), 0, stream,
                     ws + O_ZX, ws + O_C1W, ws + O_C1B, ws + O_XBC);
  hipLaunchKernelGGL(k_dtda, dim3(129), dim3(256), 0, stream,
                     ws + O_ZX, ws + O_DTB, ws + O_ALOG, ws + O_DT, ws + O_LGA);
  hipLaunchKernelGGL(k_ssd1, dim3(32 * NCH), dim3(256), 0, stream,
                     ws + O_XBC, ws + O_DT, ws + O_LGA, ws + O_Y, ws + O_SL, ws + O_CLA);
  hipLaunchKernelGGL(k_comb, dim3(256), dim3(256), 0, stream, ws + O_SL, ws + O_CLA);
  hipLaunchKernelGGL(k_ssd3, dim3(32 * NCH), dim3(256), 0, stream,
                     ws + O_XBC, ws + O_SL, ws + O_CLA, ws + O_Y);
  hipLaunchKernelGGL(k_gaterms, dim3(2050), dim3(256), 0, stream,
                     ws + O_Y, ws + O_XBC, ws + O_ZX, ws + O_DV, ws + O_RMSW);
  // out_proj GEMM (MFMA, split-K=4 + atomics): (514 x 1024) @ (512 x 1024)^T -> outg
  hipLaunchKernelGGL(k_zero, dim3(257), dim3(256), 0, stream, ws + O_OUTG, 263168);
  hipLaunchKernelGGL(k_bgemm, dim3(4, 5, 4), dim3(256), 0, stream,
                     ws + O_Y, ws + O_OPW, ws + O_OUTG, (const float*)nullptr, rowidx,
                     514, 512, 1024, 512, 0);
  hipLaunchKernelGGL(k_ln, dim3(514), dim3(256), 0, stream,
                     ws + O_OUTG, ws + O_LNG, ws + O_LNB, out);
}

// Round 10
// 255.636 us; speedup vs baseline: 7.8020x; 1.0751x over previous
//
#include <hip/hip_runtime.h>
#include <hip/hip_bf16.h>
#include <stdint.h>

// ---------------- problem constants ----------------
#define LTOK  1025      // 1024 body + 1 cls
#define NROWS 2050      // B * LTOK
#define DM    512
#define DIN   1024
#define DST   128
#define NHEAD 16
#define HDIM  64
#define CDIM  1280      // DIN + 2*DST
#define EPROJ 2320      // 2*DIN + 2*DST + NHEAD
#define QC    64        // SSD chunk length
#define NCH   17        // ceil(1025/64)

// ---------------- workspace layout (float offsets), total 16,251,296 floats = 65.0 MB ----------------
#define O_RIDX   0          // int32 x 514 (reserve 1024)
#define O_CB     1024
#define O_CLS    1536
#define O_C1B    2048
#define O_DTB    3328
#define O_ALOG   3344
#define O_DV     3360
#define O_RMSW   3376
#define O_LNG    4400
#define O_LNB    4912
#define O_CW     5440
#define O_IPW    103744
#define O_OPW    1291584
#define O_C1W    1815872
#define O_CX     1820992
#define O_ZX     1952064
#define O_XBC    6708064
#define O_DT     9332064
#define O_LGA    9364864    // log(dA) = dt * (-exp(A_log))
#define O_Y      9397664    // 2,099,200 floats; overlays H and X3 (dead after in_proj)
#define O_H      9397664    // 1,049,600
#define O_X3     10447264   // 393,216
#define O_OUTG   11496864   // 263,168
#define O_SL     11760032   // chunk states: 32*17*8192 (S_loc, then in-place S_start)
#define O_CLA    16216480   // within-chunk cumsum logdA: 32*17*64 -> ends 16,251,296

// ---------------- output layout (FLOAT32 elements) ----------------
#define OO_MASK 263168
#define OO_IDR  265216
#define OO_IDK  267264

typedef __attribute__((ext_vector_type(8))) short short8;
typedef __attribute__((ext_vector_type(4))) short shortx4;
typedef __attribute__((ext_vector_type(4))) float floatx4;

__device__ __forceinline__ short f2bs(float f) {
  union { float f; uint32_t u; } v; v.f = f;
  uint32_t r = (v.u + 0x7FFFu + ((v.u >> 16) & 1u)) >> 16;
  return (short)r;
}

struct InPtrs { const void* p[14]; };

// ---------------- input dtype detect + convert to f32 ----------------
__device__ int detect_is_f32(const uint32_t* w, int nelem) {
  int nw = nelem / 2; if (nw > 16) nw = 16;
  int insane = 0, lozero = 0, anynz = 0;
  for (int i = 0; i < nw; ++i) {
    uint32_t word = w[i];
    if (word != 0u) anynz = 1;
    uint32_t lo = word & 0xffffu;
    if (lo == 0u) { lozero++; continue; }
    float v = __uint_as_float(lo << 16);
    float a = fabsf(v);
    if (!(a >= 1e-8f && a <= 1e4f)) insane++;
  }
  if (insane >= 2) return 1;
  if (lozero == nw && anynz) return 1;
  return 0;
}

__global__ __launch_bounds__(256) void k_convert(InPtrs ptrs, float* ws) {
  static const int sizes[14] = {131072, 98304, 512, 512, 1187840, 5120, 1280,
                                16, 16, 16, 1024, 524288, 512, 512};
  static const int offs[14]  = {O_CX, O_CW, O_CB, O_CLS, O_IPW, O_C1W, O_C1B,
                                O_DTB, O_ALOG, O_DV, O_RMSW, O_OPW, O_LNG, O_LNB};
  int t = blockIdx.y;
  int n = sizes[t];
  const uint32_t* w = (const uint32_t*)ptrs.p[t];
  __shared__ int sf;
  if (threadIdx.x == 0) sf = detect_is_f32(w, n);
  __syncthreads();
  int base = (blockIdx.x * 256 + threadIdx.x) * 4;
  if (base >= n) return;
  float* dst = ws + offs[t];
  if (sf) {
    *(float4*)(dst + base) = *(const float4*)((const float*)w + base);
  } else {
    const uint32_t* s = w + (base >> 1);
    uint32_t w0 = s[0], w1 = s[1];
    float4 o;
    o.x = __uint_as_float((w0 & 0xffffu) << 16);
    o.y = __uint_as_float(w0 & 0xffff0000u);
    o.z = __uint_as_float((w1 & 0xffffu) << 16);
    o.w = __uint_as_float(w1 & 0xffff0000u);
    *(float4*)(dst + base) = o;
  }
}

// ---------------- zero a float region ----------------
__global__ __launch_bounds__(256) void k_zero(float* __restrict__ p, int n) {
  int e = (blockIdx.x * 256 + threadIdx.x) * 4;
  if (e < n) *(float4*)(p + e) = make_float4(0.f, 0.f, 0.f, 0.f);
}

// ---------------- threefry2x32 (JAX-compatible) ----------------
__device__ __forceinline__ uint32_t rotl32(uint32_t v, int d) {
  return (v << d) | (v >> (32 - d));
}
__device__ void threefry2x32(uint32_t k0, uint32_t k1, uint32_t c0, uint32_t c1,
                             uint32_t& o0, uint32_t& o1) {
  uint32_t ks0 = k0, ks1 = k1, ks2 = 0x1BD11BDAu ^ k0 ^ k1;
  uint32_t x0 = c0 + ks0, x1 = c1 + ks1;
#define TF_R4(a,b,c,d) \
  x0 += x1; x1 = rotl32(x1,a); x1 ^= x0; \
  x0 += x1; x1 = rotl32(x1,b); x1 ^= x0; \
  x0 += x1; x1 = rotl32(x1,c); x1 ^= x0; \
  x0 += x1; x1 = rotl32(x1,d); x1 ^= x0;
  TF_R4(13,15,26,6)  x0 += ks1; x1 += ks2 + 1u;
  TF_R4(17,29,16,24) x0 += ks2; x1 += ks0 + 2u;
  TF_R4(13,15,26,6)  x0 += ks0; x1 += ks1 + 3u;
  TF_R4(17,29,16,24) x0 += ks1; x1 += ks2 + 4u;
  TF_R4(13,15,26,6)  x0 += ks2; x1 += ks0 + 5u;
#undef TF_R4
  o0 = x0; o1 = x1;
}

// RNG + stable argsort ranks, parallelized: grid (16, 2); block handles 64 targets,
// 4 threads/target each scanning a 256-source quarter (bank-staggered), shfl-combined.
__global__ __launch_bounds__(256) void k_rng(float* out, int* rowidx) {
  int b = blockIdx.y;
  int seg = blockIdx.x;
  int tid = threadIdx.x;
  __shared__ float vals[1024];
  uint32_t fk0, fk1;
  threefry2x32(0u, 0u, 0u, 1u, fk0, fk1);          // fold_in(key(0), 1)
#pragma unroll
  for (int k = 0; k < 4; ++k) {
    int i = tid + k * 256;
    uint32_t o0, o1;
    threefry2x32(fk0, fk1, 0u, (uint32_t)(b * 1024 + i), o0, o1);
    uint32_t bits = o0 ^ o1;
    vals[i] = __uint_as_float((bits >> 9) | 0x3f800000u) - 1.0f;
  }
  __syncthreads();
  int tg = seg * 64 + (tid >> 2);      // target index
  int qq = tid & 3;                    // quarter
  float v = vals[tg];
  int r = 0;
  int j0 = qq * 256;
  for (int it = 0; it < 256; ++it) {
    int j = j0 + ((it + qq * 8) & 255);      // stagger: distinct banks across qq
    float vj = vals[j];
    r += (vj < v || (vj == v && j < tg)) ? 1 : 0;
  }
  r += __shfl_xor(r, 1, 64);
  r += __shfl_xor(r, 2, 64);
  if (qq == 0) {
    out[OO_IDR + b * 1024 + tg] = (float)r;
    out[OO_MASK + b * 1024 + tg] = (r < 256) ? 0.0f : 1.0f;
    if (r < 256) {
      out[OO_IDK + b * 256 + r] = (float)tg;
      rowidx[b * 257 + r] = b * LTOK + tg;
    }
    if (tg == 0) rowidx[b * 257 + 256] = b * LTOK + 1024;
  }
}

// ---------------- im2col for conv-embed ----------------
__global__ void k_im2col(const float* __restrict__ x, float* __restrict__ X3) {
  int r = blockIdx.x;
  int b = r >> 10, t = r & 1023;
  int j = threadIdx.x;
  if (j < 192) {
    int i = j / 3, k = j % 3;
    int tt = t + k - 1;
    float v = (tt >= 0 && tt < 1024) ? x[((long)(b * 1024 + tt)) * 64 + i] : 0.f;
    X3[(long)r * 192 + j] = v;
  }
}

__global__ void k_clsrow(const float* __restrict__ cls, float* __restrict__ h) {
  h[((long)(blockIdx.x * LTOK + 1024)) * DM + threadIdx.x] = cls[threadIdx.x];
}

// ---------------- MFMA bf16 GEMM: C = A @ Bw^T (+bias), f32 in/out ----------------
// 128x128 tile, double-buffered LDS, optional split-K (atomicAdd epilogue, C pre-zeroed).
__global__ __launch_bounds__(256) void k_bgemm(
    const float* __restrict__ A, const float* __restrict__ Bw,
    float* __restrict__ C, const float* __restrict__ bias,
    const int* __restrict__ rowmap, int M, int N, int K, int ldc, int cmode) {
  __shared__ __align__(16) short sA[2][128 * 40];
  __shared__ __align__(16) short sB[2][128 * 40];
  int tid = threadIdx.x;
  int lane = tid & 63, w = tid >> 6;
  int lm = lane & 15, q = lane >> 4;
  int wm = (w >> 1) * 64, wn = (w & 1) * 64;
  int bm = blockIdx.y * 128, bn = blockIdx.x * 128;
  int gz = gridDim.z;
  int Ks = K / gz;
  int kbase = blockIdx.z * Ks;
  int nk = Ks >> 5;

  int srow[4], scol[4];
  long aoff[4]; bool aok[4]; long boff[4]; bool bok[4];
#pragma unroll
  for (int it = 0; it < 4; ++it) {
    int e4 = (tid + it * 256) * 4;
    srow[it] = e4 >> 5; scol[it] = e4 & 31;
    int gm = bm + srow[it];
    aok[it] = gm < M;
    aoff[it] = aok[it] ? (long)(rowmap ? rowmap[gm] : gm) * K : 0;
    int gn = bn + srow[it];
    bok[it] = gn < N;
    boff[it] = bok[it] ? (long)gn * K : 0;
  }

  auto gload = [&](int kt, float4* va, float4* vb) {
    int kc = kbase + kt * 32;
#pragma unroll
    for (int it = 0; it < 4; ++it) {
      va[it] = aok[it] ? *(const float4*)(A + aoff[it] + kc + scol[it])
                       : make_float4(0.f, 0.f, 0.f, 0.f);
      vb[it] = bok[it] ? *(const float4*)(Bw + boff[it] + kc + scol[it])
                       : make_float4(0.f, 0.f, 0.f, 0.f);
    }
  };
  auto sstore = [&](int buf, const float4* va, const float4* vb) {
#pragma unroll
    for (int it = 0; it < 4; ++it) {
      *(shortx4*)&sA[buf][srow[it] * 40 + scol[it]] =
          shortx4{f2bs(va[it].x), f2bs(va[it].y), f2bs(va[it].z), f2bs(va[it].w)};
      *(shortx4*)&sB[buf][srow[it] * 40 + scol[it]] =
          shortx4{f2bs(vb[it].x), f2bs(vb[it].y), f2bs(vb[it].z), f2bs(vb[it].w)};
    }
  };

  floatx4 acc[4][4] = {};
  float4 va[4], vb[4], na[4], nb[4];

  gload(0, va, vb);
  sstore(0, va, vb);
  for (int kt = 0; kt < nk; ++kt) {
    int cur = kt & 1;
    if (kt + 1 < nk) gload(kt + 1, na, nb);
    __syncthreads();
    short8 afrag[4], bfrag[4];
#pragma unroll
    for (int i = 0; i < 4; ++i)
      afrag[i] = *(const short8*)&sA[cur][(wm + i * 16 + lm) * 40 + q * 8];
#pragma unroll
    for (int j = 0; j < 4; ++j)
      bfrag[j] = *(const short8*)&sB[cur][(wn + j * 16 + lm) * 40 + q * 8];
#pragma unroll
    for (int i = 0; i < 4; ++i)
#pragma unroll
      for (int j = 0; j < 4; ++j)
        acc[i][j] = __builtin_amdgcn_mfma_f32_16x16x32_bf16(afrag[i], bfrag[j], acc[i][j], 0, 0, 0);
    if (kt + 1 < nk) sstore(1 - cur, na, nb);
  }

#pragma unroll
  for (int i = 0; i < 4; ++i) {
    int rowl = wm + i * 16 + q * 4;
#pragma unroll
    for (int reg = 0; reg < 4; ++reg) {
      int r = bm + rowl + reg;
      if (r >= M) continue;
      long crow = cmode ? (long)((r >> 10) * LTOK + (r & 1023)) : (long)r;
#pragma unroll
      for (int j = 0; j < 4; ++j) {
        int ccol = bn + wn + j * 16 + lm;
        if (ccol < N) {
          float v = acc[i][j][reg];
          if (gz > 1) {
            atomicAdd(&C[crow * ldc + ccol], v);
          } else {
            if (bias) v += bias[ccol];
            C[crow * ldc + ccol] = v;
          }
        }
      }
    }
  }
}

// ---------------- depthwise causal conv(4) + silu ----------------
__global__ __launch_bounds__(256) void k_conv1d(const float* __restrict__ zx,
                                                const float* __restrict__ w,
                                                const float* __restrict__ bias,
                                                float* __restrict__ xbc) {
  long r = blockIdx.x;
  int b = (int)(r / LTOK), t = (int)(r % LTOK);
  for (int c = threadIdx.x; c < CDIM; c += 256) {
    float acc = bias[c];
    const float* wp = w + c * 4;
#pragma unroll
    for (int k = 0; k < 4; ++k) {
      int tt = t - 3 + k;
      if (tt >= 0)
        acc = fmaf(wp[k], zx[((long)(b * LTOK + tt)) * EPROJ + DIN + c], acc);
    }
    xbc[r * CDIM + c] = acc / (1.f + expf(-acc));
  }
}

// ---------------- dt = softplus(logit + bias), lga = dt * -exp(A_log) ----------------
__global__ void k_dtda(const float* __restrict__ zx, const float* __restrict__ dtb,
                       const float* __restrict__ alog, float* __restrict__ dt,
                       float* __restrict__ lga) {
  int idx = blockIdx.x * 256 + threadIdx.x;
  if (idx >= NROWS * NHEAD) return;
  int r = idx >> 4, h = idx & 15;
  float xv = zx[(long)r * EPROJ + (EPROJ - NHEAD) + h] + dtb[h];
  float dtv = (xv > 20.f) ? xv : log1pf(expf(xv));
  dt[idx] = dtv;
  lga[idx] = dtv * (-expf(alog[h]));
}

// ---------------- SSD phase 1 (MFMA bf16): per (b,h,chunk) intra-chunk work ----------------
__global__ __launch_bounds__(256) void k_ssd1(const float* __restrict__ xbc,
                                              const float* __restrict__ dt,
                                              const float* __restrict__ lga,
                                              float* __restrict__ Y,
                                              float* __restrict__ SL,
                                              float* __restrict__ CLA) {
  int blk = blockIdx.x;
  int c = blk % NCH;
  int hh = blk / NCH;            // h + 16*b
  int h = hh & 15, b = hh >> 4;
  int tid = threadIdx.x;
  int lane = tid & 63, w = tid >> 6;
  int lm = lane & 15, q = lane >> 4;

  __shared__ __align__(16) short sB[64 * 136];
  __shared__ __align__(16) short sC[64 * 136];
  __shared__ __align__(16) short sBT[128 * 72];
  __shared__ __align__(16) short sXT[64 * 72];
  __shared__ __align__(16) short sM[64 * 72];
  __shared__ float dtw[64], clA[64], wwv[64];

  int t0 = c * QC;
  const float* base = xbc + (long)b * LTOK * CDIM;

  if (tid < 64) {
    int t = t0 + tid;
    dtw[tid] = (t < LTOK) ? dt[((long)(b * LTOK + t)) * NHEAD + h] : 0.f;
    clA[tid] = (t < LTOK) ? lga[((long)(b * LTOK + t)) * NHEAD + h] : 0.f;
  }
  __syncthreads();
  if (tid == 0) {
    float s = 0.f;
    for (int i = 0; i < 64; ++i) { s += clA[i]; clA[i] = s; }
  }
  __syncthreads();
  float clEnd = clA[63];
  if (tid < 64) {
    wwv[tid] = __expf(clEnd - clA[tid]) * dtw[tid];
    CLA[(long)blk * 64 + tid] = clA[tid];
  }
  __syncthreads();

#pragma unroll
  for (int k = 0; k < 8; ++k) {
    int e4 = (tid + k * 256) * 4;
    int row = e4 >> 7, col = e4 & 127;
    int t = t0 + row;
    float4 bv = make_float4(0.f,0.f,0.f,0.f), cv = make_float4(0.f,0.f,0.f,0.f);
    if (t < LTOK) {
      const float* rp = base + (long)t * CDIM;
      bv = *(const float4*)(rp + DIN + col);
      cv = *(const float4*)(rp + DIN + DST + col);
    }
    float wv = wwv[row];
    sB[row*136+col]=f2bs(bv.x); sB[row*136+col+1]=f2bs(bv.y);
    sB[row*136+col+2]=f2bs(bv.z); sB[row*136+col+3]=f2bs(bv.w);
    sC[row*136+col]=f2bs(cv.x); sC[row*136+col+1]=f2bs(cv.y);
    sC[row*136+col+2]=f2bs(cv.z); sC[row*136+col+3]=f2bs(cv.w);
    sBT[(col  )*72+row]=f2bs(bv.x*wv); sBT[(col+1)*72+row]=f2bs(bv.y*wv);
    sBT[(col+2)*72+row]=f2bs(bv.z*wv); sBT[(col+3)*72+row]=f2bs(bv.w*wv);
  }
#pragma unroll
  for (int k = 0; k < 4; ++k) {
    int e4 = (tid + k * 256) * 4;
    int row = e4 >> 6, col = e4 & 63;
    int t = t0 + row;
    float4 xv = make_float4(0.f,0.f,0.f,0.f);
    if (t < LTOK) xv = *(const float4*)(base + (long)t * CDIM + h * 64 + col);
    sXT[(col  )*72+row]=f2bs(xv.x); sXT[(col+1)*72+row]=f2bs(xv.y);
    sXT[(col+2)*72+row]=f2bs(xv.z); sXT[(col+3)*72+row]=f2bs(xv.w);
  }
  __syncthreads();

  floatx4 g[4] = {};
#pragma unroll
  for (int kb = 0; kb < 4; ++kb) {
    short8 a = *(const short8*)&sC[(w*16 + lm)*136 + kb*32 + q*8];
#pragma unroll
    for (int ct = 0; ct < 4; ++ct) {
      short8 bb = *(const short8*)&sB[(ct*16 + lm)*136 + kb*32 + q*8];
      g[ct] = __builtin_amdgcn_mfma_f32_16x16x32_bf16(a, bb, g[ct], 0, 0, 0);
    }
  }
#pragma unroll
  for (int ct = 0; ct < 4; ++ct) {
    int tp = ct*16 + lm;
#pragma unroll
    for (int reg = 0; reg < 4; ++reg) {
      int tl = w*16 + q*4 + reg;
      float m = 0.f;
      if (tp <= tl) m = g[ct][reg] * __expf(clA[tl] - clA[tp]) * dtw[tp];
      sM[tl*72 + tp] = f2bs(m);
    }
  }
  __syncthreads();

  floatx4 y[4] = {};
#pragma unroll
  for (int kb = 0; kb < 2; ++kb) {
    short8 a = *(const short8*)&sM[(w*16 + lm)*72 + kb*32 + q*8];
#pragma unroll
    for (int ct = 0; ct < 4; ++ct) {
      short8 bb = *(const short8*)&sXT[(ct*16 + lm)*72 + kb*32 + q*8];
      y[ct] = __builtin_amdgcn_mfma_f32_16x16x32_bf16(a, bb, y[ct], 0, 0, 0);
    }
  }
#pragma unroll
  for (int ct = 0; ct < 4; ++ct) {
    int p = ct*16 + lm;
#pragma unroll
    for (int reg = 0; reg < 4; ++reg) {
      int t = t0 + w*16 + q*4 + reg;
      if (t < LTOK)
        Y[((long)(b * LTOK + t)) * DIN + h * 64 + p] = y[ct][reg];
    }
  }

  floatx4 s[2][4] = {};
#pragma unroll
  for (int kb = 0; kb < 2; ++kb) {
    short8 bfr[4];
#pragma unroll
    for (int ct = 0; ct < 4; ++ct)
      bfr[ct] = *(const short8*)&sXT[(ct*16 + lm)*72 + kb*32 + q*8];
#pragma unroll
    for (int nt = 0; nt < 2; ++nt) {
      short8 a = *(const short8*)&sBT[((w*2+nt)*16 + lm)*72 + kb*32 + q*8];
#pragma unroll
      for (int ct = 0; ct < 4; ++ct)
        s[nt][ct] = __builtin_amdgcn_mfma_f32_16x16x32_bf16(a, bfr[ct], s[nt][ct], 0, 0, 0);
    }
  }
  float* slp = SL + (long)blk * 8192;
#pragma unroll
  for (int nt = 0; nt < 2; ++nt)
#pragma unroll
    for (int ct = 0; ct < 4; ++ct)
#pragma unroll
      for (int reg = 0; reg < 4; ++reg) {
        int n = (w*2+nt)*16 + q*4 + reg;
        int p = ct*16 + lm;
        slp[n*64 + p] = s[nt][ct][reg];
      }
}

// ---------------- SSD phase 2a: in-place sequential combine over chunks ----------------
__global__ __launch_bounds__(256) void k_comb(float* __restrict__ SL,
                                              const float* __restrict__ CLA) {
  int bx = blockIdx.x;
  int piece = bx & 7;
  int hh = bx >> 3;
  int off = piece * 1024 + threadIdx.x * 4;
  float4 s = make_float4(0.f, 0.f, 0.f, 0.f);
  for (int c = 0; c < NCH; ++c) {
    long cb = (long)(hh * NCH + c);
    float* p = SL + cb * 8192 + off;
    float P = __expf(CLA[cb * 64 + 63]);
    float4 tmp = *(float4*)p;
    *(float4*)p = s;
    s.x = fmaf(P, s.x, tmp.x);
    s.y = fmaf(P, s.y, tmp.y);
    s.z = fmaf(P, s.z, tmp.z);
    s.w = fmaf(P, s.w, tmp.w);
  }
}

// ---------------- SSD phase 2b: Y += evec[t] * C_t . S_start  (fully parallel) ----------------
__global__ __launch_bounds__(256) void k_ssd3(const float* __restrict__ xbc,
                                              const float* __restrict__ SL,
                                              const float* __restrict__ CLA,
                                              float* __restrict__ Y) {
  int blk = blockIdx.x;
  int c = blk % NCH;
  int hh = blk / NCH;
  int h = hh & 15, b = hh >> 4;
  int tid = threadIdx.x;
  int tx = tid & 15, ty = tid >> 4;

  __shared__ float Cs[64 * 65];
  __shared__ float Ss[64 * 64];
  __shared__ float evec[64];

  int t0 = c * QC;
  const float* base = xbc + (long)b * LTOK * CDIM;
  const float* slp = SL + (long)blk * 8192;
  if (tid < 64) evec[tid] = __expf(CLA[(long)blk * 64 + tid]);

  float y[4][4] = {};
#pragma unroll
  for (int half = 0; half < 2; ++half) {
    int n0 = half * 64;
    __syncthreads();
#pragma unroll
    for (int k = 0; k < 16; ++k) {
      int e = tid + k * 256;
      int row = e >> 6, col = e & 63;
      int t = t0 + row;
      Cs[row * 65 + col] = (t < LTOK) ? base[(long)t * CDIM + DIN + DST + n0 + col] : 0.f;
    }
#pragma unroll
    for (int k = 0; k < 4; ++k) {
      int e = (tid + k * 256) * 4;
      *(float4*)(Ss + e) = *(const float4*)(slp + n0 * 64 + e);
    }
    __syncthreads();
    for (int n = 0; n < 64; ++n) {
      float cv[4], sv[4];
#pragma unroll
      for (int i = 0; i < 4; ++i) cv[i] = Cs[(ty * 4 + i) * 65 + n];
#pragma unroll
      for (int j = 0; j < 4; ++j) sv[j] = Ss[n * 64 + tx * 4 + j];
#pragma unroll
      for (int i = 0; i < 4; ++i)
#pragma unroll
        for (int j = 0; j < 4; ++j) y[i][j] = fmaf(cv[i], sv[j], y[i][j]);
    }
  }
#pragma unroll
  for (int i = 0; i < 4; ++i) {
    int tl = ty * 4 + i;
    int t = t0 + tl;
    if (t < LTOK) {
      float ev = evec[tl];
      float* yp = Y + ((long)(b * LTOK + t)) * DIN + h * 64 + tx * 4;
#pragma unroll
      for (int j = 0; j < 4; ++j) yp[j] += ev * y[i][j];
    }
  }
}

// ---------------- y(+D*x) + gate silu(z) + RMSNorm, in place on Y ----------------
__global__ __launch_bounds__(256) void k_gaterms(float* __restrict__ Y,
                                                 const float* __restrict__ xbc,
                                                 const float* __restrict__ zx,
                                                 const float* __restrict__ Dv,
                                                 const float* __restrict__ rmsw) {
  long r = blockIdx.x;
  int tid = threadIdx.x;
  int e = tid * 4;
  int h = tid >> 4;
  float4 a = *(const float4*)(Y + r * DIN + e);
  const float4 xv = *(const float4*)(xbc + r * CDIM + e);
  const float4 zv = *(const float4*)(zx + r * EPROJ + e);
  float Dh = Dv[h];
  float y0 = a.x + Dh * xv.x, y1 = a.y + Dh * xv.y;
  float y2 = a.z + Dh * xv.z, y3 = a.w + Dh * xv.w;
  float g0 = y0 * (zv.x / (1.f + expf(-zv.x)));
  float g1 = y1 * (zv.y / (1.f + expf(-zv.y)));
  float g2 = y2 * (zv.z / (1.f + expf(-zv.z)));
  float g3 = y3 * (zv.w / (1.f + expf(-zv.w)));
  __shared__ float red[256];
  red[tid] = g0*g0 + g1*g1 + g2*g2 + g3*g3;
  __syncthreads();
  for (int st = 128; st; st >>= 1) {
    if (tid < st) red[tid] += red[tid + st];
    __syncthreads();
  }
  float scale = rsqrtf(red[0] * (1.0f / 1024.0f) + 1e-5f);
  float4 rw = *(const float4*)(rmsw + e);
  float4 o;
  o.x = g0 * scale * rw.x; o.y = g1 * scale * rw.y;
  o.z = g2 * scale * rw.z; o.w = g3 * scale * rw.w;
  *(float4*)(Y + r * DIN + e) = o;
}

// ---------------- final LayerNorm -> f32 out ----------------
__global__ __launch_bounds__(256) void k_ln(const float* __restrict__ outg,
                                            const float* __restrict__ lng,
                                            const float* __restrict__ lnb,
                                            float* __restrict__ out) {
  int r = blockIdx.x;
  int tid = threadIdx.x;
  const float2 v = *(const float2*)(outg + (long)r * DM + tid * 2);
  __shared__ float red[256];
  red[tid] = v.x + v.y;
  __syncthreads();
  for (int st = 128; st; st >>= 1) { if (tid < st) red[tid] += red[tid + st]; __syncthreads(); }
  float mu = red[0] * (1.0f / 512.0f);
  __syncthreads();
  float dx = v.x - mu, dy = v.y - mu;
  red[tid] = dx * dx + dy * dy;
  __syncthreads();
  for (int st = 128; st; st >>= 1) { if (tid < st) red[tid] += red[tid + st]; __syncthreads(); }
  float sc = rsqrtf(red[0] * (1.0f / 512.0f) + 1e-5f);
  int c = tid * 2;
  out[(long)r * DM + c]     = dx * sc * lng[c] + lnb[c];
  out[(long)r * DM + c + 1] = dy * sc * lng[c + 1] + lnb[c + 1];
}

// ---------------- launch ----------------
extern "C" void kernel_launch(void* const* d_in, const int* in_sizes, int n_in,
                              void* d_out, int out_size, void* d_ws, size_t ws_size,
                              hipStream_t stream) {
  float* ws = (float*)d_ws;
  float* out = (float*)d_out;
  int* rowidx = (int*)(ws + O_RIDX);
  InPtrs ip;
  for (int i = 0; i < 14; ++i) ip.p[i] = d_in[i];

  hipLaunchKernelGGL(k_convert, dim3(1160, 14), dim3(256), 0, stream, ip, ws);
  hipLaunchKernelGGL(k_rng, dim3(16, 2), dim3(256), 0, stream, out, rowidx);
  hipLaunchKernelGGL(k_im2col, dim3(2048), dim3(192), 0, stream, ws + O_CX, ws + O_X3);
  hipLaunchKernelGGL(k_clsrow, dim3(2), dim3(512), 0, stream, ws + O_CLS, ws + O_H);
  // conv-embed GEMM (MFMA): (2048 x 192) @ (512 x 192)^T + bias -> H (cls-gap remap)
  hipLaunchKernelGGL(k_bgemm, dim3(4, 16, 1), dim3(256), 0, stream,
                     ws + O_X3, ws + O_CW, ws + O_H, ws + O_CB, (const int*)nullptr,
                     2048, 512, 192, 512, 1);
  // in_proj GEMM (MFMA): (2050 x 512) @ (2320 x 512)^T -> zxbcdt
  hipLaunchKernelGGL(k_bgemm, dim3(19, 17, 1), dim3(256), 0, stream,
                     ws + O_H, ws + O_IPW, ws + O_ZX, (const float*)nullptr, (const int*)nullptr,
                     2050, 2320, 512, 2320, 0);
  hipLaunchKernelGGL(k_conv1d, dim3(2050), dim3(256), 0, stream,
                     ws + O_ZX, ws + O_C1W, ws + O_C1B, ws + O_XBC);
  hipLaunchKernelGGL(k_dtda, dim3(129), dim3(256), 0, stream,
                     ws + O_ZX, ws + O_DTB, ws + O_ALOG, ws + O_DT, ws + O_LGA);
  hipLaunchKernelGGL(k_ssd1, dim3(32 * NCH), dim3(256), 0, stream,
                     ws + O_XBC, ws + O_DT, ws + O_LGA, ws + O_Y, ws + O_SL, ws + O_CLA);
  hipLaunchKernelGGL(k_comb, dim3(256), dim3(256), 0, stream, ws + O_SL, ws + O_CLA);
  hipLaunchKernelGGL(k_ssd3, dim3(32 * NCH), dim3(256), 0, stream,
                     ws + O_XBC, ws + O_SL, ws + O_CLA, ws + O_Y);
  hipLaunchKernelGGL(k_gaterms, dim3(2050), dim3(256), 0, stream,
                     ws + O_Y, ws + O_XBC, ws + O_ZX, ws + O_DV, ws + O_RMSW);
  // out_proj GEMM (MFMA, split-K=4 + atomics): (514 x 1024) @ (512 x 1024)^T -> outg
  hipLaunchKernelGGL(k_zero, dim3(257), dim3(256), 0, stream, ws + O_OUTG, 263168);
  hipLaunchKernelGGL(k_bgemm, dim3(4, 5, 4), dim3(256), 0, stream,
                     ws + O_Y, ws + O_OPW, ws + O_OUTG, (const float*)nullptr, rowidx,
                     514, 512, 1024, 512, 0);
  hipLaunchKernelGGL(k_ln, dim3(514), dim3(256), 0, stream,
                     ws + O_OUTG, ws + O_LNG, ws + O_LNB, out);
}